// Round 2
// baseline (2936.195 us; speedup 1.0000x reference)
//
#include <hip/hip_runtime.h>
#include <hip/hip_bf16.h>

#define D_MODEL 2048
#define N_HEADS 16
#define HEAD_DIM 128
#define D_FF 8192
#define BATCH 2
#define SEQ 2048
#define M_TOK (BATCH * SEQ)
#define QKV_LD 6144

typedef __attribute__((ext_vector_type(8))) short short8;
typedef __attribute__((ext_vector_type(4))) float f32x4;

__device__ __forceinline__ unsigned short f2b(float f) {
  __hip_bfloat16 h = __float2bfloat16(f);
  return *reinterpret_cast<unsigned short*>(&h);
}
__device__ __forceinline__ float b2f(unsigned short u) {
  unsigned int x = ((unsigned int)u) << 16;
  return __uint_as_float(x);
}

__device__ __forceinline__ void gload_lds16(const void* gsrc, void* ldst) {
  __builtin_amdgcn_global_load_lds(
      (const __attribute__((address_space(1))) void*)gsrc,
      (__attribute__((address_space(3))) void*)ldst, 16, 0, 0);
}

// ---------------- f32 -> bf16 convert (grid-stride, 8 elems/thread) ----------
__global__ __launch_bounds__(256)
void cvt_kernel(const float* __restrict__ src, unsigned short* __restrict__ dst,
                int nchunks) {
  int i = blockIdx.x * blockDim.x + threadIdx.x;
  int stride = gridDim.x * blockDim.x;
  for (int c = i; c < nchunks; c += stride) {
    const float4 a = *(const float4*)(src + (size_t)c * 8);
    const float4 b = *(const float4*)(src + (size_t)c * 8 + 4);
    short8 r;
    r[0] = f2b(a.x); r[1] = f2b(a.y); r[2] = f2b(a.z); r[3] = f2b(a.w);
    r[4] = f2b(b.x); r[5] = f2b(b.y); r[6] = f2b(b.z); r[7] = f2b(b.w);
    *(short8*)(dst + (size_t)c * 8) = r;
  }
}

// ---------------- concat bias: [bq+rot | bk | bv] ----------------------------
__global__ void biasqkv_kernel(const float* __restrict__ bq,
                               const float* __restrict__ bk,
                               const float* __restrict__ bv,
                               const float* __restrict__ rot,
                               float* __restrict__ outp) {
  int i = blockIdx.x * 256 + threadIdx.x;
  float v;
  if (i < 2048) v = bq[i] + rot[i & (HEAD_DIM - 1)];
  else if (i < 4096) v = bk[i - 2048];
  else v = bv[i - 4096];
  outp[i] = v;
}

// ---------------- RMSNorm: f32 in -> bf16 out, one block per row -------------
__global__ __launch_bounds__(256)
void rmsnorm_kernel(const float* __restrict__ x, const float* __restrict__ wv,
                    unsigned short* __restrict__ outp) {
  const int row = blockIdx.x;
  const float* xr = x + (size_t)row * D_MODEL;
  const int base = threadIdx.x * 8;
  float4 a = *(const float4*)(xr + base);
  float4 c = *(const float4*)(xr + base + 4);
  float ss = a.x * a.x + a.y * a.y + a.z * a.z + a.w * a.w +
             c.x * c.x + c.y * c.y + c.z * c.z + c.w * c.w;
#pragma unroll
  for (int m = 1; m < 64; m <<= 1) ss += __shfl_xor(ss, m);
  __shared__ float red[4];
  if ((threadIdx.x & 63) == 0) red[threadIdx.x >> 6] = ss;
  __syncthreads();
  float tot = red[0] + red[1] + red[2] + red[3];
  float sc = rsqrtf(tot * (1.0f / D_MODEL) + 1e-8f);
  float4 w0 = *(const float4*)(wv + base);
  float4 w1 = *(const float4*)(wv + base + 4);
  short8 r;
  r[0] = f2b(a.x * sc * w0.x); r[1] = f2b(a.y * sc * w0.y);
  r[2] = f2b(a.z * sc * w0.z); r[3] = f2b(a.w * sc * w0.w);
  r[4] = f2b(c.x * sc * w1.x); r[5] = f2b(c.y * sc * w1.y);
  r[6] = f2b(c.z * sc * w1.z); r[7] = f2b(c.w * sc * w1.w);
  *(short8*)(outp + (size_t)row * D_MODEL + base) = r;
}

// ---------------- GEMM 256x256, BK=32, triple-buffered, counted vmcnt --------
// C[M,N] = A[M,K] @ W[N,K]^T   (per-z slice: koff = z*K)
// MODE 0: bf16 out + bias.  MODE 1: f32 out + bias + res.  MODE 2: raw f32 out.
template <int MODE>
__global__ __launch_bounds__(512, 2)
void gemm256(const unsigned short* __restrict__ A, int lda,
             const unsigned short* __restrict__ W, int ldw,
             const float* __restrict__ bias, const float* __restrict__ res,
             void* __restrict__ outp, int N, int K, size_t out_zstride) {
  __shared__ unsigned short As[3][256 * 32];
  __shared__ unsigned short Bs[3][256 * 32];
  const int t = threadIdx.x;
  const int l = t & 63, w = t >> 6;
  const int wm = w >> 2, wn = w & 3;
  const int lr = l & 15, lg = l >> 4;
  const int m0 = blockIdx.y << 8, n0 = blockIdx.x << 8;
  const int koff = blockIdx.z * K;

  // staging invariants: thread t covers chunks t and t+512 of each tile
  // (chunk = 16B; row = c>>2, phys slot = c&3 holds logical slot (c&3)^(row&3))
  const int arow = t >> 2;
  const int slog = (t & 3) ^ (arow & 3);  // row+128 has same (row&3)
  const unsigned short* Ag0 = A + (size_t)(m0 + arow) * lda + koff + slog * 8;
  const unsigned short* Ag1 = Ag0 + (size_t)128 * lda;
  const unsigned short* Wg0 = W + (size_t)(n0 + arow) * ldw + koff + slog * 8;
  const unsigned short* Wg1 = Wg0 + (size_t)128 * ldw;
  const int ldsc0 = t * 8, ldsc1 = (512 + t) * 8;

  // fragment-read invariants (swizzled logical->phys slot: s ^ (row&3))
  const int sw8 = (lg ^ (lr & 3)) * 8;

  f32x4 acc[8][4] = {};
  const int NT = K / 32;

#define STAGE256(s, tt_)                                   \
  do {                                                     \
    const int kk0_ = (tt_) * 32;                           \
    gload_lds16(Ag0 + kk0_, &As[s][ldsc0]);                \
    gload_lds16(Ag1 + kk0_, &As[s][ldsc1]);                \
    gload_lds16(Wg0 + kk0_, &Bs[s][ldsc0]);                \
    gload_lds16(Wg1 + kk0_, &Bs[s][ldsc1]);                \
  } while (0)

  auto compute_tile = [&](int ct) {
    const unsigned short* __restrict__ Asl = &As[ct][0];
    const unsigned short* __restrict__ Bsl = &Bs[ct][0];
    short8 bfr[4];
#pragma unroll
    for (int n = 0; n < 4; n++)
      bfr[n] = *(const short8*)&Bsl[(wn * 64 + n * 16 + lr) * 32 + sw8];
    __builtin_amdgcn_s_setprio(1);
#pragma unroll
    for (int m = 0; m < 8; m++) {
      short8 af = *(const short8*)&Asl[(wm * 128 + m * 16 + lr) * 32 + sw8];
#pragma unroll
      for (int n = 0; n < 4; n++)
        acc[m][n] =
            __builtin_amdgcn_mfma_f32_16x16x32_bf16(af, bfr[n], acc[m][n], 0, 0, 0);
    }
    __builtin_amdgcn_s_setprio(0);
  };

  // prologue: tiles 0 and 1 in flight; wait tile 0 landed (4 newest pending)
  STAGE256(0, 0);
  STAGE256(1, 1);
  asm volatile("s_waitcnt vmcnt(4)" ::: "memory");
  __builtin_amdgcn_s_barrier();
  __builtin_amdgcn_sched_barrier(0);

  int ct = 0;
  for (int tt = 0; tt < NT; ++tt) {
    if (tt + 2 < NT) {
      int s2 = ct + 2; if (s2 >= 3) s2 -= 3;
      STAGE256(s2, tt + 2);
      compute_tile(ct);
      asm volatile("s_waitcnt vmcnt(4)" ::: "memory");  // tile tt+1 landed
    } else {
      compute_tile(ct);
      asm volatile("s_waitcnt vmcnt(0)" ::: "memory");
    }
    __builtin_amdgcn_s_barrier();
    __builtin_amdgcn_sched_barrier(0);
    ct = (ct + 1 == 3) ? 0 : ct + 1;
  }
#undef STAGE256

  // epilogue: C row = m0 + wm*128 + m*16 + lg*4 + j ; col = n0 + wn*64 + n*16 + lr
  const int crow = m0 + wm * 128 + lg * 4;
  const int ccol = n0 + wn * 64 + lr;
#pragma unroll
  for (int m = 0; m < 8; m++) {
#pragma unroll
    for (int n = 0; n < 4; n++) {
      const int cn = ccol + n * 16;
      float bv = (MODE == 2) ? 0.0f : bias[cn];
#pragma unroll
      for (int j = 0; j < 4; j++) {
        const size_t idx = (size_t)(crow + m * 16 + j) * N + cn;
        float vv = acc[m][n][j] + bv;
        if (MODE == 0) {
          ((unsigned short*)outp)[idx] = f2b(vv);
        } else if (MODE == 1) {
          ((float*)outp)[idx] = vv + res[idx];
        } else {
          ((float*)outp + blockIdx.z * out_zstride)[idx] = vv;
        }
      }
    }
  }
}

// ---------------- V transpose: qkv v-slice -> vt[(bh*128+d)*S + s] -----------
__global__ __launch_bounds__(256)
void vtrans_kernel(const unsigned short* __restrict__ qkv,
                   unsigned short* __restrict__ vt) {
  const int bh = blockIdx.y;
  const int b = bh >> 4, h = bh & 15;
  const int s0 = blockIdx.x * 32;
  __shared__ unsigned short tile[32][136];
  const int t = threadIdx.x;
  for (int i = 0; i < 2; i++) {
    int c = t + i * 256;
    int s = c >> 4, dc = c & 15;
    *(short8*)&tile[s][dc * 8] =
        *(const short8*)(qkv + (size_t)(b * SEQ + s0 + s) * QKV_LD + 4096 +
                         h * HEAD_DIM + dc * 8);
  }
  __syncthreads();
  const int d = t >> 1, sh = (t & 1) * 16;
  unsigned short* dst = vt + ((size_t)bh * HEAD_DIM + d) * SEQ + s0 + sh;
  short8 r0, r1;
#pragma unroll
  for (int j = 0; j < 8; j++) r0[j] = tile[sh + j][d];
#pragma unroll
  for (int j = 0; j < 8; j++) r1[j] = tile[sh + 8 + j][d];
  *(short8*)dst = r0;
  *(short8*)(dst + 8) = r1;
}

// ---------------- Flash attention: Q-tile 64 (16 rows/wave), KV-tile 64 ------
__global__ __launch_bounds__(256)
void attn_kernel(const unsigned short* __restrict__ qkv,
                 const unsigned short* __restrict__ vt,
                 unsigned short* __restrict__ o) {
  const int bh = blockIdx.y;
  const int b = bh >> 4, h = bh & 15;
  const int q0 = blockIdx.x << 6;
  const int t = threadIdx.x, w = t >> 6, l = t & 63;
  const int lr = l & 15, lg = l >> 4;

  __shared__ unsigned short Ks[64 * 128];
  __shared__ unsigned short Ps[4][16 * 64];

  short8 qf[4];
  {
    const unsigned short* qb =
        qkv + ((size_t)(b * SEQ + q0 + w * 16 + lr)) * QKV_LD + h * HEAD_DIM;
#pragma unroll
    for (int ks = 0; ks < 4; ks++) qf[ks] = *(const short8*)(qb + ks * 32 + lg * 8);
  }

  f32x4 oacc[8] = {};
  float mrow[4] = {-1e30f, -1e30f, -1e30f, -1e30f};
  float lrowv[4] = {0.f, 0.f, 0.f, 0.f};
  const float scl = 0.08838834764831845f;

  const unsigned short* kbase =
      qkv + (size_t)(b * SEQ) * QKV_LD + 2048 + h * HEAD_DIM;
  const unsigned short* vtb = vt + (size_t)bh * HEAD_DIM * SEQ;
  unsigned short* pw = &Ps[w][0];

  for (int kv0 = 0; kv0 < SEQ; kv0 += 64) {
    for (int i = 0; i < 4; i++) {
      int c = t + i * 256;
      int row = c >> 4, dc = c & 15;
      short8 val = *(const short8*)(kbase + (size_t)(kv0 + row) * QKV_LD + dc * 8);
      int byo = ((row * 256 + dc * 16) ^ ((row & 7) << 4));
      *(short8*)((char*)Ks + byo) = val;
    }
    __syncthreads();

    f32x4 s[4] = {};
#pragma unroll
    for (int nf = 0; nf < 4; nf++) {
      int key = nf * 16 + lr;
#pragma unroll
      for (int ks = 0; ks < 4; ks++) {
        int byo = ((key * 256 + ks * 64 + lg * 16) ^ ((key & 7) << 4));
        short8 kf = *(const short8*)((char*)Ks + byo);
        s[nf] = __builtin_amdgcn_mfma_f32_16x16x32_bf16(qf[ks], kf, s[nf], 0, 0, 0);
      }
    }

    float pm[4];
#pragma unroll
    for (int j = 0; j < 4; j++) {
      float mx = -1e30f;
#pragma unroll
      for (int nf = 0; nf < 4; nf++) {
        s[nf][j] *= scl;
        mx = fmaxf(mx, s[nf][j]);
      }
      mx = fmaxf(mx, __shfl_xor(mx, 1));
      mx = fmaxf(mx, __shfl_xor(mx, 2));
      mx = fmaxf(mx, __shfl_xor(mx, 4));
      mx = fmaxf(mx, __shfl_xor(mx, 8));
      pm[j] = mx;
    }
    float fs[4];
#pragma unroll
    for (int j = 0; j < 4; j++) {
      float mn = fmaxf(mrow[j], pm[j]);
      fs[j] = __expf(mrow[j] - mn);
      mrow[j] = mn;
    }
    float rs[4] = {0.f, 0.f, 0.f, 0.f};
#pragma unroll
    for (int nf = 0; nf < 4; nf++)
#pragma unroll
      for (int j = 0; j < 4; j++) {
        float p = __expf(s[nf][j] - mrow[j]);
        s[nf][j] = p;
        rs[j] += p;
      }
#pragma unroll
    for (int j = 0; j < 4; j++) {
      float r = rs[j];
      r += __shfl_xor(r, 1);
      r += __shfl_xor(r, 2);
      r += __shfl_xor(r, 4);
      r += __shfl_xor(r, 8);
      lrowv[j] = lrowv[j] * fs[j] + r;
    }
#pragma unroll
    for (int nf = 0; nf < 8; nf++)
#pragma unroll
      for (int j = 0; j < 4; j++) oacc[nf][j] *= fs[j];

#pragma unroll
    for (int nf = 0; nf < 4; nf++)
#pragma unroll
      for (int j = 0; j < 4; j++) {
        int row = lg * 4 + j, col = nf * 16 + lr;
        int byo = ((row * 128 + col * 2) ^ ((row & 7) << 4));
        *(unsigned short*)((char*)pw + byo) = f2b(s[nf][j]);
      }
    asm volatile("s_waitcnt lgkmcnt(0)" ::: "memory");
#pragma unroll
    for (int ks = 0; ks < 2; ks++) {
      int byo = ((lr * 128 + ks * 64 + lg * 16) ^ ((lr & 7) << 4));
      short8 pa = *(const short8*)((char*)pw + byo);
#pragma unroll
      for (int nf = 0; nf < 8; nf++) {
        short8 vf = *(const short8*)(vtb + (size_t)(nf * 16 + lr) * SEQ + kv0 +
                                     ks * 32 + lg * 8);
        oacc[nf] = __builtin_amdgcn_mfma_f32_16x16x32_bf16(pa, vf, oacc[nf], 0, 0, 0);
      }
    }
    __syncthreads();
  }

  unsigned short* ob =
      o + ((size_t)(b * SEQ + q0 + w * 16)) * D_MODEL + h * HEAD_DIM;
#pragma unroll
  for (int j = 0; j < 4; j++) {
    float inv = 1.0f / lrowv[j];
    int row = lg * 4 + j;
#pragma unroll
    for (int nf = 0; nf < 8; nf++) {
      int col = nf * 16 + lr;
      ob[(size_t)row * D_MODEL + col] = f2b(oacc[nf][j] * inv);
    }
  }
}

// ---------------- SwiGLU in-place on g (row stride 16384) --------------------
__global__ __launch_bounds__(256)
void swiglu_kernel(unsigned short* __restrict__ g) {
  size_t i = (size_t)blockIdx.x * 256 + threadIdx.x;
  size_t m = i >> 10, jc = i & 1023;
  unsigned short* p1 = g + m * (2 * D_FF) + jc * 8;
  short8 aa = *(short8*)p1;
  short8 bb = *(short8*)(p1 + D_FF);
  short8 r;
#pragma unroll
  for (int jj = 0; jj < 8; jj++) {
    float x1 = b2f((unsigned short)aa[jj]);
    float x2 = b2f((unsigned short)bb[jj]);
    float sg = x2 / (1.0f + __expf(-x2));
    r[jj] = f2b(x1 * sg);
  }
  *(short8*)p1 = r;
}

// ---------------- split-K reduce: out += p0 + p1 + b2 ------------------------
__global__ __launch_bounds__(256)
void reduce2_kernel(const float* __restrict__ p0, const float* __restrict__ p1,
                    const float* __restrict__ b2, float* __restrict__ out) {
  size_t i = (size_t)blockIdx.x * 256 + threadIdx.x;  // float4 index
  float4 a = ((const float4*)p0)[i];
  float4 b = ((const float4*)p1)[i];
  float4 o = ((const float4*)out)[i];
  float4 bb = ((const float4*)b2)[i & 511];
  o.x += a.x + b.x + bb.x;
  o.y += a.y + b.y + bb.y;
  o.z += a.z + b.z + bb.z;
  o.w += a.w + b.w + bb.w;
  ((float4*)out)[i] = o;
}

// ---------------- host: launch sequence --------------------------------------
extern "C" void kernel_launch(void* const* d_in, const int* in_sizes, int n_in,
                              void* d_out, int out_size, void* d_ws,
                              size_t ws_size, hipStream_t stream) {
  (void)in_sizes; (void)n_in; (void)out_size; (void)ws_size;
  const float* x   = (const float*)d_in[0];
  const float* Wq  = (const float*)d_in[1];
  const float* bq  = (const float*)d_in[2];
  const float* Wk  = (const float*)d_in[3];
  const float* bk  = (const float*)d_in[4];
  const float* Wv  = (const float*)d_in[5];
  const float* bv  = (const float*)d_in[6];
  const float* Wo  = (const float*)d_in[7];
  const float* bo  = (const float*)d_in[8];
  const float* rot = (const float*)d_in[9];
  const float* n1w = (const float*)d_in[10];
  const float* n2w = (const float*)d_in[11];
  const float* W1  = (const float*)d_in[12];
  const float* b1  = (const float*)d_in[13];
  const float* W2  = (const float*)d_in[14];
  const float* b2  = (const float*)d_in[15];
  float* out = (float*)d_out;
  char* ws = (char*)d_ws;

  const size_t SZ_D2  = (size_t)D_MODEL * D_MODEL * 2;   // 8 MiB
  const size_t SZ_ACT = (size_t)M_TOK * D_MODEL * 2;     // 16 MiB
  const size_t SZ_W1  = (size_t)2 * D_FF * D_MODEL * 2;  // 64 MiB
  const size_t SZ_W2  = (size_t)D_MODEL * D_FF * 2;      // 32 MiB
  const size_t SZ_G   = (size_t)M_TOK * 2 * D_FF * 2;    // 128 MiB

  size_t off = 0;
  auto alloc = [&](size_t sz) { size_t o = off; off += (sz + 255) & ~(size_t)255; return o; };
  unsigned short* wqkv_b = (unsigned short*)(ws + alloc(3 * SZ_D2));  // at ws+0
  unsigned short* wo_b   = (unsigned short*)(ws + alloc(SZ_D2));
  unsigned short* w1_b   = (unsigned short*)(ws + alloc(SZ_W1));
  unsigned short* w2_b   = (unsigned short*)(ws + alloc(SZ_W2));
  float*          biasq  = (float*)(ws + alloc(QKV_LD * 4));
  unsigned short* h2_b   = (unsigned short*)(ws + alloc(SZ_ACT));
  char* pool = ws + alloc(SZ_G);
  // phase 1 overlay in pool: h | qkv | vt | o   (16+48+16+16 = 96 MiB)
  unsigned short* h_b   = (unsigned short*)(pool);
  unsigned short* qkv_b = (unsigned short*)(pool + SZ_ACT);
  unsigned short* vt_b  = (unsigned short*)(pool + 4 * SZ_ACT);
  unsigned short* o_b   = (unsigned short*)(pool + 5 * SZ_ACT);
  // phase 2 overlay: g occupies whole pool
  unsigned short* g_b   = (unsigned short*)(pool);
  // split-K partials overlay the (then-dead) wqkv/wo/w1 region: 2x 33.6 MiB <= 96 MiB
  float* p0 = (float*)ws;
  float* p1 = p0 + (size_t)M_TOK * D_MODEL;

  // weights -> bf16 (Q,K,V concatenated row-wise)
  cvt_kernel<<<1024, 256, 0, stream>>>(Wq, wqkv_b, D_MODEL * D_MODEL / 8);
  cvt_kernel<<<1024, 256, 0, stream>>>(Wk, wqkv_b + (size_t)D_MODEL * D_MODEL, D_MODEL * D_MODEL / 8);
  cvt_kernel<<<1024, 256, 0, stream>>>(Wv, wqkv_b + (size_t)2 * D_MODEL * D_MODEL, D_MODEL * D_MODEL / 8);
  cvt_kernel<<<1024, 256, 0, stream>>>(Wo, wo_b, D_MODEL * D_MODEL / 8);
  cvt_kernel<<<2048, 256, 0, stream>>>(W1, w1_b, 2 * D_FF * D_MODEL / 8);
  cvt_kernel<<<2048, 256, 0, stream>>>(W2, w2_b, D_MODEL * D_FF / 8);
  biasqkv_kernel<<<QKV_LD / 256, 256, 0, stream>>>(bq, bk, bv, rot, biasq);

  // norm1 -> h
  rmsnorm_kernel<<<M_TOK, 256, 0, stream>>>(x, n1w, h_b);

  // fused QKV projection: [4096,2048] @ [6144,2048]^T -> [4096,6144]
  gemm256<0><<<dim3(QKV_LD / 256, M_TOK / 256), 512, 0, stream>>>(
      h_b, D_MODEL, wqkv_b, D_MODEL, biasq, nullptr, qkv_b, QKV_LD, D_MODEL, 0);

  // V transpose + attention
  vtrans_kernel<<<dim3(SEQ / 32, BATCH * N_HEADS), 256, 0, stream>>>(qkv_b, vt_b);
  attn_kernel<<<dim3(SEQ / 64, BATCH * N_HEADS), 256, 0, stream>>>(qkv_b, vt_b, o_b);

  // O projection + residual -> d_out (f32)
  gemm256<1><<<dim3(D_MODEL / 256, M_TOK / 256), 512, 0, stream>>>(
      o_b, D_MODEL, wo_b, D_MODEL, bo, x, out, D_MODEL, D_MODEL, 0);

  // norm2 -> h2
  rmsnorm_kernel<<<M_TOK, 256, 0, stream>>>(out, n2w, h2_b);

  // W1 -> g (bf16, 4096 x 16384)
  gemm256<0><<<dim3(2 * D_FF / 256, M_TOK / 256), 512, 0, stream>>>(
      h2_b, D_MODEL, w1_b, D_MODEL, b1, nullptr, g_b, 2 * D_FF, D_MODEL, 0);

  // SwiGLU in-place
  swiglu_kernel<<<(M_TOK * D_FF / 8) / 256, 256, 0, stream>>>(g_b);

  // W2 split-K (z=0: K 0..4095, z=1: K 4096..8191) -> partials
  gemm256<2><<<dim3(D_MODEL / 256, M_TOK / 256, 2), 512, 0, stream>>>(
      g_b, 2 * D_FF, w2_b, D_FF, nullptr, nullptr, p0, D_MODEL, D_FF / 2,
      (size_t)M_TOK * D_MODEL);

  // out += p0 + p1 + b2
  reduce2_kernel<<<(M_TOK * D_MODEL / 4) / 256, 256, 0, stream>>>(p0, p1, b2, out);
}

// Round 3
// 1424.430 us; speedup vs baseline: 2.0613x; 2.0613x over previous
//
#include <hip/hip_runtime.h>
#include <hip/hip_bf16.h>

#define D_MODEL 2048
#define N_HEADS 16
#define HEAD_DIM 128
#define D_FF 8192
#define BATCH 2
#define SEQ 2048
#define M_TOK (BATCH * SEQ)
#define QKV_LD 6144

typedef __attribute__((ext_vector_type(8))) short short8;
typedef __attribute__((ext_vector_type(4))) float f32x4;

__device__ __forceinline__ unsigned short f2b(float f) {
  __hip_bfloat16 h = __float2bfloat16(f);
  return *reinterpret_cast<unsigned short*>(&h);
}
__device__ __forceinline__ float b2f(unsigned short u) {
  unsigned int x = ((unsigned int)u) << 16;
  return __uint_as_float(x);
}

__device__ __forceinline__ void gload_lds16(const void* gsrc, void* ldst) {
  __builtin_amdgcn_global_load_lds(
      (const __attribute__((address_space(1))) void*)gsrc,
      (__attribute__((address_space(3))) void*)ldst, 16, 0, 0);
}

// ---------------- f32 -> bf16 convert (grid-stride, 8 elems/thread) ----------
__global__ __launch_bounds__(256)
void cvt_kernel(const float* __restrict__ src, unsigned short* __restrict__ dst,
                int nchunks) {
  int i = blockIdx.x * blockDim.x + threadIdx.x;
  int stride = gridDim.x * blockDim.x;
  for (int c = i; c < nchunks; c += stride) {
    const float4 a = *(const float4*)(src + (size_t)c * 8);
    const float4 b = *(const float4*)(src + (size_t)c * 8 + 4);
    short8 r;
    r[0] = f2b(a.x); r[1] = f2b(a.y); r[2] = f2b(a.z); r[3] = f2b(a.w);
    r[4] = f2b(b.x); r[5] = f2b(b.y); r[6] = f2b(b.z); r[7] = f2b(b.w);
    *(short8*)(dst + (size_t)c * 8) = r;
  }
}

// ---------------- concat bias: [bq+rot | bk | bv] ----------------------------
__global__ void biasqkv_kernel(const float* __restrict__ bq,
                               const float* __restrict__ bk,
                               const float* __restrict__ bv,
                               const float* __restrict__ rot,
                               float* __restrict__ outp) {
  int i = blockIdx.x * 256 + threadIdx.x;
  float v;
  if (i < 2048) v = bq[i] + rot[i & (HEAD_DIM - 1)];
  else if (i < 4096) v = bk[i - 2048];
  else v = bv[i - 4096];
  outp[i] = v;
}

// ---------------- RMSNorm: f32 in -> bf16 out, one block per row -------------
__global__ __launch_bounds__(256)
void rmsnorm_kernel(const float* __restrict__ x, const float* __restrict__ wv,
                    unsigned short* __restrict__ outp) {
  const int row = blockIdx.x;
  const float* xr = x + (size_t)row * D_MODEL;
  const int base = threadIdx.x * 8;
  float4 a = *(const float4*)(xr + base);
  float4 c = *(const float4*)(xr + base + 4);
  float ss = a.x * a.x + a.y * a.y + a.z * a.z + a.w * a.w +
             c.x * c.x + c.y * c.y + c.z * c.z + c.w * c.w;
#pragma unroll
  for (int m = 1; m < 64; m <<= 1) ss += __shfl_xor(ss, m);
  __shared__ float red[4];
  if ((threadIdx.x & 63) == 0) red[threadIdx.x >> 6] = ss;
  __syncthreads();
  float tot = red[0] + red[1] + red[2] + red[3];
  float sc = rsqrtf(tot * (1.0f / D_MODEL) + 1e-8f);
  float4 w0 = *(const float4*)(wv + base);
  float4 w1 = *(const float4*)(wv + base + 4);
  short8 r;
  r[0] = f2b(a.x * sc * w0.x); r[1] = f2b(a.y * sc * w0.y);
  r[2] = f2b(a.z * sc * w0.z); r[3] = f2b(a.w * sc * w0.w);
  r[4] = f2b(c.x * sc * w1.x); r[5] = f2b(c.y * sc * w1.y);
  r[6] = f2b(c.z * sc * w1.z); r[7] = f2b(c.w * sc * w1.w);
  *(short8*)(outp + (size_t)row * D_MODEL + base) = r;
}

// ---------------- GEMM 128x128 (proven m97 structure) + T1 XCD swizzle -------
// C[M,N] = A[M, koff:koff+K] @ W[N, koff:koff+K]^T  (koff = blockIdx.z * K)
// MODE 0: bf16 out + bias.  MODE 1: f32 out + bias + res.  MODE 2: raw f32 out.
template <int MODE>
__global__ __launch_bounds__(256)
void gemm_bt(const unsigned short* __restrict__ A, int lda,
             const unsigned short* __restrict__ W, int ldw,
             const float* __restrict__ bias, const float* res, void* outp,
             int N, int K, size_t out_zstride) {
  __shared__ unsigned short As[128 * 32];
  __shared__ unsigned short Bs[128 * 32];
  const int t = threadIdx.x;
  const int l = t & 63;
  const int w = t >> 6;

  // T1: bijective XCD swizzle (all grids have nwg % 8 == 0)
  const int gx = gridDim.x;
  const int nwg = gx * gridDim.y;
  const int cpx = nwg >> 3;
  const int orig = blockIdx.y * gx + blockIdx.x;
  const int wgid = (orig & 7) * cpx + (orig >> 3);
  const int bx = wgid % gx;
  const int by = wgid / gx;

  const int m0 = by << 7;
  const int n0 = bx << 7;
  const int wr = (w >> 1) << 6;
  const int wc = (w & 1) << 6;
  const int koff = blockIdx.z * K;

  const unsigned short* Ab = A + (size_t)m0 * lda + koff;
  const unsigned short* Wb = W + (size_t)n0 * ldw + koff;

  f32x4 acc[4][4] = {};

  const int c0 = t, c1 = t + 256;
  const int ar0 = c0 >> 2, ak0 = (c0 & 3) * 8;
  const int ar1 = c1 >> 2, ak1 = (c1 & 3) * 8;
  const int lr = l & 15, lk = (l >> 4) * 8;

  for (int k0 = 0; k0 < K; k0 += 32) {
    gload_lds16(Ab + (size_t)ar0 * lda + k0 + ak0, &As[c0 * 8]);
    gload_lds16(Ab + (size_t)ar1 * lda + k0 + ak1, &As[c1 * 8]);
    gload_lds16(Wb + (size_t)ar0 * ldw + k0 + ak0, &Bs[c0 * 8]);
    gload_lds16(Wb + (size_t)ar1 * ldw + k0 + ak1, &Bs[c1 * 8]);
    __syncthreads();
    short8 a[4], b[4];
#pragma unroll
    for (int mi = 0; mi < 4; mi++)
      a[mi] = *(const short8*)&As[(wr + mi * 16 + lr) * 32 + lk];
#pragma unroll
    for (int ni = 0; ni < 4; ni++)
      b[ni] = *(const short8*)&Bs[(wc + ni * 16 + lr) * 32 + lk];
#pragma unroll
    for (int mi = 0; mi < 4; mi++)
#pragma unroll
      for (int ni = 0; ni < 4; ni++)
        acc[mi][ni] = __builtin_amdgcn_mfma_f32_16x16x32_bf16(
            a[mi], b[ni], acc[mi][ni], 0, 0, 0);
    __syncthreads();
  }

  const int lg = (l >> 4) * 4;
#pragma unroll
  for (int mi = 0; mi < 4; mi++) {
#pragma unroll
    for (int ni = 0; ni < 4; ni++) {
      int cn = n0 + wc + ni * 16 + lr;
      float bval = (MODE == 2) ? 0.0f : bias[cn];
#pragma unroll
      for (int j = 0; j < 4; j++) {
        int r = m0 + wr + mi * 16 + lg + j;
        float vv = acc[mi][ni][j] + bval;
        size_t idx = (size_t)r * N + cn;
        if (MODE == 1) {
          ((float*)outp)[idx] = vv + res[idx];
        } else if (MODE == 2) {
          ((float*)outp + blockIdx.z * out_zstride)[idx] = vv;
        } else {
          ((unsigned short*)outp)[idx] = f2b(vv);
        }
      }
    }
  }
}

// ---------------- V transpose: qkv v-slice -> vt[(bh*128+d)*S + s] -----------
__global__ __launch_bounds__(256)
void vtrans_kernel(const unsigned short* __restrict__ qkv,
                   unsigned short* __restrict__ vt) {
  const int bh = blockIdx.y;
  const int b = bh >> 4, h = bh & 15;
  const int s0 = blockIdx.x * 32;
  __shared__ unsigned short tile[32][136];
  const int t = threadIdx.x;
  for (int i = 0; i < 2; i++) {
    int c = t + i * 256;
    int s = c >> 4, dc = c & 15;
    *(short8*)&tile[s][dc * 8] =
        *(const short8*)(qkv + (size_t)(b * SEQ + s0 + s) * QKV_LD + 4096 +
                         h * HEAD_DIM + dc * 8);
  }
  __syncthreads();
  const int d = t >> 1, sh = (t & 1) * 16;
  unsigned short* dst = vt + ((size_t)bh * HEAD_DIM + d) * SEQ + s0 + sh;
  short8 r0, r1;
#pragma unroll
  for (int j = 0; j < 8; j++) r0[j] = tile[sh + j][d];
#pragma unroll
  for (int j = 0; j < 8; j++) r1[j] = tile[sh + 8 + j][d];
  *(short8*)dst = r0;
  *(short8*)(dst + 8) = r1;
}

// ---------------- Flash attention: direct-global K (no staging, no barriers) -
__global__ __launch_bounds__(256)
void attn_kernel(const unsigned short* __restrict__ qkv,
                 const unsigned short* __restrict__ vt,
                 unsigned short* __restrict__ o) {
  const int bh = blockIdx.y;
  const int b = bh >> 4, h = bh & 15;
  const int q0 = blockIdx.x << 6;
  const int t = threadIdx.x, w = t >> 6, l = t & 63;
  const int lr = l & 15, lg = l >> 4;

  __shared__ unsigned short Ps[4][16 * 64];  // per-wave P buffer (swizzled)

  short8 qf[4];
  {
    const unsigned short* qb =
        qkv + ((size_t)(b * SEQ + q0 + w * 16 + lr)) * QKV_LD + h * HEAD_DIM;
#pragma unroll
    for (int ks = 0; ks < 4; ks++) qf[ks] = *(const short8*)(qb + ks * 32 + lg * 8);
  }

  f32x4 oacc[8] = {};
  float mrow[4] = {-1e30f, -1e30f, -1e30f, -1e30f};
  float lrowv[4] = {0.f, 0.f, 0.f, 0.f};
  const float scl = 0.08838834764831845f;  // 1/sqrt(128)

  const unsigned short* kbase =
      qkv + (size_t)(b * SEQ) * QKV_LD + 2048 + h * HEAD_DIM;
  const unsigned short* vtb = vt + (size_t)bh * HEAD_DIM * SEQ;
  unsigned short* pw = &Ps[w][0];

  for (int kv0 = 0; kv0 < SEQ; kv0 += 64) {
    // S = Q @ K^T  (16 x 64 per wave), K fragments read direct from global/L2
    f32x4 s[4] = {};
#pragma unroll
    for (int nf = 0; nf < 4; nf++) {
      const unsigned short* krow = kbase + (size_t)(kv0 + nf * 16 + lr) * QKV_LD;
#pragma unroll
      for (int ks = 0; ks < 4; ks++) {
        short8 kf = *(const short8*)(krow + ks * 32 + lg * 8);
        s[nf] = __builtin_amdgcn_mfma_f32_16x16x32_bf16(qf[ks], kf, s[nf], 0, 0, 0);
      }
    }

    float pm[4];
#pragma unroll
    for (int j = 0; j < 4; j++) {
      float mx = -1e30f;
#pragma unroll
      for (int nf = 0; nf < 4; nf++) {
        s[nf][j] *= scl;
        mx = fmaxf(mx, s[nf][j]);
      }
      mx = fmaxf(mx, __shfl_xor(mx, 1));
      mx = fmaxf(mx, __shfl_xor(mx, 2));
      mx = fmaxf(mx, __shfl_xor(mx, 4));
      mx = fmaxf(mx, __shfl_xor(mx, 8));
      pm[j] = mx;
    }
    float fs[4];
#pragma unroll
    for (int j = 0; j < 4; j++) {
      float mn = fmaxf(mrow[j], pm[j]);
      fs[j] = __expf(mrow[j] - mn);
      mrow[j] = mn;
    }
    float rs[4] = {0.f, 0.f, 0.f, 0.f};
#pragma unroll
    for (int nf = 0; nf < 4; nf++)
#pragma unroll
      for (int j = 0; j < 4; j++) {
        float p = __expf(s[nf][j] - mrow[j]);
        s[nf][j] = p;
        rs[j] += p;
      }
#pragma unroll
    for (int j = 0; j < 4; j++) {
      float r = rs[j];
      r += __shfl_xor(r, 1);
      r += __shfl_xor(r, 2);
      r += __shfl_xor(r, 4);
      r += __shfl_xor(r, 8);
      lrowv[j] = lrowv[j] * fs[j] + r;
    }
#pragma unroll
    for (int nf = 0; nf < 8; nf++)
#pragma unroll
      for (int j = 0; j < 4; j++) oacc[nf][j] *= fs[j];

    // P -> per-wave LDS (bf16, swizzled), then PV
#pragma unroll
    for (int nf = 0; nf < 4; nf++)
#pragma unroll
      for (int j = 0; j < 4; j++) {
        int row = lg * 4 + j, col = nf * 16 + lr;
        int byo = ((row * 128 + col * 2) ^ ((row & 7) << 4));
        *(unsigned short*)((char*)pw + byo) = f2b(s[nf][j]);
      }
    asm volatile("s_waitcnt lgkmcnt(0)" ::: "memory");
    __builtin_amdgcn_sched_barrier(0);
#pragma unroll
    for (int ks = 0; ks < 2; ks++) {
      int byo = ((lr * 128 + ks * 64 + lg * 16) ^ ((lr & 7) << 4));
      short8 pa = *(const short8*)((char*)pw + byo);
#pragma unroll
      for (int nf = 0; nf < 8; nf++) {
        short8 vf = *(const short8*)(vtb + (size_t)(nf * 16 + lr) * SEQ + kv0 +
                                     ks * 32 + lg * 8);
        oacc[nf] = __builtin_amdgcn_mfma_f32_16x16x32_bf16(pa, vf, oacc[nf], 0, 0, 0);
      }
    }
  }

  unsigned short* ob =
      o + ((size_t)(b * SEQ + q0 + w * 16)) * D_MODEL + h * HEAD_DIM;
#pragma unroll
  for (int j = 0; j < 4; j++) {
    float inv = 1.0f / lrowv[j];
    int row = lg * 4 + j;
#pragma unroll
    for (int nf = 0; nf < 8; nf++) {
      int col = nf * 16 + lr;
      ob[(size_t)row * D_MODEL + col] = f2b(oacc[nf][j] * inv);
    }
  }
}

// ---------------- SwiGLU in-place on g (row stride 16384) --------------------
__global__ __launch_bounds__(256)
void swiglu_kernel(unsigned short* __restrict__ g) {
  size_t i = (size_t)blockIdx.x * 256 + threadIdx.x;
  size_t m = i >> 10, jc = i & 1023;
  unsigned short* p1 = g + m * (2 * D_FF) + jc * 8;
  short8 aa = *(short8*)p1;
  short8 bb = *(short8*)(p1 + D_FF);
  short8 r;
#pragma unroll
  for (int jj = 0; jj < 8; jj++) {
    float x1 = b2f((unsigned short)aa[jj]);
    float x2 = b2f((unsigned short)bb[jj]);
    float sg = x2 / (1.0f + __expf(-x2));
    r[jj] = f2b(x1 * sg);
  }
  *(short8*)p1 = r;
}

// ---------------- split-K reduce: out += p0 + p1 + b2 ------------------------
__global__ __launch_bounds__(256)
void reduce2_kernel(const float* __restrict__ p0, const float* __restrict__ p1,
                    const float* __restrict__ b2, float* __restrict__ out) {
  size_t i = (size_t)blockIdx.x * 256 + threadIdx.x;  // float4 index
  float4 a = ((const float4*)p0)[i];
  float4 b = ((const float4*)p1)[i];
  float4 o = ((const float4*)out)[i];
  float4 bb = ((const float4*)b2)[i & 511];
  o.x += a.x + b.x + bb.x;
  o.y += a.y + b.y + bb.y;
  o.z += a.z + b.z + bb.z;
  o.w += a.w + b.w + bb.w;
  ((float4*)out)[i] = o;
}

// ---------------- host: launch sequence --------------------------------------
extern "C" void kernel_launch(void* const* d_in, const int* in_sizes, int n_in,
                              void* d_out, int out_size, void* d_ws,
                              size_t ws_size, hipStream_t stream) {
  (void)in_sizes; (void)n_in; (void)out_size; (void)ws_size;
  const float* x   = (const float*)d_in[0];
  const float* Wq  = (const float*)d_in[1];
  const float* bq  = (const float*)d_in[2];
  const float* Wk  = (const float*)d_in[3];
  const float* bk  = (const float*)d_in[4];
  const float* Wv  = (const float*)d_in[5];
  const float* bv  = (const float*)d_in[6];
  const float* Wo  = (const float*)d_in[7];
  const float* bo  = (const float*)d_in[8];
  const float* rot = (const float*)d_in[9];
  const float* n1w = (const float*)d_in[10];
  const float* n2w = (const float*)d_in[11];
  const float* W1  = (const float*)d_in[12];
  const float* b1  = (const float*)d_in[13];
  const float* W2  = (const float*)d_in[14];
  const float* b2  = (const float*)d_in[15];
  float* out = (float*)d_out;
  char* ws = (char*)d_ws;

  const size_t SZ_D2  = (size_t)D_MODEL * D_MODEL * 2;   // 8 MiB
  const size_t SZ_ACT = (size_t)M_TOK * D_MODEL * 2;     // 16 MiB
  const size_t SZ_W1  = (size_t)2 * D_FF * D_MODEL * 2;  // 64 MiB
  const size_t SZ_W2  = (size_t)D_MODEL * D_FF * 2;      // 32 MiB
  const size_t SZ_G   = (size_t)M_TOK * 2 * D_FF * 2;    // 128 MiB

  size_t off = 0;
  auto alloc = [&](size_t sz) { size_t o = off; off += (sz + 255) & ~(size_t)255; return o; };
  unsigned short* wqkv_b = (unsigned short*)(ws + alloc(3 * SZ_D2));  // at ws+0
  unsigned short* wo_b   = (unsigned short*)(ws + alloc(SZ_D2));
  unsigned short* w1_b   = (unsigned short*)(ws + alloc(SZ_W1));
  unsigned short* w2_b   = (unsigned short*)(ws + alloc(SZ_W2));
  float*          biasq  = (float*)(ws + alloc(QKV_LD * 4));
  unsigned short* h2_b   = (unsigned short*)(ws + alloc(SZ_ACT));
  char* pool = ws + alloc(SZ_G);
  // phase 1 overlay in pool: h | qkv | vt | o   (16+48+16+16 = 96 MiB)
  unsigned short* h_b   = (unsigned short*)(pool);
  unsigned short* qkv_b = (unsigned short*)(pool + SZ_ACT);
  unsigned short* vt_b  = (unsigned short*)(pool + 4 * SZ_ACT);
  unsigned short* o_b   = (unsigned short*)(pool + 5 * SZ_ACT);
  // phase 2 overlay: g occupies whole pool
  unsigned short* g_b   = (unsigned short*)(pool);
  // split-K partials overlay the (then-dead) wqkv/wo/w1 region: 2x 32 MiB < 96 MiB
  float* p0 = (float*)ws;
  float* p1 = p0 + (size_t)M_TOK * D_MODEL;

  // weights -> bf16 (Q,K,V concatenated row-wise)
  cvt_kernel<<<1024, 256, 0, stream>>>(Wq, wqkv_b, D_MODEL * D_MODEL / 8);
  cvt_kernel<<<1024, 256, 0, stream>>>(Wk, wqkv_b + (size_t)D_MODEL * D_MODEL, D_MODEL * D_MODEL / 8);
  cvt_kernel<<<1024, 256, 0, stream>>>(Wv, wqkv_b + (size_t)2 * D_MODEL * D_MODEL, D_MODEL * D_MODEL / 8);
  cvt_kernel<<<1024, 256, 0, stream>>>(Wo, wo_b, D_MODEL * D_MODEL / 8);
  cvt_kernel<<<2048, 256, 0, stream>>>(W1, w1_b, 2 * D_FF * D_MODEL / 8);
  cvt_kernel<<<2048, 256, 0, stream>>>(W2, w2_b, D_MODEL * D_FF / 8);
  biasqkv_kernel<<<QKV_LD / 256, 256, 0, stream>>>(bq, bk, bv, rot, biasq);

  // norm1 -> h
  rmsnorm_kernel<<<M_TOK, 256, 0, stream>>>(x, n1w, h_b);

  // fused QKV projection: [4096,2048] @ [6144,2048]^T -> [4096,6144]
  gemm_bt<0><<<dim3(QKV_LD / 128, M_TOK / 128), 256, 0, stream>>>(
      h_b, D_MODEL, wqkv_b, D_MODEL, biasq, nullptr, qkv_b, QKV_LD, D_MODEL, 0);

  // V transpose + attention
  vtrans_kernel<<<dim3(SEQ / 32, BATCH * N_HEADS), 256, 0, stream>>>(qkv_b, vt_b);
  attn_kernel<<<dim3(SEQ / 64, BATCH * N_HEADS), 256, 0, stream>>>(qkv_b, vt_b, o_b);

  // O projection + residual -> d_out (f32)
  gemm_bt<1><<<dim3(D_MODEL / 128, M_TOK / 128), 256, 0, stream>>>(
      o_b, D_MODEL, wo_b, D_MODEL, bo, x, out, D_MODEL, D_MODEL, 0);

  // norm2 -> h2
  rmsnorm_kernel<<<M_TOK, 256, 0, stream>>>(out, n2w, h2_b);

  // W1 -> g (bf16, 4096 x 16384)
  gemm_bt<0><<<dim3(2 * D_FF / 128, M_TOK / 128), 256, 0, stream>>>(
      h2_b, D_MODEL, w1_b, D_MODEL, b1, nullptr, g_b, 2 * D_FF, D_MODEL, 0);

  // SwiGLU in-place
  swiglu_kernel<<<(M_TOK * D_FF / 8) / 256, 256, 0, stream>>>(g_b);

  // W2 split-K (z=0: K 0..4095, z=1: K 4096..8191) -> partials
  gemm_bt<2><<<dim3(D_MODEL / 128, M_TOK / 128, 2), 256, 0, stream>>>(
      g_b, 2 * D_FF, w2_b, D_FF, nullptr, nullptr, p0, D_MODEL, D_FF / 2,
      (size_t)M_TOK * D_MODEL);

  // out += p0 + p1 + b2
  reduce2_kernel<<<(M_TOK * D_MODEL / 4) / 256, 256, 0, stream>>>(p0, p1, b2, out);
}

// Round 4
// 1305.078 us; speedup vs baseline: 2.2498x; 1.0915x over previous
//
#include <hip/hip_runtime.h>
#include <hip/hip_bf16.h>

#define D_MODEL 2048
#define N_HEADS 16
#define HEAD_DIM 128
#define D_FF 8192
#define BATCH 2
#define SEQ 2048
#define M_TOK (BATCH * SEQ)
#define QKV_LD 6144

typedef __attribute__((ext_vector_type(8))) short short8;
typedef __attribute__((ext_vector_type(4))) float f32x4;

__device__ __forceinline__ unsigned short f2b(float f) {
  __hip_bfloat16 h = __float2bfloat16(f);
  return *reinterpret_cast<unsigned short*>(&h);
}
__device__ __forceinline__ float b2f(unsigned short u) {
  unsigned int x = ((unsigned int)u) << 16;
  return __uint_as_float(x);
}

__device__ __forceinline__ void gload_lds16(const void* gsrc, void* ldst) {
  __builtin_amdgcn_global_load_lds(
      (const __attribute__((address_space(1))) void*)gsrc,
      (__attribute__((address_space(3))) void*)ldst, 16, 0, 0);
}

// ---------------- f32 -> bf16 convert (grid-stride, 8 elems/thread) ----------
__global__ __launch_bounds__(256)
void cvt_kernel(const float* __restrict__ src, unsigned short* __restrict__ dst,
                int nchunks) {
  int i = blockIdx.x * blockDim.x + threadIdx.x;
  int stride = gridDim.x * blockDim.x;
  for (int c = i; c < nchunks; c += stride) {
    const float4 a = *(const float4*)(src + (size_t)c * 8);
    const float4 b = *(const float4*)(src + (size_t)c * 8 + 4);
    short8 r;
    r[0] = f2b(a.x); r[1] = f2b(a.y); r[2] = f2b(a.z); r[3] = f2b(a.w);
    r[4] = f2b(b.x); r[5] = f2b(b.y); r[6] = f2b(b.z); r[7] = f2b(b.w);
    *(short8*)(dst + (size_t)c * 8) = r;
  }
}

// ---------------- concat bias: [bq+rot | bk | bv] ----------------------------
__global__ void biasqkv_kernel(const float* __restrict__ bq,
                               const float* __restrict__ bk,
                               const float* __restrict__ bv,
                               const float* __restrict__ rot,
                               float* __restrict__ outp) {
  int i = blockIdx.x * 256 + threadIdx.x;
  float v;
  if (i < 2048) v = bq[i] + rot[i & (HEAD_DIM - 1)];
  else if (i < 4096) v = bk[i - 2048];
  else v = bv[i - 4096];
  outp[i] = v;
}

// ---------------- RMSNorm: f32 in -> bf16 out, one block per row -------------
__global__ __launch_bounds__(256)
void rmsnorm_kernel(const float* __restrict__ x, const float* __restrict__ wv,
                    unsigned short* __restrict__ outp) {
  const int row = blockIdx.x;
  const float* xr = x + (size_t)row * D_MODEL;
  const int base = threadIdx.x * 8;
  float4 a = *(const float4*)(xr + base);
  float4 c = *(const float4*)(xr + base + 4);
  float ss = a.x * a.x + a.y * a.y + a.z * a.z + a.w * a.w +
             c.x * c.x + c.y * c.y + c.z * c.z + c.w * c.w;
#pragma unroll
  for (int m = 1; m < 64; m <<= 1) ss += __shfl_xor(ss, m);
  __shared__ float red[4];
  if ((threadIdx.x & 63) == 0) red[threadIdx.x >> 6] = ss;
  __syncthreads();
  float tot = red[0] + red[1] + red[2] + red[3];
  float sc = rsqrtf(tot * (1.0f / D_MODEL) + 1e-8f);
  float4 w0 = *(const float4*)(wv + base);
  float4 w1 = *(const float4*)(wv + base + 4);
  short8 r;
  r[0] = f2b(a.x * sc * w0.x); r[1] = f2b(a.y * sc * w0.y);
  r[2] = f2b(a.z * sc * w0.z); r[3] = f2b(a.w * sc * w0.w);
  r[4] = f2b(c.x * sc * w1.x); r[5] = f2b(c.y * sc * w1.y);
  r[6] = f2b(c.z * sc * w1.z); r[7] = f2b(c.w * sc * w1.w);
  *(short8*)(outp + (size_t)row * D_MODEL + base) = r;
}

// ---------------- GEMM 128x128 (proven m97 structure) + T1 XCD swizzle -------
// C[M,N] = A[M, koff:koff+K] @ W[N, koff:koff+K]^T  (koff = blockIdx.z * K)
// MODE 0: bf16 out + bias.  MODE 1: f32 out + bias + res.  MODE 2: raw f32 out.
template <int MODE>
__global__ __launch_bounds__(256)
void gemm_bt(const unsigned short* __restrict__ A, int lda,
             const unsigned short* __restrict__ W, int ldw,
             const float* __restrict__ bias, const float* res, void* outp,
             int N, int K, size_t out_zstride) {
  __shared__ unsigned short As[128 * 32];
  __shared__ unsigned short Bs[128 * 32];
  const int t = threadIdx.x;
  const int l = t & 63;
  const int w = t >> 6;

  // T1: bijective XCD swizzle (all grids have nwg % 8 == 0)
  const int gx = gridDim.x;
  const int nwg = gx * gridDim.y;
  const int cpx = nwg >> 3;
  const int orig = blockIdx.y * gx + blockIdx.x;
  const int wgid = (orig & 7) * cpx + (orig >> 3);
  const int bx = wgid % gx;
  const int by = wgid / gx;

  const int m0 = by << 7;
  const int n0 = bx << 7;
  const int wr = (w >> 1) << 6;
  const int wc = (w & 1) << 6;
  const int koff = blockIdx.z * K;

  const unsigned short* Ab = A + (size_t)m0 * lda + koff;
  const unsigned short* Wb = W + (size_t)n0 * ldw + koff;

  f32x4 acc[4][4] = {};

  const int c0 = t, c1 = t + 256;
  const int ar0 = c0 >> 2, ak0 = (c0 & 3) * 8;
  const int ar1 = c1 >> 2, ak1 = (c1 & 3) * 8;
  const int lr = l & 15, lk = (l >> 4) * 8;

  for (int k0 = 0; k0 < K; k0 += 32) {
    gload_lds16(Ab + (size_t)ar0 * lda + k0 + ak0, &As[c0 * 8]);
    gload_lds16(Ab + (size_t)ar1 * lda + k0 + ak1, &As[c1 * 8]);
    gload_lds16(Wb + (size_t)ar0 * ldw + k0 + ak0, &Bs[c0 * 8]);
    gload_lds16(Wb + (size_t)ar1 * ldw + k0 + ak1, &Bs[c1 * 8]);
    __syncthreads();
    short8 a[4], b[4];
#pragma unroll
    for (int mi = 0; mi < 4; mi++)
      a[mi] = *(const short8*)&As[(wr + mi * 16 + lr) * 32 + lk];
#pragma unroll
    for (int ni = 0; ni < 4; ni++)
      b[ni] = *(const short8*)&Bs[(wc + ni * 16 + lr) * 32 + lk];
#pragma unroll
    for (int mi = 0; mi < 4; mi++)
#pragma unroll
      for (int ni = 0; ni < 4; ni++)
        acc[mi][ni] = __builtin_amdgcn_mfma_f32_16x16x32_bf16(
            a[mi], b[ni], acc[mi][ni], 0, 0, 0);
    __syncthreads();
  }

  const int lg = (l >> 4) * 4;
#pragma unroll
  for (int mi = 0; mi < 4; mi++) {
#pragma unroll
    for (int ni = 0; ni < 4; ni++) {
      int cn = n0 + wc + ni * 16 + lr;
      float bval = (MODE == 2) ? 0.0f : bias[cn];
#pragma unroll
      for (int j = 0; j < 4; j++) {
        int r = m0 + wr + mi * 16 + lg + j;
        float vv = acc[mi][ni][j] + bval;
        size_t idx = (size_t)r * N + cn;
        if (MODE == 1) {
          ((float*)outp)[idx] = vv + res[idx];
        } else if (MODE == 2) {
          ((float*)outp + blockIdx.z * out_zstride)[idx] = vv;
        } else {
          ((unsigned short*)outp)[idx] = f2b(vv);
        }
      }
    }
  }
}

// ---------------- V transpose: qkv v-slice -> vt[(bh*128+d)*S + s] -----------
__global__ __launch_bounds__(256)
void vtrans_kernel(const unsigned short* __restrict__ qkv,
                   unsigned short* __restrict__ vt) {
  const int bh = blockIdx.y;
  const int b = bh >> 4, h = bh & 15;
  const int s0 = blockIdx.x * 32;
  __shared__ unsigned short tile[32][136];
  const int t = threadIdx.x;
  for (int i = 0; i < 2; i++) {
    int c = t + i * 256;
    int s = c >> 4, dc = c & 15;
    *(short8*)&tile[s][dc * 8] =
        *(const short8*)(qkv + (size_t)(b * SEQ + s0 + s) * QKV_LD + 4096 +
                         h * HEAD_DIM + dc * 8);
  }
  __syncthreads();
  const int d = t >> 1, sh = (t & 1) * 16;
  unsigned short* dst = vt + ((size_t)bh * HEAD_DIM + d) * SEQ + s0 + sh;
  short8 r0, r1;
#pragma unroll
  for (int j = 0; j < 8; j++) r0[j] = tile[sh + j][d];
#pragma unroll
  for (int j = 0; j < 8; j++) r1[j] = tile[sh + 8 + j][d];
  *(short8*)dst = r0;
  *(short8*)(dst + 8) = r1;
}

// ---------------- Flash attention: async double-buffered K staging -----------
// K staged via global_load_lds: linear LDS dest + pre-swizzled global source
// (rule 21 / m173); reads use byte ^= (row&7)<<4. One barrier per KV tile;
// stage of tile t+1 issues at top of iter t, drains in the bottom syncthreads.
__global__ __launch_bounds__(256)
void attn_kernel(const unsigned short* __restrict__ qkv,
                 const unsigned short* __restrict__ vt,
                 unsigned short* __restrict__ o) {
  const int bh = blockIdx.y;
  const int b = bh >> 4, h = bh & 15;
  const int q0 = blockIdx.x << 6;
  const int t = threadIdx.x, w = t >> 6, l = t & 63;
  const int lr = l & 15, lg = l >> 4;

  __shared__ unsigned short Ks[2][64 * 128];  // XOR-swizzled content
  __shared__ unsigned short Ps[4][16 * 64];   // per-wave P buffer (swizzled)

  short8 qf[4];
  {
    const unsigned short* qb =
        qkv + ((size_t)(b * SEQ + q0 + w * 16 + lr)) * QKV_LD + h * HEAD_DIM;
#pragma unroll
    for (int ks = 0; ks < 4; ks++) qf[ks] = *(const short8*)(qb + ks * 32 + lg * 8);
  }

  f32x4 oacc[8] = {};
  float mrow[4] = {-1e30f, -1e30f, -1e30f, -1e30f};
  float lrowv[4] = {0.f, 0.f, 0.f, 0.f};
  const float scl = 0.08838834764831845f;  // 1/sqrt(128)

  const unsigned short* kbase =
      qkv + (size_t)(b * SEQ) * QKV_LD + 2048 + h * HEAD_DIM;
  const unsigned short* vtb = vt + (size_t)bh * HEAD_DIM * SEQ;
  unsigned short* pw = &Ps[w][0];

  // staging geometry: chunk c = t + i*256 (16B chunks), row=c>>4, dc=c&15.
  // LDS linear dest byte c*16 must hold global byte-col (dc*16)^((row&7)<<4).
#define STAGEK(buf, kv0_)                                                     \
  do {                                                                        \
    _Pragma("unroll")                                                         \
    for (int i_ = 0; i_ < 4; i_++) {                                          \
      int c_ = t + i_ * 256;                                                  \
      int row_ = c_ >> 4, dc_ = c_ & 15;                                      \
      int sel_ = ((dc_ * 16) ^ ((row_ & 7) << 4)) >> 1;                       \
      gload_lds16(kbase + (size_t)((kv0_) + row_) * QKV_LD + sel_,            \
                  &Ks[buf][c_ * 8]);                                          \
    }                                                                         \
  } while (0)

  STAGEK(0, 0);
  __syncthreads();

  for (int it = 0; it < SEQ / 64; ++it) {
    const int cur = it & 1;
    const int kv0 = it * 64;
    if (it + 1 < SEQ / 64) STAGEK(cur ^ 1, kv0 + 64);

    // S = Q @ K^T  (16 x 64 per wave) from swizzled LDS
    const char* kb = (const char*)&Ks[cur][0];
    f32x4 s[4] = {};
#pragma unroll
    for (int nf = 0; nf < 4; nf++) {
      int key = nf * 16 + lr;
#pragma unroll
      for (int ks = 0; ks < 4; ks++) {
        int byo = ((key * 256 + ks * 64 + lg * 16) ^ ((key & 7) << 4));
        short8 kf = *(const short8*)(kb + byo);
        s[nf] = __builtin_amdgcn_mfma_f32_16x16x32_bf16(qf[ks], kf, s[nf], 0, 0, 0);
      }
    }

    // online softmax (rows = lg*4 + j, cols spread over lanes lr & frags)
    float pm[4];
#pragma unroll
    for (int j = 0; j < 4; j++) {
      float mx = -1e30f;
#pragma unroll
      for (int nf = 0; nf < 4; nf++) {
        s[nf][j] *= scl;
        mx = fmaxf(mx, s[nf][j]);
      }
      mx = fmaxf(mx, __shfl_xor(mx, 1));
      mx = fmaxf(mx, __shfl_xor(mx, 2));
      mx = fmaxf(mx, __shfl_xor(mx, 4));
      mx = fmaxf(mx, __shfl_xor(mx, 8));
      pm[j] = mx;
    }
    float fs[4];
#pragma unroll
    for (int j = 0; j < 4; j++) {
      float mn = fmaxf(mrow[j], pm[j]);
      fs[j] = __expf(mrow[j] - mn);
      mrow[j] = mn;
    }
    float rs[4] = {0.f, 0.f, 0.f, 0.f};
#pragma unroll
    for (int nf = 0; nf < 4; nf++)
#pragma unroll
      for (int j = 0; j < 4; j++) {
        float p = __expf(s[nf][j] - mrow[j]);
        s[nf][j] = p;
        rs[j] += p;
      }
#pragma unroll
    for (int j = 0; j < 4; j++) {
      float r = rs[j];
      r += __shfl_xor(r, 1);
      r += __shfl_xor(r, 2);
      r += __shfl_xor(r, 4);
      r += __shfl_xor(r, 8);
      lrowv[j] = lrowv[j] * fs[j] + r;
    }
#pragma unroll
    for (int nf = 0; nf < 8; nf++)
#pragma unroll
      for (int j = 0; j < 4; j++) oacc[nf][j] *= fs[j];

    // P -> per-wave LDS (bf16, swizzled), then PV (V direct from global/L2)
#pragma unroll
    for (int nf = 0; nf < 4; nf++)
#pragma unroll
      for (int j = 0; j < 4; j++) {
        int row = lg * 4 + j, col = nf * 16 + lr;
        int byo = ((row * 128 + col * 2) ^ ((row & 7) << 4));
        *(unsigned short*)((char*)pw + byo) = f2b(s[nf][j]);
      }
    asm volatile("s_waitcnt lgkmcnt(0)" ::: "memory");
    __builtin_amdgcn_sched_barrier(0);
#pragma unroll
    for (int ks = 0; ks < 2; ks++) {
      int byo = ((lr * 128 + ks * 64 + lg * 16) ^ ((lr & 7) << 4));
      short8 pa = *(const short8*)((char*)pw + byo);
#pragma unroll
      for (int nf = 0; nf < 8; nf++) {
        short8 vf = *(const short8*)(vtb + (size_t)(nf * 16 + lr) * SEQ + kv0 +
                                     ks * 32 + lg * 8);
        oacc[nf] = __builtin_amdgcn_mfma_f32_16x16x32_bf16(pa, vf, oacc[nf], 0, 0, 0);
      }
    }
    __syncthreads();  // drains the K stage (vmcnt 0) + protects buffers
  }
#undef STAGEK

  unsigned short* ob =
      o + ((size_t)(b * SEQ + q0 + w * 16)) * D_MODEL + h * HEAD_DIM;
#pragma unroll
  for (int j = 0; j < 4; j++) {
    float inv = 1.0f / lrowv[j];
    int row = lg * 4 + j;
#pragma unroll
    for (int nf = 0; nf < 8; nf++) {
      int col = nf * 16 + lr;
      ob[(size_t)row * D_MODEL + col] = f2b(oacc[nf][j] * inv);
    }
  }
}

// ---------------- SwiGLU in-place on g (row stride 16384) --------------------
__global__ __launch_bounds__(256)
void swiglu_kernel(unsigned short* __restrict__ g) {
  size_t i = (size_t)blockIdx.x * 256 + threadIdx.x;
  size_t m = i >> 10, jc = i & 1023;
  unsigned short* p1 = g + m * (2 * D_FF) + jc * 8;
  short8 aa = *(short8*)p1;
  short8 bb = *(short8*)(p1 + D_FF);
  short8 r;
#pragma unroll
  for (int jj = 0; jj < 8; jj++) {
    float x1 = b2f((unsigned short)aa[jj]);
    float x2 = b2f((unsigned short)bb[jj]);
    float sg = x2 / (1.0f + __expf(-x2));
    r[jj] = f2b(x1 * sg);
  }
  *(short8*)p1 = r;
}

// ---------------- split-K reduce: out += p0 + p1 + b2 ------------------------
__global__ __launch_bounds__(256)
void reduce2_kernel(const float* __restrict__ p0, const float* __restrict__ p1,
                    const float* __restrict__ b2, float* __restrict__ out) {
  size_t i = (size_t)blockIdx.x * 256 + threadIdx.x;  // float4 index
  float4 a = ((const float4*)p0)[i];
  float4 b = ((const float4*)p1)[i];
  float4 o = ((const float4*)out)[i];
  float4 bb = ((const float4*)b2)[i & 511];
  o.x += a.x + b.x + bb.x;
  o.y += a.y + b.y + bb.y;
  o.z += a.z + b.z + bb.z;
  o.w += a.w + b.w + bb.w;
  ((float4*)out)[i] = o;
}

// ---------------- host: launch sequence --------------------------------------
extern "C" void kernel_launch(void* const* d_in, const int* in_sizes, int n_in,
                              void* d_out, int out_size, void* d_ws,
                              size_t ws_size, hipStream_t stream) {
  (void)in_sizes; (void)n_in; (void)out_size; (void)ws_size;
  const float* x   = (const float*)d_in[0];
  const float* Wq  = (const float*)d_in[1];
  const float* bq  = (const float*)d_in[2];
  const float* Wk  = (const float*)d_in[3];
  const float* bk  = (const float*)d_in[4];
  const float* Wv  = (const float*)d_in[5];
  const float* bv  = (const float*)d_in[6];
  const float* Wo  = (const float*)d_in[7];
  const float* bo  = (const float*)d_in[8];
  const float* rot = (const float*)d_in[9];
  const float* n1w = (const float*)d_in[10];
  const float* n2w = (const float*)d_in[11];
  const float* W1  = (const float*)d_in[12];
  const float* b1  = (const float*)d_in[13];
  const float* W2  = (const float*)d_in[14];
  const float* b2  = (const float*)d_in[15];
  float* out = (float*)d_out;
  char* ws = (char*)d_ws;

  const size_t SZ_D2  = (size_t)D_MODEL * D_MODEL * 2;   // 8 MiB
  const size_t SZ_ACT = (size_t)M_TOK * D_MODEL * 2;     // 16 MiB
  const size_t SZ_W1  = (size_t)2 * D_FF * D_MODEL * 2;  // 64 MiB
  const size_t SZ_W2  = (size_t)D_MODEL * D_FF * 2;      // 32 MiB
  const size_t SZ_G   = (size_t)M_TOK * 2 * D_FF * 2;    // 128 MiB

  size_t off = 0;
  auto alloc = [&](size_t sz) { size_t o = off; off += (sz + 255) & ~(size_t)255; return o; };
  unsigned short* wqkv_b = (unsigned short*)(ws + alloc(3 * SZ_D2));  // at ws+0
  unsigned short* wo_b   = (unsigned short*)(ws + alloc(SZ_D2));
  unsigned short* w1_b   = (unsigned short*)(ws + alloc(SZ_W1));
  unsigned short* w2_b   = (unsigned short*)(ws + alloc(SZ_W2));
  float*          biasq  = (float*)(ws + alloc(QKV_LD * 4));
  unsigned short* h2_b   = (unsigned short*)(ws + alloc(SZ_ACT));
  char* pool = ws + alloc(SZ_G);
  // phase 1 overlay in pool: h | qkv | vt | o   (16+48+16+16 = 96 MiB)
  unsigned short* h_b   = (unsigned short*)(pool);
  unsigned short* qkv_b = (unsigned short*)(pool + SZ_ACT);
  unsigned short* vt_b  = (unsigned short*)(pool + 4 * SZ_ACT);
  unsigned short* o_b   = (unsigned short*)(pool + 5 * SZ_ACT);
  // phase 2 overlay: g occupies whole pool
  unsigned short* g_b   = (unsigned short*)(pool);
  // split-K partials overlay the (then-dead) wqkv/wo/w1 region: 2x 32 MiB < 96 MiB
  float* p0 = (float*)ws;
  float* p1 = p0 + (size_t)M_TOK * D_MODEL;

  // weights -> bf16 (Q,K,V concatenated row-wise)
  cvt_kernel<<<1024, 256, 0, stream>>>(Wq, wqkv_b, D_MODEL * D_MODEL / 8);
  cvt_kernel<<<1024, 256, 0, stream>>>(Wk, wqkv_b + (size_t)D_MODEL * D_MODEL, D_MODEL * D_MODEL / 8);
  cvt_kernel<<<1024, 256, 0, stream>>>(Wv, wqkv_b + (size_t)2 * D_MODEL * D_MODEL, D_MODEL * D_MODEL / 8);
  cvt_kernel<<<1024, 256, 0, stream>>>(Wo, wo_b, D_MODEL * D_MODEL / 8);
  cvt_kernel<<<2048, 256, 0, stream>>>(W1, w1_b, 2 * D_FF * D_MODEL / 8);
  cvt_kernel<<<2048, 256, 0, stream>>>(W2, w2_b, D_MODEL * D_FF / 8);
  biasqkv_kernel<<<QKV_LD / 256, 256, 0, stream>>>(bq, bk, bv, rot, biasq);

  // norm1 -> h
  rmsnorm_kernel<<<M_TOK, 256, 0, stream>>>(x, n1w, h_b);

  // fused QKV projection: [4096,2048] @ [6144,2048]^T -> [4096,6144]
  gemm_bt<0><<<dim3(QKV_LD / 128, M_TOK / 128), 256, 0, stream>>>(
      h_b, D_MODEL, wqkv_b, D_MODEL, biasq, nullptr, qkv_b, QKV_LD, D_MODEL, 0);

  // V transpose + attention
  vtrans_kernel<<<dim3(SEQ / 32, BATCH * N_HEADS), 256, 0, stream>>>(qkv_b, vt_b);
  attn_kernel<<<dim3(SEQ / 64, BATCH * N_HEADS), 256, 0, stream>>>(qkv_b, vt_b, o_b);

  // O projection + residual -> d_out (f32)
  gemm_bt<1><<<dim3(D_MODEL / 128, M_TOK / 128), 256, 0, stream>>>(
      o_b, D_MODEL, wo_b, D_MODEL, bo, x, out, D_MODEL, D_MODEL, 0);

  // norm2 -> h2
  rmsnorm_kernel<<<M_TOK, 256, 0, stream>>>(out, n2w, h2_b);

  // W1 -> g (bf16, 4096 x 16384)
  gemm_bt<0><<<dim3(2 * D_FF / 128, M_TOK / 128), 256, 0, stream>>>(
      h2_b, D_MODEL, w1_b, D_MODEL, b1, nullptr, g_b, 2 * D_FF, D_MODEL, 0);

  // SwiGLU in-place
  swiglu_kernel<<<(M_TOK * D_FF / 8) / 256, 256, 0, stream>>>(g_b);

  // W2 split-K (z=0: K 0..4095, z=1: K 4096..8191) -> partials
  gemm_bt<2><<<dim3(D_MODEL / 128, M_TOK / 128, 2), 256, 0, stream>>>(
      g_b, 2 * D_FF, w2_b, D_FF, nullptr, nullptr, p0, D_MODEL, D_FF / 2,
      (size_t)M_TOK * D_MODEL);

  // out += p0 + p1 + b2
  reduce2_kernel<<<(M_TOK * D_MODEL / 4) / 256, 256, 0, stream>>>(p0, p1, b2, out);
}

// Round 5
// 1251.107 us; speedup vs baseline: 2.3469x; 1.0431x over previous
//
#include <hip/hip_runtime.h>
#include <hip/hip_bf16.h>

#define D_MODEL 2048
#define N_HEADS 16
#define HEAD_DIM 128
#define D_FF 8192
#define BATCH 2
#define SEQ 2048
#define M_TOK (BATCH * SEQ)
#define QKV_LD 6144

typedef __attribute__((ext_vector_type(8))) short short8;
typedef __attribute__((ext_vector_type(4))) float f32x4;

__device__ __forceinline__ unsigned short f2b(float f) {
  __hip_bfloat16 h = __float2bfloat16(f);
  return *reinterpret_cast<unsigned short*>(&h);
}
__device__ __forceinline__ float b2f(unsigned short u) {
  unsigned int x = ((unsigned int)u) << 16;
  return __uint_as_float(x);
}

__device__ __forceinline__ void gload_lds16(const void* gsrc, void* ldst) {
  __builtin_amdgcn_global_load_lds(
      (const __attribute__((address_space(1))) void*)gsrc,
      (__attribute__((address_space(3))) void*)ldst, 16, 0, 0);
}

// ---------------- f32 -> bf16 convert ----------------------------------------
__global__ __launch_bounds__(256)
void cvt_kernel(const float* __restrict__ src, unsigned short* __restrict__ dst,
                int nchunks) {
  int i = blockIdx.x * blockDim.x + threadIdx.x;
  int stride = gridDim.x * blockDim.x;
  for (int c = i; c < nchunks; c += stride) {
    const float4 a = *(const float4*)(src + (size_t)c * 8);
    const float4 b = *(const float4*)(src + (size_t)c * 8 + 4);
    short8 r;
    r[0] = f2b(a.x); r[1] = f2b(a.y); r[2] = f2b(a.z); r[3] = f2b(a.w);
    r[4] = f2b(b.x); r[5] = f2b(b.y); r[6] = f2b(b.z); r[7] = f2b(b.w);
    *(short8*)(dst + (size_t)c * 8) = r;
  }
}

// ---------------- concat bias: [bq+rot | bk | bv] ----------------------------
__global__ void biasqkv_kernel(const float* __restrict__ bq,
                               const float* __restrict__ bk,
                               const float* __restrict__ bv,
                               const float* __restrict__ rot,
                               float* __restrict__ outp) {
  int i = blockIdx.x * 256 + threadIdx.x;
  float v;
  if (i < 2048) v = bq[i] + rot[i & (HEAD_DIM - 1)];
  else if (i < 4096) v = bk[i - 2048];
  else v = bv[i - 4096];
  outp[i] = v;
}

// ---------------- RMSNorm: f32 in -> bf16 out --------------------------------
__global__ __launch_bounds__(256)
void rmsnorm_kernel(const float* __restrict__ x, const float* __restrict__ wv,
                    unsigned short* __restrict__ outp) {
  const int row = blockIdx.x;
  const float* xr = x + (size_t)row * D_MODEL;
  const int base = threadIdx.x * 8;
  float4 a = *(const float4*)(xr + base);
  float4 c = *(const float4*)(xr + base + 4);
  float ss = a.x * a.x + a.y * a.y + a.z * a.z + a.w * a.w +
             c.x * c.x + c.y * c.y + c.z * c.z + c.w * c.w;
#pragma unroll
  for (int m = 1; m < 64; m <<= 1) ss += __shfl_xor(ss, m);
  __shared__ float red[4];
  if ((threadIdx.x & 63) == 0) red[threadIdx.x >> 6] = ss;
  __syncthreads();
  float tot = red[0] + red[1] + red[2] + red[3];
  float sc = rsqrtf(tot * (1.0f / D_MODEL) + 1e-8f);
  float4 w0 = *(const float4*)(wv + base);
  float4 w1 = *(const float4*)(wv + base + 4);
  short8 r;
  r[0] = f2b(a.x * sc * w0.x); r[1] = f2b(a.y * sc * w0.y);
  r[2] = f2b(a.z * sc * w0.z); r[3] = f2b(a.w * sc * w0.w);
  r[4] = f2b(c.x * sc * w1.x); r[5] = f2b(c.y * sc * w1.y);
  r[6] = f2b(c.z * sc * w1.z); r[7] = f2b(c.w * sc * w1.w);
  *(short8*)(outp + (size_t)row * D_MODEL + base) = r;
}

// ============= GEMM 256x256, BK=64, 8-phase pipelined (T2+T3+T4+T5) ==========
// C[M,N] = A[M,K] @ W[N,K]^T + bias, bf16 out.
// 512 threads = 8 waves (2x4 within each 128x128 C-quadrant, 64x32 each).
// LDS: 4 slots per matrix: [dbuf][half] of [128 rows][64 k] bf16, 128 KiB.
// Phase = one C-quadrant x K=64: 12 ds_read_b128 + stage 1 half-tile + 16 MFMA.
// Stagger: ph0->B[d^1][1](kt+1), ph1->A[d^1][1](kt+1), ph2->A[d][0](kt+2),
//          ph3->B[d][0](kt+2) + vmcnt(4) verifying kt+1's four slots.
// XOR swizzle: LDS row byte ^= ((row&7)<<4); staged via pre-swizzled global
// source + linear LDS dest (rule 21), read back with the same XOR.
__global__ __launch_bounds__(512, 2)
void gemm_p8(const unsigned short* __restrict__ A, int lda,
             const unsigned short* __restrict__ W, int ldw,
             const float* __restrict__ bias, unsigned short* __restrict__ outp,
             int N, int K) {
  __shared__ unsigned short AL[2][2][128 * 64];
  __shared__ unsigned short BL[2][2][128 * 64];
  const int t = threadIdx.x;
  const int l = t & 63, w = t >> 6;
  const int wqm = w >> 2, wqn = w & 3;     // wave pos inside a quadrant
  const int lr = l & 15, lg = l >> 4;
  const int m0 = blockIdx.y << 8, n0 = blockIdx.x << 8;

  // staging geometry: half-tile = 128 rows x 64 k = 1024 16B-chunks.
  // thread t stages chunks t and t+512: rows r0 and r0+64, same col selector.
  const int r0 = t >> 3;
  const int cb = (t & 7) * 16;
  const int sel = ((cb ^ ((r0 & 7) << 4)) >> 1);  // pre-swizzled elem col
  const unsigned short* Abase = A + (size_t)m0 * lda;
  const unsigned short* Wbase = W + (size_t)n0 * ldw;
  const int d0e = t * 8, d1e = (t + 512) * 8;

#define STAGE(XL, Xb, ld, dd, h, ktd)                                        \
  do {                                                                       \
    const unsigned short* s_ =                                               \
        (Xb) + (size_t)((h) * 128 + r0) * (ld) + (ktd) * 64 + sel;           \
    gload_lds16(s_, &XL[dd][h][d0e]);                                        \
    gload_lds16(s_ + (size_t)64 * (ld), &XL[dd][h][d1e]);                    \
  } while (0)

  // per-thread ds_read constants (row&7 == lr&7 for all frag rows)
  const int kp0 = (lg * 16) ^ ((lr & 7) << 4);
  const int kp1 = (64 + lg * 16) ^ ((lr & 7) << 4);
  const int arow = (wqm * 64 + lr) * 128;  // byte offset of frag row
  const int brow = (wqn * 32 + lr) * 128;

  f32x4 acc[2][2][4][2] = {};

#define PHASE(dd, qm, qn, STAGE_STMT, VM_STMT)                               \
  do {                                                                       \
    const char* Ab_ = (const char*)&AL[dd][qm][0];                           \
    const char* Bb_ = (const char*)&BL[dd][qn][0];                           \
    short8 af_[4][2], bf_[2][2];                                             \
    _Pragma("unroll") for (int m_ = 0; m_ < 4; m_++) {                       \
      af_[m_][0] = *(const short8*)(Ab_ + arow + m_ * 2048 + kp0);           \
      af_[m_][1] = *(const short8*)(Ab_ + arow + m_ * 2048 + kp1);           \
    }                                                                        \
    _Pragma("unroll") for (int n_ = 0; n_ < 2; n_++) {                       \
      bf_[n_][0] = *(const short8*)(Bb_ + brow + n_ * 2048 + kp0);           \
      bf_[n_][1] = *(const short8*)(Bb_ + brow + n_ * 2048 + kp1);           \
    }                                                                        \
    STAGE_STMT;                                                              \
    __builtin_amdgcn_sched_barrier(0);                                       \
    VM_STMT;                                                                 \
    __builtin_amdgcn_sched_barrier(0);                                       \
    __builtin_amdgcn_s_barrier();                                            \
    __builtin_amdgcn_sched_barrier(0);                                       \
    __builtin_amdgcn_s_setprio(1);                                           \
    _Pragma("unroll") for (int m_ = 0; m_ < 4; m_++)                         \
      _Pragma("unroll") for (int n_ = 0; n_ < 2; n_++) {                     \
        acc[qm][qn][m_][n_] = __builtin_amdgcn_mfma_f32_16x16x32_bf16(       \
            af_[m_][0], bf_[n_][0], acc[qm][qn][m_][n_], 0, 0, 0);           \
        acc[qm][qn][m_][n_] = __builtin_amdgcn_mfma_f32_16x16x32_bf16(       \
            af_[m_][1], bf_[n_][1], acc[qm][qn][m_][n_], 0, 0, 0);           \
      }                                                                      \
    __builtin_amdgcn_s_setprio(0);                                           \
    __builtin_amdgcn_sched_barrier(0);                                       \
    __builtin_amdgcn_s_barrier();                                            \
    __builtin_amdgcn_sched_barrier(0);                                       \
  } while (0)

  const int NT = K >> 6;  // K-tiles of 64

  // prologue: kt0 fully (4 half-tiles), kt1's A-half0 + B-half0
  STAGE(AL, Abase, lda, 0, 0, 0);
  STAGE(AL, Abase, lda, 0, 1, 0);
  STAGE(BL, Wbase, ldw, 0, 0, 0);
  STAGE(BL, Wbase, ldw, 0, 1, 0);
  STAGE(AL, Abase, lda, 1, 0, 1);
  STAGE(BL, Wbase, ldw, 1, 0, 1);
  asm volatile("s_waitcnt vmcnt(4)" ::: "memory");
  __builtin_amdgcn_sched_barrier(0);
  __builtin_amdgcn_s_barrier();
  __builtin_amdgcn_sched_barrier(0);

  for (int kt = 0; kt < NT; kt += 2) {
    // ---- K-tile kt (dbuf 0), quadrants (0,0) (0,1) (1,0) (1,1) ----
    PHASE(0, 0, 0,
          { if (kt + 1 < NT) STAGE(BL, Wbase, ldw, 1, 1, kt + 1); }, {});
    PHASE(0, 0, 1,
          { if (kt + 1 < NT) STAGE(AL, Abase, lda, 1, 1, kt + 1); }, {});
    PHASE(0, 1, 0,
          { if (kt + 2 < NT) STAGE(AL, Abase, lda, 0, 0, kt + 2); }, {});
    PHASE(0, 1, 1,
          { if (kt + 2 < NT) STAGE(BL, Wbase, ldw, 0, 0, kt + 2); },
          {
            if (kt + 2 < NT)
              asm volatile("s_waitcnt vmcnt(4)" ::: "memory");
            else
              asm volatile("s_waitcnt vmcnt(0)" ::: "memory");
          });
    // ---- K-tile kt+1 (dbuf 1) ----
    PHASE(1, 0, 0,
          { if (kt + 2 < NT) STAGE(BL, Wbase, ldw, 0, 1, kt + 2); }, {});
    PHASE(1, 0, 1,
          { if (kt + 2 < NT) STAGE(AL, Abase, lda, 0, 1, kt + 2); }, {});
    PHASE(1, 1, 0,
          { if (kt + 3 < NT) STAGE(AL, Abase, lda, 1, 0, kt + 3); }, {});
    PHASE(1, 1, 1,
          { if (kt + 3 < NT) STAGE(BL, Wbase, ldw, 1, 0, kt + 3); },
          {
            if (kt + 3 < NT)
              asm volatile("s_waitcnt vmcnt(4)" ::: "memory");
            else
              asm volatile("s_waitcnt vmcnt(0)" ::: "memory");
          });
  }
#undef PHASE
#undef STAGE

  // epilogue: row = m0+qm*128+wqm*64+m*16+lg*4+j ; col = n0+qn*128+wqn*32+n*16+lr
#pragma unroll
  for (int qm = 0; qm < 2; qm++)
#pragma unroll
    for (int qn = 0; qn < 2; qn++)
#pragma unroll
      for (int m = 0; m < 4; m++)
#pragma unroll
        for (int n = 0; n < 2; n++) {
          const int col = n0 + qn * 128 + wqn * 32 + n * 16 + lr;
          const int rowb = m0 + qm * 128 + wqm * 64 + m * 16 + lg * 4;
          const float bv = bias[col];
#pragma unroll
          for (int j = 0; j < 4; j++)
            outp[(size_t)(rowb + j) * N + col] = f2b(acc[qm][qn][m][n][j] + bv);
        }
}

// ---------------- GEMM 128x128 (m97 structure, no swizzle) -------------------
// MODE 1: f32 out + bias + res.  MODE 2: raw f32 out (split-K partial).
template <int MODE>
__global__ __launch_bounds__(256)
void gemm_bt(const unsigned short* __restrict__ A, int lda,
             const unsigned short* __restrict__ W, int ldw,
             const float* __restrict__ bias, const float* res, void* outp,
             int N, int K, size_t out_zstride) {
  __shared__ unsigned short As[128 * 32];
  __shared__ unsigned short Bs[128 * 32];
  const int t = threadIdx.x;
  const int l = t & 63;
  const int w = t >> 6;
  const int m0 = blockIdx.y << 7;
  const int n0 = blockIdx.x << 7;
  const int wr = (w >> 1) << 6;
  const int wc = (w & 1) << 6;
  const int koff = blockIdx.z * K;

  const unsigned short* Ab = A + (size_t)m0 * lda + koff;
  const unsigned short* Wb = W + (size_t)n0 * ldw + koff;

  f32x4 acc[4][4] = {};

  const int c0 = t, c1 = t + 256;
  const int ar0 = c0 >> 2, ak0 = (c0 & 3) * 8;
  const int ar1 = c1 >> 2, ak1 = (c1 & 3) * 8;
  const int lr = l & 15, lk = (l >> 4) * 8;

  for (int k0 = 0; k0 < K; k0 += 32) {
    gload_lds16(Ab + (size_t)ar0 * lda + k0 + ak0, &As[c0 * 8]);
    gload_lds16(Ab + (size_t)ar1 * lda + k0 + ak1, &As[c1 * 8]);
    gload_lds16(Wb + (size_t)ar0 * ldw + k0 + ak0, &Bs[c0 * 8]);
    gload_lds16(Wb + (size_t)ar1 * ldw + k0 + ak1, &Bs[c1 * 8]);
    __syncthreads();
    short8 a[4], b[4];
#pragma unroll
    for (int mi = 0; mi < 4; mi++)
      a[mi] = *(const short8*)&As[(wr + mi * 16 + lr) * 32 + lk];
#pragma unroll
    for (int ni = 0; ni < 4; ni++)
      b[ni] = *(const short8*)&Bs[(wc + ni * 16 + lr) * 32 + lk];
#pragma unroll
    for (int mi = 0; mi < 4; mi++)
#pragma unroll
      for (int ni = 0; ni < 4; ni++)
        acc[mi][ni] = __builtin_amdgcn_mfma_f32_16x16x32_bf16(
            a[mi], b[ni], acc[mi][ni], 0, 0, 0);
    __syncthreads();
  }

  const int lg = (l >> 4) * 4;
#pragma unroll
  for (int mi = 0; mi < 4; mi++) {
#pragma unroll
    for (int ni = 0; ni < 4; ni++) {
      int cn = n0 + wc + ni * 16 + lr;
      float bval = (MODE == 2) ? 0.0f : bias[cn];
#pragma unroll
      for (int j = 0; j < 4; j++) {
        int r = m0 + wr + mi * 16 + lg + j;
        float vv = acc[mi][ni][j] + bval;
        size_t idx = (size_t)r * N + cn;
        if (MODE == 1) {
          ((float*)outp)[idx] = vv + res[idx];
        } else {
          ((float*)outp + blockIdx.z * out_zstride)[idx] = vv;
        }
      }
    }
  }
}

// ---------------- V transpose: qkv v-slice -> vt[(bh*128+d)*S + s] -----------
__global__ __launch_bounds__(256)
void vtrans_kernel(const unsigned short* __restrict__ qkv,
                   unsigned short* __restrict__ vt) {
  const int bh = blockIdx.y;
  const int b = bh >> 4, h = bh & 15;
  const int s0 = blockIdx.x * 32;
  __shared__ unsigned short tile[32][136];
  const int t = threadIdx.x;
  for (int i = 0; i < 2; i++) {
    int c = t + i * 256;
    int s = c >> 4, dc = c & 15;
    *(short8*)&tile[s][dc * 8] =
        *(const short8*)(qkv + (size_t)(b * SEQ + s0 + s) * QKV_LD + 4096 +
                         h * HEAD_DIM + dc * 8);
  }
  __syncthreads();
  const int d = t >> 1, sh = (t & 1) * 16;
  unsigned short* dst = vt + ((size_t)bh * HEAD_DIM + d) * SEQ + s0 + sh;
  short8 r0, r1;
#pragma unroll
  for (int j = 0; j < 8; j++) r0[j] = tile[sh + j][d];
#pragma unroll
  for (int j = 0; j < 8; j++) r1[j] = tile[sh + 8 + j][d];
  *(short8*)dst = r0;
  *(short8*)(dst + 8) = r1;
}

// ---------------- Flash attention: async double-buffered K staging -----------
__global__ __launch_bounds__(256)
void attn_kernel(const unsigned short* __restrict__ qkv,
                 const unsigned short* __restrict__ vt,
                 unsigned short* __restrict__ o) {
  const int bh = blockIdx.y;
  const int b = bh >> 4, h = bh & 15;
  const int q0 = blockIdx.x << 6;
  const int t = threadIdx.x, w = t >> 6, l = t & 63;
  const int lr = l & 15, lg = l >> 4;

  __shared__ unsigned short Ks[2][64 * 128];  // XOR-swizzled content
  __shared__ unsigned short Ps[4][16 * 64];   // per-wave P buffer (swizzled)

  short8 qf[4];
  {
    const unsigned short* qb =
        qkv + ((size_t)(b * SEQ + q0 + w * 16 + lr)) * QKV_LD + h * HEAD_DIM;
#pragma unroll
    for (int ks = 0; ks < 4; ks++) qf[ks] = *(const short8*)(qb + ks * 32 + lg * 8);
  }

  f32x4 oacc[8] = {};
  float mrow[4] = {-1e30f, -1e30f, -1e30f, -1e30f};
  float lrowv[4] = {0.f, 0.f, 0.f, 0.f};
  const float scl = 0.08838834764831845f;  // 1/sqrt(128)

  const unsigned short* kbase =
      qkv + (size_t)(b * SEQ) * QKV_LD + 2048 + h * HEAD_DIM;
  const unsigned short* vtb = vt + (size_t)bh * HEAD_DIM * SEQ;
  unsigned short* pw = &Ps[w][0];

#define STAGEK(buf, kv0_)                                                     \
  do {                                                                        \
    _Pragma("unroll")                                                         \
    for (int i_ = 0; i_ < 4; i_++) {                                          \
      int c_ = t + i_ * 256;                                                  \
      int row_ = c_ >> 4, dc_ = c_ & 15;                                      \
      int sel_ = ((dc_ * 16) ^ ((row_ & 7) << 4)) >> 1;                       \
      gload_lds16(kbase + (size_t)((kv0_) + row_) * QKV_LD + sel_,            \
                  &Ks[buf][c_ * 8]);                                          \
    }                                                                         \
  } while (0)

  STAGEK(0, 0);
  __syncthreads();

  for (int it = 0; it < SEQ / 64; ++it) {
    const int cur = it & 1;
    const int kv0 = it * 64;
    if (it + 1 < SEQ / 64) STAGEK(cur ^ 1, kv0 + 64);

    const char* kb = (const char*)&Ks[cur][0];
    f32x4 s[4] = {};
#pragma unroll
    for (int nf = 0; nf < 4; nf++) {
      int key = nf * 16 + lr;
#pragma unroll
      for (int ks = 0; ks < 4; ks++) {
        int byo = ((key * 256 + ks * 64 + lg * 16) ^ ((key & 7) << 4));
        short8 kf = *(const short8*)(kb + byo);
        s[nf] = __builtin_amdgcn_mfma_f32_16x16x32_bf16(qf[ks], kf, s[nf], 0, 0, 0);
      }
    }

    float pm[4];
#pragma unroll
    for (int j = 0; j < 4; j++) {
      float mx = -1e30f;
#pragma unroll
      for (int nf = 0; nf < 4; nf++) {
        s[nf][j] *= scl;
        mx = fmaxf(mx, s[nf][j]);
      }
      mx = fmaxf(mx, __shfl_xor(mx, 1));
      mx = fmaxf(mx, __shfl_xor(mx, 2));
      mx = fmaxf(mx, __shfl_xor(mx, 4));
      mx = fmaxf(mx, __shfl_xor(mx, 8));
      pm[j] = mx;
    }
    float fs[4];
#pragma unroll
    for (int j = 0; j < 4; j++) {
      float mn = fmaxf(mrow[j], pm[j]);
      fs[j] = __expf(mrow[j] - mn);
      mrow[j] = mn;
    }
    float rs[4] = {0.f, 0.f, 0.f, 0.f};
#pragma unroll
    for (int nf = 0; nf < 4; nf++)
#pragma unroll
      for (int j = 0; j < 4; j++) {
        float p = __expf(s[nf][j] - mrow[j]);
        s[nf][j] = p;
        rs[j] += p;
      }
#pragma unroll
    for (int j = 0; j < 4; j++) {
      float r = rs[j];
      r += __shfl_xor(r, 1);
      r += __shfl_xor(r, 2);
      r += __shfl_xor(r, 4);
      r += __shfl_xor(r, 8);
      lrowv[j] = lrowv[j] * fs[j] + r;
    }
#pragma unroll
    for (int nf = 0; nf < 8; nf++)
#pragma unroll
      for (int j = 0; j < 4; j++) oacc[nf][j] *= fs[j];

#pragma unroll
    for (int nf = 0; nf < 4; nf++)
#pragma unroll
      for (int j = 0; j < 4; j++) {
        int row = lg * 4 + j, col = nf * 16 + lr;
        int byo = ((row * 128 + col * 2) ^ ((row & 7) << 4));
        *(unsigned short*)((char*)pw + byo) = f2b(s[nf][j]);
      }
    asm volatile("s_waitcnt lgkmcnt(0)" ::: "memory");
    __builtin_amdgcn_sched_barrier(0);
#pragma unroll
    for (int ks = 0; ks < 2; ks++) {
      int byo = ((lr * 128 + ks * 64 + lg * 16) ^ ((lr & 7) << 4));
      short8 pa = *(const short8*)((char*)pw + byo);
#pragma unroll
      for (int nf = 0; nf < 8; nf++) {
        short8 vf = *(const short8*)(vtb + (size_t)(nf * 16 + lr) * SEQ + kv0 +
                                     ks * 32 + lg * 8);
        oacc[nf] = __builtin_amdgcn_mfma_f32_16x16x32_bf16(pa, vf, oacc[nf], 0, 0, 0);
      }
    }
    __syncthreads();
  }
#undef STAGEK

  unsigned short* ob =
      o + ((size_t)(b * SEQ + q0 + w * 16)) * D_MODEL + h * HEAD_DIM;
#pragma unroll
  for (int j = 0; j < 4; j++) {
    float inv = 1.0f / lrowv[j];
    int row = lg * 4 + j;
#pragma unroll
    for (int nf = 0; nf < 8; nf++) {
      int col = nf * 16 + lr;
      ob[(size_t)row * D_MODEL + col] = f2b(oacc[nf][j] * inv);
    }
  }
}

// ---------------- SwiGLU in-place on g (row stride 16384) --------------------
__global__ __launch_bounds__(256)
void swiglu_kernel(unsigned short* __restrict__ g) {
  size_t i = (size_t)blockIdx.x * 256 + threadIdx.x;
  size_t m = i >> 10, jc = i & 1023;
  unsigned short* p1 = g + m * (2 * D_FF) + jc * 8;
  short8 aa = *(short8*)p1;
  short8 bb = *(short8*)(p1 + D_FF);
  short8 r;
#pragma unroll
  for (int jj = 0; jj < 8; jj++) {
    float x1 = b2f((unsigned short)aa[jj]);
    float x2 = b2f((unsigned short)bb[jj]);
    float sg = x2 / (1.0f + __expf(-x2));
    r[jj] = f2b(x1 * sg);
  }
  *(short8*)p1 = r;
}

// ---------------- split-K reduce: out += p0 + p1 + b2 ------------------------
__global__ __launch_bounds__(256)
void reduce2_kernel(const float* __restrict__ p0, const float* __restrict__ p1,
                    const float* __restrict__ b2, float* __restrict__ out) {
  size_t i = (size_t)blockIdx.x * 256 + threadIdx.x;
  float4 a = ((const float4*)p0)[i];
  float4 b = ((const float4*)p1)[i];
  float4 o = ((const float4*)out)[i];
  float4 bb = ((const float4*)b2)[i & 511];
  o.x += a.x + b.x + bb.x;
  o.y += a.y + b.y + bb.y;
  o.z += a.z + b.z + bb.z;
  o.w += a.w + b.w + bb.w;
  ((float4*)out)[i] = o;
}

// ---------------- host: launch sequence --------------------------------------
extern "C" void kernel_launch(void* const* d_in, const int* in_sizes, int n_in,
                              void* d_out, int out_size, void* d_ws,
                              size_t ws_size, hipStream_t stream) {
  (void)in_sizes; (void)n_in; (void)out_size; (void)ws_size;
  const float* x   = (const float*)d_in[0];
  const float* Wq  = (const float*)d_in[1];
  const float* bq  = (const float*)d_in[2];
  const float* Wk  = (const float*)d_in[3];
  const float* bk  = (const float*)d_in[4];
  const float* Wv  = (const float*)d_in[5];
  const float* bv  = (const float*)d_in[6];
  const float* Wo  = (const float*)d_in[7];
  const float* bo  = (const float*)d_in[8];
  const float* rot = (const float*)d_in[9];
  const float* n1w = (const float*)d_in[10];
  const float* n2w = (const float*)d_in[11];
  const float* W1  = (const float*)d_in[12];
  const float* b1  = (const float*)d_in[13];
  const float* W2  = (const float*)d_in[14];
  const float* b2  = (const float*)d_in[15];
  float* out = (float*)d_out;
  char* ws = (char*)d_ws;

  const size_t SZ_D2  = (size_t)D_MODEL * D_MODEL * 2;   // 8 MiB
  const size_t SZ_ACT = (size_t)M_TOK * D_MODEL * 2;     // 16 MiB
  const size_t SZ_W1  = (size_t)2 * D_FF * D_MODEL * 2;  // 64 MiB
  const size_t SZ_W2  = (size_t)D_MODEL * D_FF * 2;      // 32 MiB
  const size_t SZ_G   = (size_t)M_TOK * 2 * D_FF * 2;    // 128 MiB

  size_t off = 0;
  auto alloc = [&](size_t sz) { size_t o = off; off += (sz + 255) & ~(size_t)255; return o; };
  unsigned short* wqkv_b = (unsigned short*)(ws + alloc(3 * SZ_D2));  // at ws+0
  unsigned short* wo_b   = (unsigned short*)(ws + alloc(SZ_D2));
  unsigned short* w1_b   = (unsigned short*)(ws + alloc(SZ_W1));
  unsigned short* w2_b   = (unsigned short*)(ws + alloc(SZ_W2));
  float*          biasq  = (float*)(ws + alloc(QKV_LD * 4));
  unsigned short* h2_b   = (unsigned short*)(ws + alloc(SZ_ACT));
  char* pool = ws + alloc(SZ_G);
  // phase 1 overlay in pool: h | qkv | vt | o   (16+48+16+16 = 96 MiB)
  unsigned short* h_b   = (unsigned short*)(pool);
  unsigned short* qkv_b = (unsigned short*)(pool + SZ_ACT);
  unsigned short* vt_b  = (unsigned short*)(pool + 4 * SZ_ACT);
  unsigned short* o_b   = (unsigned short*)(pool + 5 * SZ_ACT);
  // phase 2 overlay: g occupies whole pool
  unsigned short* g_b   = (unsigned short*)(pool);
  // split-K partials overlay the (then-dead) wqkv/wo/w1 region
  float* p0 = (float*)ws;
  float* p1 = p0 + (size_t)M_TOK * D_MODEL;

  // weights -> bf16 (Q,K,V concatenated row-wise)
  cvt_kernel<<<1024, 256, 0, stream>>>(Wq, wqkv_b, D_MODEL * D_MODEL / 8);
  cvt_kernel<<<1024, 256, 0, stream>>>(Wk, wqkv_b + (size_t)D_MODEL * D_MODEL, D_MODEL * D_MODEL / 8);
  cvt_kernel<<<1024, 256, 0, stream>>>(Wv, wqkv_b + (size_t)2 * D_MODEL * D_MODEL, D_MODEL * D_MODEL / 8);
  cvt_kernel<<<1024, 256, 0, stream>>>(Wo, wo_b, D_MODEL * D_MODEL / 8);
  cvt_kernel<<<2048, 256, 0, stream>>>(W1, w1_b, 2 * D_FF * D_MODEL / 8);
  cvt_kernel<<<2048, 256, 0, stream>>>(W2, w2_b, D_MODEL * D_FF / 8);
  biasqkv_kernel<<<QKV_LD / 256, 256, 0, stream>>>(bq, bk, bv, rot, biasq);

  // norm1 -> h
  rmsnorm_kernel<<<M_TOK, 256, 0, stream>>>(x, n1w, h_b);

  // fused QKV projection (8-phase 256^2): [4096,2048] @ [6144,2048]^T
  gemm_p8<<<dim3(QKV_LD / 256, M_TOK / 256), 512, 0, stream>>>(
      h_b, D_MODEL, wqkv_b, D_MODEL, biasq, qkv_b, QKV_LD, D_MODEL);

  // V transpose + attention
  vtrans_kernel<<<dim3(SEQ / 32, BATCH * N_HEADS), 256, 0, stream>>>(qkv_b, vt_b);
  attn_kernel<<<dim3(SEQ / 64, BATCH * N_HEADS), 256, 0, stream>>>(qkv_b, vt_b, o_b);

  // O projection + residual -> d_out (f32), 128^2 structure
  gemm_bt<1><<<dim3(D_MODEL / 128, M_TOK / 128), 256, 0, stream>>>(
      o_b, D_MODEL, wo_b, D_MODEL, bo, x, out, D_MODEL, D_MODEL, 0);

  // norm2 -> h2
  rmsnorm_kernel<<<M_TOK, 256, 0, stream>>>(out, n2w, h2_b);

  // W1 -> g (8-phase 256^2): [4096,2048] @ [16384,2048]^T
  gemm_p8<<<dim3(2 * D_FF / 256, M_TOK / 256), 512, 0, stream>>>(
      h2_b, D_MODEL, w1_b, D_MODEL, b1, g_b, 2 * D_FF, D_MODEL);

  // SwiGLU in-place
  swiglu_kernel<<<(M_TOK * D_FF / 8) / 256, 256, 0, stream>>>(g_b);

  // W2 split-K -> partials (128^2 structure)
  gemm_bt<2><<<dim3(D_MODEL / 128, M_TOK / 128, 2), 256, 0, stream>>>(
      g_b, 2 * D_FF, w2_b, D_FF, nullptr, nullptr, p0, D_MODEL, D_FF / 2,
      (size_t)M_TOK * D_MODEL);

  // out += p0 + p1 + b2
  reduce2_kernel<<<(M_TOK * D_MODEL / 4) / 256, 256, 0, stream>>>(p0, p1, b2, out);
}

// Round 6
// 1086.340 us; speedup vs baseline: 2.7028x; 1.1517x over previous
//
#include <hip/hip_runtime.h>
#include <hip/hip_bf16.h>

#define D_MODEL 2048
#define N_HEADS 16
#define HEAD_DIM 128
#define D_FF 8192
#define BATCH 2
#define SEQ 2048
#define M_TOK (BATCH * SEQ)
#define QKV_LD 6144
// 1/sqrt(128) * log2(e): folded into Wq/bq so scores are in exp2 domain
#define QSCALE 0.12751744f

typedef __attribute__((ext_vector_type(8))) short short8;
typedef __attribute__((ext_vector_type(4))) short short4v;
typedef __attribute__((ext_vector_type(4))) float f32x4;
typedef __attribute__((ext_vector_type(16))) float f32x16;
typedef __attribute__((ext_vector_type(2))) unsigned int uint2v;
typedef __attribute__((ext_vector_type(4))) unsigned int uint4v;

__device__ __forceinline__ unsigned short f2b(float f) {
  __hip_bfloat16 h = __float2bfloat16(f);
  return *reinterpret_cast<unsigned short*>(&h);
}
__device__ __forceinline__ float b2f(unsigned short u) {
  unsigned int x = ((unsigned int)u) << 16;
  return __uint_as_float(x);
}

__device__ __forceinline__ void gload_lds16(const void* gsrc, void* ldst) {
  __builtin_amdgcn_global_load_lds(
      (const __attribute__((address_space(1))) void*)gsrc,
      (__attribute__((address_space(3))) void*)ldst, 16, 0, 0);
}

__device__ __forceinline__ f32x16 mfma32(short8 a, short8 b, f32x16 c) {
  return __builtin_amdgcn_mfma_f32_32x32x16_bf16(a, b, c, 0, 0, 0);
}
__device__ __forceinline__ unsigned int cvtpk(float lo, float hi) {
  unsigned int r;
  asm("v_cvt_pk_bf16_f32 %0, %1, %2" : "=v"(r) : "v"(lo), "v"(hi));
  return r;
}
__device__ __forceinline__ uint2v plswap(unsigned int a, unsigned int b) {
  return __builtin_amdgcn_permlane32_swap(a, b, false, false);
}

// ---------------- f32 -> bf16 convert (optional scale) -----------------------
__global__ __launch_bounds__(256)
void cvt_kernel(const float* __restrict__ src, unsigned short* __restrict__ dst,
                int nchunks, float scale) {
  int i = blockIdx.x * blockDim.x + threadIdx.x;
  int stride = gridDim.x * blockDim.x;
  for (int c = i; c < nchunks; c += stride) {
    const float4 a = *(const float4*)(src + (size_t)c * 8);
    const float4 b = *(const float4*)(src + (size_t)c * 8 + 4);
    short8 r;
    r[0] = f2b(a.x * scale); r[1] = f2b(a.y * scale);
    r[2] = f2b(a.z * scale); r[3] = f2b(a.w * scale);
    r[4] = f2b(b.x * scale); r[5] = f2b(b.y * scale);
    r[6] = f2b(b.z * scale); r[7] = f2b(b.w * scale);
    *(short8*)(dst + (size_t)c * 8) = r;
  }
}

// ---------------- concat bias: [(bq+rot)*QSCALE | bk | bv] -------------------
__global__ void biasqkv_kernel(const float* __restrict__ bq,
                               const float* __restrict__ bk,
                               const float* __restrict__ bv,
                               const float* __restrict__ rot,
                               float* __restrict__ outp) {
  int i = blockIdx.x * 256 + threadIdx.x;
  float v;
  if (i < 2048) v = (bq[i] + rot[i & (HEAD_DIM - 1)]) * QSCALE;
  else if (i < 4096) v = bk[i - 2048];
  else v = bv[i - 4096];
  outp[i] = v;
}

// ---------------- RMSNorm: f32 in -> bf16 out --------------------------------
__global__ __launch_bounds__(256)
void rmsnorm_kernel(const float* __restrict__ x, const float* __restrict__ wv,
                    unsigned short* __restrict__ outp) {
  const int row = blockIdx.x;
  const float* xr = x + (size_t)row * D_MODEL;
  const int base = threadIdx.x * 8;
  float4 a = *(const float4*)(xr + base);
  float4 c = *(const float4*)(xr + base + 4);
  float ss = a.x * a.x + a.y * a.y + a.z * a.z + a.w * a.w +
             c.x * c.x + c.y * c.y + c.z * c.z + c.w * c.w;
#pragma unroll
  for (int m = 1; m < 64; m <<= 1) ss += __shfl_xor(ss, m);
  __shared__ float red[4];
  if ((threadIdx.x & 63) == 0) red[threadIdx.x >> 6] = ss;
  __syncthreads();
  float tot = red[0] + red[1] + red[2] + red[3];
  float sc = rsqrtf(tot * (1.0f / D_MODEL) + 1e-8f);
  float4 w0 = *(const float4*)(wv + base);
  float4 w1 = *(const float4*)(wv + base + 4);
  short8 r;
  r[0] = f2b(a.x * sc * w0.x); r[1] = f2b(a.y * sc * w0.y);
  r[2] = f2b(a.z * sc * w0.z); r[3] = f2b(a.w * sc * w0.w);
  r[4] = f2b(c.x * sc * w1.x); r[5] = f2b(c.y * sc * w1.y);
  r[6] = f2b(c.z * sc * w1.z); r[7] = f2b(c.w * sc * w1.w);
  *(short8*)(outp + (size_t)row * D_MODEL + base) = r;
}

// ============= GEMM 256x256, BK=64, 8-phase pipelined (T2+T3+T4+T5) ==========
__global__ __launch_bounds__(512, 2)
void gemm_p8(const unsigned short* __restrict__ A, int lda,
             const unsigned short* __restrict__ W, int ldw,
             const float* __restrict__ bias, unsigned short* __restrict__ outp,
             int N, int K) {
  __shared__ unsigned short AL[2][2][128 * 64];
  __shared__ unsigned short BL[2][2][128 * 64];
  const int t = threadIdx.x;
  const int l = t & 63, w = t >> 6;
  const int wqm = w >> 2, wqn = w & 3;
  const int lr = l & 15, lg = l >> 4;
  const int m0 = blockIdx.y << 8, n0 = blockIdx.x << 8;

  const int r0 = t >> 3;
  const int cb = (t & 7) * 16;
  const int sel = ((cb ^ ((r0 & 7) << 4)) >> 1);
  const unsigned short* Abase = A + (size_t)m0 * lda;
  const unsigned short* Wbase = W + (size_t)n0 * ldw;
  const int d0e = t * 8, d1e = (t + 512) * 8;

#define STAGE(XL, Xb, ld, dd, h, ktd)                                        \
  do {                                                                       \
    const unsigned short* s_ =                                               \
        (Xb) + (size_t)((h) * 128 + r0) * (ld) + (ktd) * 64 + sel;           \
    gload_lds16(s_, &XL[dd][h][d0e]);                                        \
    gload_lds16(s_ + (size_t)64 * (ld), &XL[dd][h][d1e]);                    \
  } while (0)

  const int kp0 = (lg * 16) ^ ((lr & 7) << 4);
  const int kp1 = (64 + lg * 16) ^ ((lr & 7) << 4);
  const int arow = (wqm * 64 + lr) * 128;
  const int brow = (wqn * 32 + lr) * 128;

  f32x4 acc[2][2][4][2] = {};

#define PHASE(dd, qm, qn, STAGE_STMT, VM_STMT)                               \
  do {                                                                       \
    const char* Ab_ = (const char*)&AL[dd][qm][0];                           \
    const char* Bb_ = (const char*)&BL[dd][qn][0];                           \
    short8 af_[4][2], bf_[2][2];                                             \
    _Pragma("unroll") for (int m_ = 0; m_ < 4; m_++) {                       \
      af_[m_][0] = *(const short8*)(Ab_ + arow + m_ * 2048 + kp0);           \
      af_[m_][1] = *(const short8*)(Ab_ + arow + m_ * 2048 + kp1);           \
    }                                                                        \
    _Pragma("unroll") for (int n_ = 0; n_ < 2; n_++) {                       \
      bf_[n_][0] = *(const short8*)(Bb_ + brow + n_ * 2048 + kp0);           \
      bf_[n_][1] = *(const short8*)(Bb_ + brow + n_ * 2048 + kp1);           \
    }                                                                        \
    STAGE_STMT;                                                              \
    __builtin_amdgcn_sched_barrier(0);                                       \
    VM_STMT;                                                                 \
    __builtin_amdgcn_sched_barrier(0);                                       \
    __builtin_amdgcn_s_barrier();                                            \
    __builtin_amdgcn_sched_barrier(0);                                       \
    __builtin_amdgcn_s_setprio(1);                                           \
    _Pragma("unroll") for (int m_ = 0; m_ < 4; m_++)                         \
      _Pragma("unroll") for (int n_ = 0; n_ < 2; n_++) {                     \
        acc[qm][qn][m_][n_] = __builtin_amdgcn_mfma_f32_16x16x32_bf16(       \
            af_[m_][0], bf_[n_][0], acc[qm][qn][m_][n_], 0, 0, 0);           \
        acc[qm][qn][m_][n_] = __builtin_amdgcn_mfma_f32_16x16x32_bf16(       \
            af_[m_][1], bf_[n_][1], acc[qm][qn][m_][n_], 0, 0, 0);           \
      }                                                                      \
    __builtin_amdgcn_s_setprio(0);                                           \
    __builtin_amdgcn_sched_barrier(0);                                       \
    __builtin_amdgcn_s_barrier();                                            \
    __builtin_amdgcn_sched_barrier(0);                                       \
  } while (0)

  const int NT = K >> 6;

  STAGE(AL, Abase, lda, 0, 0, 0);
  STAGE(AL, Abase, lda, 0, 1, 0);
  STAGE(BL, Wbase, ldw, 0, 0, 0);
  STAGE(BL, Wbase, ldw, 0, 1, 0);
  STAGE(AL, Abase, lda, 1, 0, 1);
  STAGE(BL, Wbase, ldw, 1, 0, 1);
  asm volatile("s_waitcnt vmcnt(4)" ::: "memory");
  __builtin_amdgcn_sched_barrier(0);
  __builtin_amdgcn_s_barrier();
  __builtin_amdgcn_sched_barrier(0);

  for (int kt = 0; kt < NT; kt += 2) {
    PHASE(0, 0, 0,
          { if (kt + 1 < NT) STAGE(BL, Wbase, ldw, 1, 1, kt + 1); }, {});
    PHASE(0, 0, 1,
          { if (kt + 1 < NT) STAGE(AL, Abase, lda, 1, 1, kt + 1); }, {});
    PHASE(0, 1, 0,
          { if (kt + 2 < NT) STAGE(AL, Abase, lda, 0, 0, kt + 2); }, {});
    PHASE(0, 1, 1,
          { if (kt + 2 < NT) STAGE(BL, Wbase, ldw, 0, 0, kt + 2); },
          {
            if (kt + 2 < NT)
              asm volatile("s_waitcnt vmcnt(4)" ::: "memory");
            else
              asm volatile("s_waitcnt vmcnt(0)" ::: "memory");
          });
    PHASE(1, 0, 0,
          { if (kt + 2 < NT) STAGE(BL, Wbase, ldw, 0, 1, kt + 2); }, {});
    PHASE(1, 0, 1,
          { if (kt + 2 < NT) STAGE(AL, Abase, lda, 0, 1, kt + 2); }, {});
    PHASE(1, 1, 0,
          { if (kt + 3 < NT) STAGE(AL, Abase, lda, 1, 0, kt + 3); }, {});
    PHASE(1, 1, 1,
          { if (kt + 3 < NT) STAGE(BL, Wbase, ldw, 1, 0, kt + 3); },
          {
            if (kt + 3 < NT)
              asm volatile("s_waitcnt vmcnt(4)" ::: "memory");
            else
              asm volatile("s_waitcnt vmcnt(0)" ::: "memory");
          });
  }
#undef PHASE
#undef STAGE

#pragma unroll
  for (int qm = 0; qm < 2; qm++)
#pragma unroll
    for (int qn = 0; qn < 2; qn++)
#pragma unroll
      for (int m = 0; m < 4; m++)
#pragma unroll
        for (int n = 0; n < 2; n++) {
          const int col = n0 + qn * 128 + wqn * 32 + n * 16 + lr;
          const int rowb = m0 + qm * 128 + wqm * 64 + m * 16 + lg * 4;
          const float bv = bias[col];
#pragma unroll
          for (int j = 0; j < 4; j++)
            outp[(size_t)(rowb + j) * N + col] = f2b(acc[qm][qn][m][n][j] + bv);
        }
}

// ---------------- GEMM 128x128 (m97 structure) -------------------------------
// MODE 1: f32 out + bias + res.  MODE 2: raw f32 out (split-K partial).
template <int MODE>
__global__ __launch_bounds__(256)
void gemm_bt(const unsigned short* __restrict__ A, int lda,
             const unsigned short* __restrict__ W, int ldw,
             const float* __restrict__ bias, const float* res, void* outp,
             int N, int K, size_t out_zstride) {
  __shared__ unsigned short As[128 * 32];
  __shared__ unsigned short Bs[128 * 32];
  const int t = threadIdx.x;
  const int l = t & 63;
  const int w = t >> 6;
  const int m0 = blockIdx.y << 7;
  const int n0 = blockIdx.x << 7;
  const int wr = (w >> 1) << 6;
  const int wc = (w & 1) << 6;
  const int koff = blockIdx.z * K;

  const unsigned short* Ab = A + (size_t)m0 * lda + koff;
  const unsigned short* Wb = W + (size_t)n0 * ldw + koff;

  f32x4 acc[4][4] = {};

  const int c0 = t, c1 = t + 256;
  const int ar0 = c0 >> 2, ak0 = (c0 & 3) * 8;
  const int ar1 = c1 >> 2, ak1 = (c1 & 3) * 8;
  const int lr = l & 15, lk = (l >> 4) * 8;

  for (int k0 = 0; k0 < K; k0 += 32) {
    gload_lds16(Ab + (size_t)ar0 * lda + k0 + ak0, &As[c0 * 8]);
    gload_lds16(Ab + (size_t)ar1 * lda + k0 + ak1, &As[c1 * 8]);
    gload_lds16(Wb + (size_t)ar0 * ldw + k0 + ak0, &Bs[c0 * 8]);
    gload_lds16(Wb + (size_t)ar1 * ldw + k0 + ak1, &Bs[c1 * 8]);
    __syncthreads();
    short8 a[4], b[4];
#pragma unroll
    for (int mi = 0; mi < 4; mi++)
      a[mi] = *(const short8*)&As[(wr + mi * 16 + lr) * 32 + lk];
#pragma unroll
    for (int ni = 0; ni < 4; ni++)
      b[ni] = *(const short8*)&Bs[(wc + ni * 16 + lr) * 32 + lk];
#pragma unroll
    for (int mi = 0; mi < 4; mi++)
#pragma unroll
      for (int ni = 0; ni < 4; ni++)
        acc[mi][ni] = __builtin_amdgcn_mfma_f32_16x16x32_bf16(
            a[mi], b[ni], acc[mi][ni], 0, 0, 0);
    __syncthreads();
  }

  const int lg = (l >> 4) * 4;
#pragma unroll
  for (int mi = 0; mi < 4; mi++) {
#pragma unroll
    for (int ni = 0; ni < 4; ni++) {
      int cn = n0 + wc + ni * 16 + lr;
      float bval = (MODE == 2) ? 0.0f : bias[cn];
#pragma unroll
      for (int j = 0; j < 4; j++) {
        int r = m0 + wr + mi * 16 + lg + j;
        float vv = acc[mi][ni][j] + bval;
        size_t idx = (size_t)r * N + cn;
        if (MODE == 1) {
          ((float*)outp)[idx] = vv + res[idx];
        } else {
          ((float*)outp + blockIdx.z * out_zstride)[idx] = vv;
        }
      }
    }
  }
}

// ---------------- V transpose: qkv v-slice -> vt[(bh*128+d)*S + s] -----------
__global__ __launch_bounds__(256)
void vtrans_kernel(const unsigned short* __restrict__ qkv,
                   unsigned short* __restrict__ vt) {
  const int bh = blockIdx.y;
  const int b = bh >> 4, h = bh & 15;
  const int s0 = blockIdx.x * 32;
  __shared__ unsigned short tile[32][136];
  const int t = threadIdx.x;
  for (int i = 0; i < 2; i++) {
    int c = t + i * 256;
    int s = c >> 4, dc = c & 15;
    *(short8*)&tile[s][dc * 8] =
        *(const short8*)(qkv + (size_t)(b * SEQ + s0 + s) * QKV_LD + 4096 +
                         h * HEAD_DIM + dc * 8);
  }
  __syncthreads();
  const int d = t >> 1, sh = (t & 1) * 16;
  unsigned short* dst = vt + ((size_t)bh * HEAD_DIM + d) * SEQ + s0 + sh;
  short8 r0, r1;
#pragma unroll
  for (int j = 0; j < 8; j++) r0[j] = tile[sh + j][d];
#pragma unroll
  for (int j = 0; j < 8; j++) r1[j] = tile[sh + 8 + j][d];
  *(short8*)dst = r0;
  *(short8*)(dst + 8) = r1;
}

// ======== Flash attention: 8-warp 32x32 swapped-operand (m214 structure) =====
// Per warp: 32 q-rows. mfma(K,Q) -> lane holds P[kv=crow(r,hi)][q=lane&31];
// softmax in-register (1 permlane32_swap row-reduce); cvt_pk+permlane builds
// PV's B-frags; mfma(V,P) -> O^T with q=lane&31 so fs & 1/l are lane scalars.
// K: LDS double-buffered, XOR-swizzled (pre-swizzled gload_lds source).
// V: direct from vt[(bh*128+d)*SEQ+s] (L2-resident), issued before softmax.
// Scores arrive pre-scaled by 1/sqrt(128)*log2(e) (folded into Wq/bq).
__global__ __launch_bounds__(512, 2)
void attn_kernel(const unsigned short* __restrict__ qkv,
                 const unsigned short* __restrict__ vt,
                 unsigned short* __restrict__ o) {
  const int bh = blockIdx.y;
  const int b = bh >> 4, h = bh & 15;
  const int q0 = blockIdx.x << 8;  // 256 q-rows per block
  const int t = threadIdx.x, w = t >> 6, l = t & 63;
  const int ln = l & 31, hi = l >> 5;

  __shared__ unsigned short Ks[2][64 * 128];  // XOR-swizzled content

  // Q fragments (B-operand): row q = q0 + w*32 + ln, k(d) = sl*16 + hi*8
  short8 qf[8];
  {
    const unsigned short* qb =
        qkv + (size_t)(b * SEQ + q0 + w * 32 + ln) * QKV_LD + h * HEAD_DIM +
        hi * 8;
#pragma unroll
    for (int sl = 0; sl < 8; sl++) qf[sl] = *(const short8*)(qb + sl * 16);
  }

  f32x16 oacc[4] = {};  // O^T: d-blk of 32; lane: q=ln, d=blk*32+crow(r,hi)
  float mrow = -1e30f, lrow = 0.f;

  const unsigned short* kbase =
      qkv + (size_t)(b * SEQ) * QKV_LD + 2048 + h * HEAD_DIM;
  const unsigned short* vbase = vt + (size_t)bh * HEAD_DIM * SEQ;

  // K staging: 1024 16B-chunks, 512 threads; linear LDS dest + preswz source
#define STAGEK(buf, kv0_)                                                    \
  do {                                                                       \
    _Pragma("unroll") for (int i_ = 0; i_ < 2; i_++) {                       \
      int c_ = t + i_ * 512;                                                 \
      int row_ = c_ >> 4, dc_ = c_ & 15;                                     \
      int sel_ = ((dc_ * 16) ^ ((row_ & 7) << 4)) >> 1;                      \
      gload_lds16(kbase + (size_t)((kv0_) + row_) * QKV_LD + sel_,           \
                  &Ks[buf][c_ * 8]);                                         \
    }                                                                        \
  } while (0)

  STAGEK(0, 0);
  __syncthreads();

  for (int it = 0; it < SEQ / 64; ++it) {
    const int cur = it & 1;
    const int kv0 = it * 64;

    // V loads for this tile (independent; land under QK+softmax)
    short8 vf[4][4];
#pragma unroll
    for (int db = 0; db < 4; db++)
#pragma unroll
      for (int ks = 0; ks < 4; ks++)
        vf[db][ks] = *(const short8*)(vbase + (size_t)(db * 32 + ln) * SEQ +
                                      kv0 + ks * 16 + hi * 8);

    if (it + 1 < SEQ / 64) STAGEK(cur ^ 1, kv0 + 64);

    // QK^T (swapped): s0 = kv 0..31, s1 = kv 32..63 for q=ln
    const char* kb = (const char*)&Ks[cur][0];
    f32x16 s0 = {}, s1 = {};
#pragma unroll
    for (int sl = 0; sl < 8; sl++) {
      const int cw = (sl * 32 + hi * 16) ^ ((ln & 7) << 4);
      short8 kf0 = *(const short8*)(kb + ln * 256 + cw);
      short8 kf1 = *(const short8*)(kb + (32 + ln) * 256 + cw);
      s0 = mfma32(kf0, qf[sl], s0);
      s1 = mfma32(kf1, qf[sl], s1);
    }

    // full row max: 31 in-lane fmax + one permlane32_swap
    float mx = s0[0];
#pragma unroll
    for (int r = 1; r < 16; r++) mx = fmaxf(mx, s0[r]);
#pragma unroll
    for (int r = 0; r < 16; r++) mx = fmaxf(mx, s1[r]);
    {
      uint2v r2 = plswap(__float_as_uint(mx), __float_as_uint(mx));
      mx = fmaxf(__uint_as_float(r2[0]), __uint_as_float(r2[1]));
    }

    // defer-max: rescale only when max grew by > 8 (log2 domain)
    if (!__all(mx <= mrow + 8.f)) {
      float mnew = fmaxf(mrow, mx);
      float fs = exp2f(mrow - mnew);
      mrow = mnew;
      lrow *= fs;
#pragma unroll
      for (int db = 0; db < 4; db++)
#pragma unroll
        for (int r = 0; r < 16; r++) oacc[db][r] *= fs;
    }

    float p0[16], p1[16];
    float sum = 0.f;
#pragma unroll
    for (int r = 0; r < 16; r++) {
      p0[r] = exp2f(s0[r] - mrow);
      sum += p0[r];
    }
#pragma unroll
    for (int r = 0; r < 16; r++) {
      p1[r] = exp2f(s1[r] - mrow);
      sum += p1[r];
    }
    lrow += sum;  // per-lane partial; halves combined once at the end

    // pack P -> PV B-frags: pk[ks] covers kv = ks*16 + hi*8 + 0..7
    uint4v pk[4];
#define PACKSUB(P, K0)                                                       \
  {                                                                          \
    unsigned int a_, b_;                                                     \
    uint2v r_;                                                               \
    a_ = cvtpk(P[0], P[1]); b_ = cvtpk(P[4], P[5]);                          \
    r_ = plswap(a_, b_); pk[K0][0] = r_[0]; pk[K0][2] = r_[1];               \
    a_ = cvtpk(P[2], P[3]); b_ = cvtpk(P[6], P[7]);                          \
    r_ = plswap(a_, b_); pk[K0][1] = r_[0]; pk[K0][3] = r_[1];               \
    a_ = cvtpk(P[8], P[9]); b_ = cvtpk(P[12], P[13]);                        \
    r_ = plswap(a_, b_); pk[K0 + 1][0] = r_[0]; pk[K0 + 1][2] = r_[1];       \
    a_ = cvtpk(P[10], P[11]); b_ = cvtpk(P[14], P[15]);                      \
    r_ = plswap(a_, b_); pk[K0 + 1][1] = r_[0]; pk[K0 + 1][3] = r_[1];       \
  }
    PACKSUB(p0, 0);
    PACKSUB(p1, 2);
#undef PACKSUB

    // PV (swapped): oacc[db] += V[db][ks] x P[ks]
#pragma unroll
    for (int db = 0; db < 4; db++)
#pragma unroll
      for (int ks = 0; ks < 4; ks++)
        oacc[db] = mfma32(vf[db][ks], __builtin_bit_cast(short8, pk[ks]),
                          oacc[db]);

    __syncthreads();  // drains K stage; protects dbuf for next iter
  }
#undef STAGEK

  // combine lrow halves, normalize, store (q = ln is lane-uniform)
  {
    uint2v r2 = plswap(__float_as_uint(lrow), __float_as_uint(lrow));
    lrow = __uint_as_float(r2[0]) + __uint_as_float(r2[1]);
  }
  const float inv = 1.0f / lrow;
  unsigned short* ob = o + (size_t)(b * SEQ + q0 + w * 32 + ln) * D_MODEL +
                       h * HEAD_DIM + hi * 4;
#pragma unroll
  for (int db = 0; db < 4; db++)
#pragma unroll
    for (int r = 0; r < 4; r++) {
      short4v v4;
#pragma unroll
      for (int j = 0; j < 4; j++)
        v4[j] = (short)f2b(oacc[db][4 * r + j] * inv);
      *(short4v*)(ob + db * 32 + r * 8) = v4;
    }
}

// ---------------- SwiGLU in-place on g (row stride 16384) --------------------
__global__ __launch_bounds__(256)
void swiglu_kernel(unsigned short* __restrict__ g) {
  size_t i = (size_t)blockIdx.x * 256 + threadIdx.x;
  size_t m = i >> 10, jc = i & 1023;
  unsigned short* p1 = g + m * (2 * D_FF) + jc * 8;
  short8 aa = *(short8*)p1;
  short8 bb = *(short8*)(p1 + D_FF);
  short8 r;
#pragma unroll
  for (int jj = 0; jj < 8; jj++) {
    float x1 = b2f((unsigned short)aa[jj]);
    float x2 = b2f((unsigned short)bb[jj]);
    float sg = x2 / (1.0f + __expf(-x2));
    r[jj] = f2b(x1 * sg);
  }
  *(short8*)p1 = r;
}

// ---------------- split-K reduce: out += p0 + p1 + b2 ------------------------
__global__ __launch_bounds__(256)
void reduce2_kernel(const float* __restrict__ p0, const float* __restrict__ p1,
                    const float* __restrict__ b2, float* __restrict__ out) {
  size_t i = (size_t)blockIdx.x * 256 + threadIdx.x;
  float4 a = ((const float4*)p0)[i];
  float4 b = ((const float4*)p1)[i];
  float4 o = ((const float4*)out)[i];
  float4 bb = ((const float4*)b2)[i & 511];
  o.x += a.x + b.x + bb.x;
  o.y += a.y + b.y + bb.y;
  o.z += a.z + b.z + bb.z;
  o.w += a.w + b.w + bb.w;
  ((float4*)out)[i] = o;
}

// ---------------- host: launch sequence --------------------------------------
extern "C" void kernel_launch(void* const* d_in, const int* in_sizes, int n_in,
                              void* d_out, int out_size, void* d_ws,
                              size_t ws_size, hipStream_t stream) {
  (void)in_sizes; (void)n_in; (void)out_size; (void)ws_size;
  const float* x   = (const float*)d_in[0];
  const float* Wq  = (const float*)d_in[1];
  const float* bq  = (const float*)d_in[2];
  const float* Wk  = (const float*)d_in[3];
  const float* bk  = (const float*)d_in[4];
  const float* Wv  = (const float*)d_in[5];
  const float* bv  = (const float*)d_in[6];
  const float* Wo  = (const float*)d_in[7];
  const float* bo  = (const float*)d_in[8];
  const float* rot = (const float*)d_in[9];
  const float* n1w = (const float*)d_in[10];
  const float* n2w = (const float*)d_in[11];
  const float* W1  = (const float*)d_in[12];
  const float* b1  = (const float*)d_in[13];
  const float* W2  = (const float*)d_in[14];
  const float* b2  = (const float*)d_in[15];
  float* out = (float*)d_out;
  char* ws = (char*)d_ws;

  const size_t SZ_D2  = (size_t)D_MODEL * D_MODEL * 2;   // 8 MiB
  const size_t SZ_ACT = (size_t)M_TOK * D_MODEL * 2;     // 16 MiB
  const size_t SZ_W1  = (size_t)2 * D_FF * D_MODEL * 2;  // 64 MiB
  const size_t SZ_W2  = (size_t)D_MODEL * D_FF * 2;      // 32 MiB
  const size_t SZ_G   = (size_t)M_TOK * 2 * D_FF * 2;    // 128 MiB

  size_t off = 0;
  auto alloc = [&](size_t sz) { size_t o = off; off += (sz + 255) & ~(size_t)255; return o; };
  unsigned short* wqkv_b = (unsigned short*)(ws + alloc(3 * SZ_D2));  // at ws+0
  unsigned short* wo_b   = (unsigned short*)(ws + alloc(SZ_D2));
  unsigned short* w1_b   = (unsigned short*)(ws + alloc(SZ_W1));
  unsigned short* w2_b   = (unsigned short*)(ws + alloc(SZ_W2));
  float*          biasq  = (float*)(ws + alloc(QKV_LD * 4));
  unsigned short* h2_b   = (unsigned short*)(ws + alloc(SZ_ACT));
  char* pool = ws + alloc(SZ_G);
  // phase 1 overlay in pool: h | qkv | vt | o   (16+48+16+16 = 96 MiB)
  unsigned short* h_b   = (unsigned short*)(pool);
  unsigned short* qkv_b = (unsigned short*)(pool + SZ_ACT);
  unsigned short* vt_b  = (unsigned short*)(pool + 4 * SZ_ACT);
  unsigned short* o_b   = (unsigned short*)(pool + 5 * SZ_ACT);
  // phase 2 overlay: g occupies whole pool
  unsigned short* g_b   = (unsigned short*)(pool);
  // split-K partials overlay the (then-dead) wqkv/wo/w1 region
  float* p0 = (float*)ws;
  float* p1 = p0 + (size_t)M_TOK * D_MODEL;

  // weights -> bf16 (Q,K,V concatenated row-wise; Wq pre-scaled by QSCALE)
  cvt_kernel<<<1024, 256, 0, stream>>>(Wq, wqkv_b, D_MODEL * D_MODEL / 8, QSCALE);
  cvt_kernel<<<1024, 256, 0, stream>>>(Wk, wqkv_b + (size_t)D_MODEL * D_MODEL, D_MODEL * D_MODEL / 8, 1.0f);
  cvt_kernel<<<1024, 256, 0, stream>>>(Wv, wqkv_b + (size_t)2 * D_MODEL * D_MODEL, D_MODEL * D_MODEL / 8, 1.0f);
  cvt_kernel<<<1024, 256, 0, stream>>>(Wo, wo_b, D_MODEL * D_MODEL / 8, 1.0f);
  cvt_kernel<<<2048, 256, 0, stream>>>(W1, w1_b, 2 * D_FF * D_MODEL / 8, 1.0f);
  cvt_kernel<<<2048, 256, 0, stream>>>(W2, w2_b, D_MODEL * D_FF / 8, 1.0f);
  biasqkv_kernel<<<QKV_LD / 256, 256, 0, stream>>>(bq, bk, bv, rot, biasq);

  // norm1 -> h
  rmsnorm_kernel<<<M_TOK, 256, 0, stream>>>(x, n1w, h_b);

  // fused QKV projection (8-phase 256^2): [4096,2048] @ [6144,2048]^T
  gemm_p8<<<dim3(QKV_LD / 256, M_TOK / 256), 512, 0, stream>>>(
      h_b, D_MODEL, wqkv_b, D_MODEL, biasq, qkv_b, QKV_LD, D_MODEL);

  // V transpose + attention (8-warp 32x32 swapped structure)
  vtrans_kernel<<<dim3(SEQ / 32, BATCH * N_HEADS), 256, 0, stream>>>(qkv_b, vt_b);
  attn_kernel<<<dim3(SEQ / 256, BATCH * N_HEADS), 512, 0, stream>>>(qkv_b, vt_b, o_b);

  // O projection + residual -> d_out (f32), 128^2 structure
  gemm_bt<1><<<dim3(D_MODEL / 128, M_TOK / 128), 256, 0, stream>>>(
      o_b, D_MODEL, wo_b, D_MODEL, bo, x, out, D_MODEL, D_MODEL, 0);

  // norm2 -> h2
  rmsnorm_kernel<<<M_TOK, 256, 0, stream>>>(out, n2w, h2_b);

  // W1 -> g (8-phase 256^2): [4096,2048] @ [16384,2048]^T
  gemm_p8<<<dim3(2 * D_FF / 256, M_TOK / 256), 512, 0, stream>>>(
      h2_b, D_MODEL, w1_b, D_MODEL, b1, g_b, 2 * D_FF, D_MODEL);

  // SwiGLU in-place
  swiglu_kernel<<<(M_TOK * D_FF / 8) / 256, 256, 0, stream>>>(g_b);

  // W2 split-K -> partials (128^2 structure)
  gemm_bt<2><<<dim3(D_MODEL / 128, M_TOK / 128, 2), 256, 0, stream>>>(
      g_b, 2 * D_FF, w2_b, D_FF, nullptr, nullptr, p0, D_MODEL, D_FF / 2,
      (size_t)M_TOK * D_MODEL);

  // out += p0 + p1 + b2
  reduce2_kernel<<<(M_TOK * D_MODEL / 4) / 256, 256, 0, stream>>>(p0, p1, b2, out);
}

// Round 8
// 955.169 us; speedup vs baseline: 3.0740x; 1.1373x over previous
//
#include <hip/hip_runtime.h>
#include <hip/hip_bf16.h>

#define D_MODEL 2048
#define N_HEADS 16
#define HEAD_DIM 128
#define D_FF 8192
#define BATCH 2
#define SEQ 2048
#define M_TOK (BATCH * SEQ)
#define QKV_LD 6144
// 1/sqrt(128) * log2(e): folded into Wq/bq so scores are in exp2 domain
#define QSCALE 0.12751744f

typedef __attribute__((ext_vector_type(8))) short short8;
typedef __attribute__((ext_vector_type(4))) short short4v;
typedef __attribute__((ext_vector_type(4))) float f32x4;
typedef __attribute__((ext_vector_type(16))) float f32x16;
typedef __attribute__((ext_vector_type(2))) unsigned int uint2v;
typedef __attribute__((ext_vector_type(4))) unsigned int uint4v;

__device__ __forceinline__ unsigned short f2b(float f) {
  __hip_bfloat16 h = __float2bfloat16(f);
  return *reinterpret_cast<unsigned short*>(&h);
}
__device__ __forceinline__ float b2f(unsigned short u) {
  unsigned int x = ((unsigned int)u) << 16;
  return __uint_as_float(x);
}

__device__ __forceinline__ void gload_lds16(const void* gsrc, void* ldst) {
  __builtin_amdgcn_global_load_lds(
      (const __attribute__((address_space(1))) void*)gsrc,
      (__attribute__((address_space(3))) void*)ldst, 16, 0, 0);
}

__device__ __forceinline__ f32x16 mfma32(short8 a, short8 b, f32x16 c) {
  return __builtin_amdgcn_mfma_f32_32x32x16_bf16(a, b, c, 0, 0, 0);
}
__device__ __forceinline__ unsigned int cvtpk(float lo, float hi) {
  unsigned int r;
  asm("v_cvt_pk_bf16_f32 %0, %1, %2" : "=v"(r) : "v"(lo), "v"(hi));
  return r;
}
__device__ __forceinline__ uint2v plswap(unsigned int a, unsigned int b) {
  return __builtin_amdgcn_permlane32_swap(a, b, false, false);
}

// ---------------- f32 -> bf16 convert (optional scale) -----------------------
__global__ __launch_bounds__(256)
void cvt_kernel(const float* __restrict__ src, unsigned short* __restrict__ dst,
                int nchunks, float scale) {
  int i = blockIdx.x * blockDim.x + threadIdx.x;
  int stride = gridDim.x * blockDim.x;
  for (int c = i; c < nchunks; c += stride) {
    const float4 a = *(const float4*)(src + (size_t)c * 8);
    const float4 b = *(const float4*)(src + (size_t)c * 8 + 4);
    short8 r;
    r[0] = f2b(a.x * scale); r[1] = f2b(a.y * scale);
    r[2] = f2b(a.z * scale); r[3] = f2b(a.w * scale);
    r[4] = f2b(b.x * scale); r[5] = f2b(b.y * scale);
    r[6] = f2b(b.z * scale); r[7] = f2b(b.w * scale);
    *(short8*)(dst + (size_t)c * 8) = r;
  }
}

// ---------------- concat bias: [(bq+rot)*QSCALE | bk | bv] -------------------
__global__ void biasqkv_kernel(const float* __restrict__ bq,
                               const float* __restrict__ bk,
                               const float* __restrict__ bv,
                               const float* __restrict__ rot,
                               float* __restrict__ outp) {
  int i = blockIdx.x * 256 + threadIdx.x;
  float v;
  if (i < 2048) v = (bq[i] + rot[i & (HEAD_DIM - 1)]) * QSCALE;
  else if (i < 4096) v = bk[i - 2048];
  else v = bv[i - 4096];
  outp[i] = v;
}

// ---------------- RMSNorm: f32 in -> bf16 out --------------------------------
__global__ __launch_bounds__(256)
void rmsnorm_kernel(const float* __restrict__ x, const float* __restrict__ wv,
                    unsigned short* __restrict__ outp) {
  const int row = blockIdx.x;
  const float* xr = x + (size_t)row * D_MODEL;
  const int base = threadIdx.x * 8;
  float4 a = *(const float4*)(xr + base);
  float4 c = *(const float4*)(xr + base + 4);
  float ss = a.x * a.x + a.y * a.y + a.z * a.z + a.w * a.w +
             c.x * c.x + c.y * c.y + c.z * c.z + c.w * c.w;
#pragma unroll
  for (int m = 1; m < 64; m <<= 1) ss += __shfl_xor(ss, m);
  __shared__ float red[4];
  if ((threadIdx.x & 63) == 0) red[threadIdx.x >> 6] = ss;
  __syncthreads();
  float tot = red[0] + red[1] + red[2] + red[3];
  float sc = rsqrtf(tot * (1.0f / D_MODEL) + 1e-8f);
  float4 w0 = *(const float4*)(wv + base);
  float4 w1 = *(const float4*)(wv + base + 4);
  short8 r;
  r[0] = f2b(a.x * sc * w0.x); r[1] = f2b(a.y * sc * w0.y);
  r[2] = f2b(a.z * sc * w0.z); r[3] = f2b(a.w * sc * w0.w);
  r[4] = f2b(c.x * sc * w1.x); r[5] = f2b(c.y * sc * w1.y);
  r[6] = f2b(c.z * sc * w1.z); r[7] = f2b(c.w * sc * w1.w);
  *(short8*)(outp + (size_t)row * D_MODEL + base) = r;
}

// ===== GEMM 256x256, BK=64, 8-phase pipelined, 32x32x16 MFMA (T2-T5) =========
// C[M,N] = A[M, koff:+K] @ W[N, koff:+K]^T. 512 threads = 8 waves (2m x 4n).
// Wave wm covers C rows {wm*64..+63} and {128+wm*64..+63}: phase rb reads
// A-half rb>>1, rows wm*64+(rb&1)*32 -> A-half liveness is PHASE-LOCAL
// (phases 0-1 use half 0, phases 2-3 half 1), matching the proven r5/r6
// staging stagger + vmcnt(4) chain. B-frags read once per K-tile (phase 0),
// held in regs. MODE 0: bf16 out + bias.  MODE 2: f32 partial out.
template <int MODE>
__global__ __launch_bounds__(512, 2)
void gemm_p8(const unsigned short* __restrict__ A, int lda,
             const unsigned short* __restrict__ W, int ldw,
             const float* __restrict__ bias, void* __restrict__ outp,
             int N, int K, size_t out_zstride) {
  __shared__ unsigned short AL[2][2][128 * 64];
  __shared__ unsigned short BL[2][2][128 * 64];
  const int t = threadIdx.x;
  const int l = t & 63, w = t >> 6;
  const int wm = w >> 2, wn = w & 3;
  const int ln = l & 31, hi = l >> 5;
  const int m0 = blockIdx.y << 8, n0 = blockIdx.x << 8;
  const int koff = blockIdx.z * K;

  // staging: half-tile = 128 rows x 64 k; thread t stages chunks t, t+512
  const int r0 = t >> 3;
  const int cb16 = (t & 7) * 16;
  const int sel = ((cb16 ^ ((r0 & 7) << 4)) >> 1);
  const unsigned short* Abase = A + (size_t)m0 * lda + koff;
  const unsigned short* Wbase = W + (size_t)n0 * ldw + koff;
  const int d0e = t * 8, d1e = (t + 512) * 8;

#define STAGE(XL, Xb, ld, dd, h, ktd)                                        \
  do {                                                                       \
    const unsigned short* s_ =                                               \
        (Xb) + (size_t)((h) * 128 + r0) * (ld) + (ktd) * 64 + sel;           \
    gload_lds16(s_, &XL[dd][h][d0e]);                                        \
    gload_lds16(s_ + (size_t)64 * (ld), &XL[dd][h][d1e]);                    \
  } while (0)

  const int swz = (ln & 7) << 4;
  const int hb = wn >> 1;                       // B half for this wave
  const int browb = ((wn & 1) * 64 + ln) * 128; // B row base byte

  f32x16 acc[4][2] = {};
  short8 bf[2][4];  // B-frags held across the 4 phases of a K-tile

#define READB(dd)                                                            \
  do {                                                                       \
    const char* Bb_ = (const char*)&BL[dd][hb][0];                           \
    _Pragma("unroll") for (int cb_ = 0; cb_ < 2; cb_++)                      \
      _Pragma("unroll") for (int ks_ = 0; ks_ < 4; ks_++)                    \
        bf[cb_][ks_] = *(const short8*)(Bb_ + browb + cb_ * 4096 +           \
                                        ((ks_ * 32 + hi * 16) ^ swz));       \
  } while (0)

#define PHASE(dd, rb, RB, STAGE_STMT, VM_STMT)                               \
  do {                                                                       \
    const char* Ab_ = (const char*)&AL[dd][(rb) >> 1][0];                    \
    short8 af_[4];                                                           \
    if (RB) READB(dd);                                                       \
    _Pragma("unroll") for (int ks_ = 0; ks_ < 4; ks_++)                      \
      af_[ks_] = *(const short8*)(Ab_ +                                      \
                                  (wm * 64 + ((rb) & 1) * 32 + ln) * 128 +   \
                                  ((ks_ * 32 + hi * 16) ^ swz));             \
    STAGE_STMT;                                                              \
    __builtin_amdgcn_sched_barrier(0);                                       \
    VM_STMT;                                                                 \
    __builtin_amdgcn_sched_barrier(0);                                       \
    __builtin_amdgcn_s_barrier();                                            \
    __builtin_amdgcn_sched_barrier(0);                                       \
    __builtin_amdgcn_s_setprio(1);                                           \
    _Pragma("unroll") for (int cb_ = 0; cb_ < 2; cb_++)                      \
      _Pragma("unroll") for (int ks_ = 0; ks_ < 4; ks_++)                    \
        acc[rb][cb_] = mfma32(af_[ks_], bf[cb_][ks_], acc[rb][cb_]);         \
    __builtin_amdgcn_s_setprio(0);                                           \
    __builtin_amdgcn_sched_barrier(0);                                       \
    __builtin_amdgcn_s_barrier();                                            \
    __builtin_amdgcn_sched_barrier(0);                                       \
  } while (0)

  const int NT = K >> 6;

  // prologue: kt0 fully, kt1's A-half0 + B-half0 (identical to proven r5/r6)
  STAGE(AL, Abase, lda, 0, 0, 0);
  STAGE(AL, Abase, lda, 0, 1, 0);
  STAGE(BL, Wbase, ldw, 0, 0, 0);
  STAGE(BL, Wbase, ldw, 0, 1, 0);
  STAGE(AL, Abase, lda, 1, 0, 1);
  STAGE(BL, Wbase, ldw, 1, 0, 1);
  asm volatile("s_waitcnt vmcnt(4)" ::: "memory");
  __builtin_amdgcn_sched_barrier(0);
  __builtin_amdgcn_s_barrier();
  __builtin_amdgcn_sched_barrier(0);

  for (int kt = 0; kt < NT; kt += 2) {
    PHASE(0, 0, 1,
          { if (kt + 1 < NT) STAGE(BL, Wbase, ldw, 1, 1, kt + 1); }, {});
    PHASE(0, 1, 0,
          { if (kt + 1 < NT) STAGE(AL, Abase, lda, 1, 1, kt + 1); }, {});
    PHASE(0, 2, 0,
          { if (kt + 2 < NT) STAGE(AL, Abase, lda, 0, 0, kt + 2); }, {});
    PHASE(0, 3, 0,
          { if (kt + 2 < NT) STAGE(BL, Wbase, ldw, 0, 0, kt + 2); },
          {
            if (kt + 2 < NT)
              asm volatile("s_waitcnt vmcnt(4)" ::: "memory");
            else
              asm volatile("s_waitcnt vmcnt(0)" ::: "memory");
          });
    PHASE(1, 0, 1,
          { if (kt + 2 < NT) STAGE(BL, Wbase, ldw, 0, 1, kt + 2); }, {});
    PHASE(1, 1, 0,
          { if (kt + 2 < NT) STAGE(AL, Abase, lda, 0, 1, kt + 2); }, {});
    PHASE(1, 2, 0,
          { if (kt + 3 < NT) STAGE(AL, Abase, lda, 1, 0, kt + 3); }, {});
    PHASE(1, 3, 0,
          { if (kt + 3 < NT) STAGE(BL, Wbase, ldw, 1, 0, kt + 3); },
          {
            if (kt + 3 < NT)
              asm volatile("s_waitcnt vmcnt(4)" ::: "memory");
            else
              asm volatile("s_waitcnt vmcnt(0)" ::: "memory");
          });
  }
#undef PHASE
#undef READB
#undef STAGE

  // epilogue: row = m0+(rb>>1)*128+wm*64+(rb&1)*32+(r&3)+8*(r>>2)+4*hi
  //           col = n0+wn*64+cb*32+ln
#pragma unroll
  for (int rb = 0; rb < 4; rb++)
#pragma unroll
    for (int cb = 0; cb < 2; cb++) {
      const int col = n0 + wn * 64 + cb * 32 + ln;
      const float bv = (MODE == 0) ? bias[col] : 0.0f;
      const int rowb = m0 + (rb >> 1) * 128 + wm * 64 + (rb & 1) * 32 + 4 * hi;
#pragma unroll
      for (int r = 0; r < 16; r++) {
        const int row = rowb + (r & 3) + 8 * (r >> 2);
        const float vv = acc[rb][cb][r] + bv;
        if (MODE == 0)
          ((unsigned short*)outp)[(size_t)row * N + col] = f2b(vv);
        else
          ((float*)outp + blockIdx.z * out_zstride)[(size_t)row * N + col] = vv;
      }
    }
}

// ---------------- GEMM 128x128 (m97 structure): O-proj -----------------------
// MODE 1: f32 out + bias + res.
template <int MODE>
__global__ __launch_bounds__(256)
void gemm_bt(const unsigned short* __restrict__ A, int lda,
             const unsigned short* __restrict__ W, int ldw,
             const float* __restrict__ bias, const float* res, void* outp,
             int N, int K, size_t out_zstride) {
  __shared__ unsigned short As[128 * 32];
  __shared__ unsigned short Bs[128 * 32];
  const int t = threadIdx.x;
  const int l = t & 63;
  const int w = t >> 6;
  const int m0 = blockIdx.y << 7;
  const int n0 = blockIdx.x << 7;
  const int wr = (w >> 1) << 6;
  const int wc = (w & 1) << 6;
  const int koff = blockIdx.z * K;

  const unsigned short* Ab = A + (size_t)m0 * lda + koff;
  const unsigned short* Wb = W + (size_t)n0 * ldw + koff;

  f32x4 acc[4][4] = {};

  const int c0 = t, c1 = t + 256;
  const int ar0 = c0 >> 2, ak0 = (c0 & 3) * 8;
  const int ar1 = c1 >> 2, ak1 = (c1 & 3) * 8;
  const int lr = l & 15, lk = (l >> 4) * 8;

  for (int k0 = 0; k0 < K; k0 += 32) {
    gload_lds16(Ab + (size_t)ar0 * lda + k0 + ak0, &As[c0 * 8]);
    gload_lds16(Ab + (size_t)ar1 * lda + k0 + ak1, &As[c1 * 8]);
    gload_lds16(Wb + (size_t)ar0 * ldw + k0 + ak0, &Bs[c0 * 8]);
    gload_lds16(Wb + (size_t)ar1 * ldw + k0 + ak1, &Bs[c1 * 8]);
    __syncthreads();
    short8 a[4], b[4];
#pragma unroll
    for (int mi = 0; mi < 4; mi++)
      a[mi] = *(const short8*)&As[(wr + mi * 16 + lr) * 32 + lk];
#pragma unroll
    for (int ni = 0; ni < 4; ni++)
      b[ni] = *(const short8*)&Bs[(wc + ni * 16 + lr) * 32 + lk];
#pragma unroll
    for (int mi = 0; mi < 4; mi++)
#pragma unroll
      for (int ni = 0; ni < 4; ni++)
        acc[mi][ni] = __builtin_amdgcn_mfma_f32_16x16x32_bf16(
            a[mi], b[ni], acc[mi][ni], 0, 0, 0);
    __syncthreads();
  }

  const int lg = (l >> 4) * 4;
#pragma unroll
  for (int mi = 0; mi < 4; mi++) {
#pragma unroll
    for (int ni = 0; ni < 4; ni++) {
      int cn = n0 + wc + ni * 16 + lr;
      float bval = bias[cn];
#pragma unroll
      for (int j = 0; j < 4; j++) {
        int r = m0 + wr + mi * 16 + lg + j;
        float vv = acc[mi][ni][j] + bval;
        size_t idx = (size_t)r * N + cn;
        ((float*)outp)[idx] = vv + res[idx];
      }
    }
  }
  (void)out_zstride;
}

// ---------------- V transpose: qkv v-slice -> vt[(bh*128+d)*S + s] -----------
__global__ __launch_bounds__(256)
void vtrans_kernel(const unsigned short* __restrict__ qkv,
                   unsigned short* __restrict__ vt) {
  const int bh = blockIdx.y;
  const int b = bh >> 4, h = bh & 15;
  const int s0 = blockIdx.x * 32;
  __shared__ unsigned short tile[32][136];
  const int t = threadIdx.x;
  for (int i = 0; i < 2; i++) {
    int c = t + i * 256;
    int s = c >> 4, dc = c & 15;
    *(short8*)&tile[s][dc * 8] =
        *(const short8*)(qkv + (size_t)(b * SEQ + s0 + s) * QKV_LD + 4096 +
                         h * HEAD_DIM + dc * 8);
  }
  __syncthreads();
  const int d = t >> 1, sh = (t & 1) * 16;
  unsigned short* dst = vt + ((size_t)bh * HEAD_DIM + d) * SEQ + s0 + sh;
  short8 r0, r1;
#pragma unroll
  for (int j = 0; j < 8; j++) r0[j] = tile[sh + j][d];
#pragma unroll
  for (int j = 0; j < 8; j++) r1[j] = tile[sh + 8 + j][d];
  *(short8*)dst = r0;
  *(short8*)(dst + 8) = r1;
}

// ======== Flash attention: 8-warp 32x32 swapped-operand ======================
__global__ __launch_bounds__(512, 2)
void attn_kernel(const unsigned short* __restrict__ qkv,
                 const unsigned short* __restrict__ vt,
                 unsigned short* __restrict__ o) {
  const int bh = blockIdx.y;
  const int b = bh >> 4, h = bh & 15;
  const int q0 = blockIdx.x << 8;
  const int t = threadIdx.x, w = t >> 6, l = t & 63;
  const int ln = l & 31, hi = l >> 5;

  __shared__ unsigned short Ks[2][64 * 128];

  short8 qf[8];
  {
    const unsigned short* qb =
        qkv + (size_t)(b * SEQ + q0 + w * 32 + ln) * QKV_LD + h * HEAD_DIM +
        hi * 8;
#pragma unroll
    for (int sl = 0; sl < 8; sl++) qf[sl] = *(const short8*)(qb + sl * 16);
  }

  f32x16 oacc[4] = {};
  float mrow = -1e30f, lrow = 0.f;

  const unsigned short* kbase =
      qkv + (size_t)(b * SEQ) * QKV_LD + 2048 + h * HEAD_DIM;
  const unsigned short* vbase = vt + (size_t)bh * HEAD_DIM * SEQ;

#define STAGEK(buf, kv0_)                                                    \
  do {                                                                       \
    _Pragma("unroll") for (int i_ = 0; i_ < 2; i_++) {                       \
      int c_ = t + i_ * 512;                                                 \
      int row_ = c_ >> 4, dc_ = c_ & 15;                                     \
      int sel_ = ((dc_ * 16) ^ ((row_ & 7) << 4)) >> 1;                      \
      gload_lds16(kbase + (size_t)((kv0_) + row_) * QKV_LD + sel_,           \
                  &Ks[buf][c_ * 8]);                                         \
    }                                                                        \
  } while (0)

  STAGEK(0, 0);
  __syncthreads();

  for (int it = 0; it < SEQ / 64; ++it) {
    const int cur = it & 1;
    const int kv0 = it * 64;

    short8 vf[4][4];
#pragma unroll
    for (int db = 0; db < 4; db++)
#pragma unroll
      for (int ks = 0; ks < 4; ks++)
        vf[db][ks] = *(const short8*)(vbase + (size_t)(db * 32 + ln) * SEQ +
                                      kv0 + ks * 16 + hi * 8);

    if (it + 1 < SEQ / 64) STAGEK(cur ^ 1, kv0 + 64);

    const char* kb = (const char*)&Ks[cur][0];
    f32x16 s0 = {}, s1 = {};
#pragma unroll
    for (int sl = 0; sl < 8; sl++) {
      const int cw = (sl * 32 + hi * 16) ^ ((ln & 7) << 4);
      short8 kf0 = *(const short8*)(kb + ln * 256 + cw);
      short8 kf1 = *(const short8*)(kb + (32 + ln) * 256 + cw);
      s0 = mfma32(kf0, qf[sl], s0);
      s1 = mfma32(kf1, qf[sl], s1);
    }

    float mx = s0[0];
#pragma unroll
    for (int r = 1; r < 16; r++) mx = fmaxf(mx, s0[r]);
#pragma unroll
    for (int r = 0; r < 16; r++) mx = fmaxf(mx, s1[r]);
    {
      uint2v r2 = plswap(__float_as_uint(mx), __float_as_uint(mx));
      mx = fmaxf(__uint_as_float(r2[0]), __uint_as_float(r2[1]));
    }

    if (!__all(mx <= mrow + 8.f)) {
      float mnew = fmaxf(mrow, mx);
      float fs = exp2f(mrow - mnew);
      mrow = mnew;
      lrow *= fs;
#pragma unroll
      for (int db = 0; db < 4; db++)
#pragma unroll
        for (int r = 0; r < 16; r++) oacc[db][r] *= fs;
    }

    float p0[16], p1[16];
    float sum = 0.f;
#pragma unroll
    for (int r = 0; r < 16; r++) {
      p0[r] = exp2f(s0[r] - mrow);
      sum += p0[r];
    }
#pragma unroll
    for (int r = 0; r < 16; r++) {
      p1[r] = exp2f(s1[r] - mrow);
      sum += p1[r];
    }
    lrow += sum;

    uint4v pk[4];
#define PACKSUB(P, K0)                                                       \
  {                                                                          \
    unsigned int a_, b_;                                                     \
    uint2v r_;                                                               \
    a_ = cvtpk(P[0], P[1]); b_ = cvtpk(P[4], P[5]);                          \
    r_ = plswap(a_, b_); pk[K0][0] = r_[0]; pk[K0][2] = r_[1];               \
    a_ = cvtpk(P[2], P[3]); b_ = cvtpk(P[6], P[7]);                          \
    r_ = plswap(a_, b_); pk[K0][1] = r_[0]; pk[K0][3] = r_[1];               \
    a_ = cvtpk(P[8], P[9]); b_ = cvtpk(P[12], P[13]);                        \
    r_ = plswap(a_, b_); pk[K0 + 1][0] = r_[0]; pk[K0 + 1][2] = r_[1];       \
    a_ = cvtpk(P[10], P[11]); b_ = cvtpk(P[14], P[15]);                      \
    r_ = plswap(a_, b_); pk[K0 + 1][1] = r_[0]; pk[K0 + 1][3] = r_[1];       \
  }
    PACKSUB(p0, 0);
    PACKSUB(p1, 2);
#undef PACKSUB

#pragma unroll
    for (int db = 0; db < 4; db++)
#pragma unroll
      for (int ks = 0; ks < 4; ks++)
        oacc[db] = mfma32(vf[db][ks], __builtin_bit_cast(short8, pk[ks]),
                          oacc[db]);

    __syncthreads();
  }
#undef STAGEK

  {
    uint2v r2 = plswap(__float_as_uint(lrow), __float_as_uint(lrow));
    lrow = __uint_as_float(r2[0]) + __uint_as_float(r2[1]);
  }
  const float inv = 1.0f / lrow;
  unsigned short* ob = o + (size_t)(b * SEQ + q0 + w * 32 + ln) * D_MODEL +
                       h * HEAD_DIM + hi * 4;
#pragma unroll
  for (int db = 0; db < 4; db++)
#pragma unroll
    for (int r = 0; r < 4; r++) {
      short4v v4;
#pragma unroll
      for (int j = 0; j < 4; j++)
        v4[j] = (short)f2b(oacc[db][4 * r + j] * inv);
      *(short4v*)(ob + db * 32 + r * 8) = v4;
    }
}

// ---------------- SwiGLU in-place on g (row stride 16384) --------------------
__global__ __launch_bounds__(256)
void swiglu_kernel(unsigned short* __restrict__ g) {
  size_t i = (size_t)blockIdx.x * 256 + threadIdx.x;
  size_t m = i >> 10, jc = i & 1023;
  unsigned short* p1 = g + m * (2 * D_FF) + jc * 8;
  short8 aa = *(short8*)p1;
  short8 bb = *(short8*)(p1 + D_FF);
  short8 r;
#pragma unroll
  for (int jj = 0; jj < 8; jj++) {
    float x1 = b2f((unsigned short)aa[jj]);
    float x2 = b2f((unsigned short)bb[jj]);
    float sg = x2 / (1.0f + __expf(-x2));
    r[jj] = f2b(x1 * sg);
  }
  *(short8*)p1 = r;
}

// ---------------- split-K reduce: out += p0 + p1 + b2 ------------------------
__global__ __launch_bounds__(256)
void reduce2_kernel(const float* __restrict__ p0, const float* __restrict__ p1,
                    const float* __restrict__ b2, float* __restrict__ out) {
  size_t i = (size_t)blockIdx.x * 256 + threadIdx.x;
  float4 a = ((const float4*)p0)[i];
  float4 b = ((const float4*)p1)[i];
  float4 o = ((const float4*)out)[i];
  float4 bb = ((const float4*)b2)[i & 511];
  o.x += a.x + b.x + bb.x;
  o.y += a.y + b.y + bb.y;
  o.z += a.z + b.z + bb.z;
  o.w += a.w + b.w + bb.w;
  ((float4*)out)[i] = o;
}

// ---------------- host: launch sequence --------------------------------------
extern "C" void kernel_launch(void* const* d_in, const int* in_sizes, int n_in,
                              void* d_out, int out_size, void* d_ws,
                              size_t ws_size, hipStream_t stream) {
  (void)in_sizes; (void)n_in; (void)out_size; (void)ws_size;
  const float* x   = (const float*)d_in[0];
  const float* Wq  = (const float*)d_in[1];
  const float* bq  = (const float*)d_in[2];
  const float* Wk  = (const float*)d_in[3];
  const float* bk  = (const float*)d_in[4];
  const float* Wv  = (const float*)d_in[5];
  const float* bv  = (const float*)d_in[6];
  const float* Wo  = (const float*)d_in[7];
  const float* bo  = (const float*)d_in[8];
  const float* rot = (const float*)d_in[9];
  const float* n1w = (const float*)d_in[10];
  const float* n2w = (const float*)d_in[11];
  const float* W1  = (const float*)d_in[12];
  const float* b1  = (const float*)d_in[13];
  const float* W2  = (const float*)d_in[14];
  const float* b2  = (const float*)d_in[15];
  float* out = (float*)d_out;
  char* ws = (char*)d_ws;

  const size_t SZ_D2  = (size_t)D_MODEL * D_MODEL * 2;   // 8 MiB
  const size_t SZ_ACT = (size_t)M_TOK * D_MODEL * 2;     // 16 MiB
  const size_t SZ_W1  = (size_t)2 * D_FF * D_MODEL * 2;  // 64 MiB
  const size_t SZ_W2  = (size_t)D_MODEL * D_FF * 2;      // 32 MiB
  const size_t SZ_G   = (size_t)M_TOK * 2 * D_FF * 2;    // 128 MiB

  size_t off = 0;
  auto alloc = [&](size_t sz) { size_t o = off; off += (sz + 255) & ~(size_t)255; return o; };
  unsigned short* wqkv_b = (unsigned short*)(ws + alloc(3 * SZ_D2));  // at ws+0
  unsigned short* wo_b   = (unsigned short*)(ws + alloc(SZ_D2));
  unsigned short* w1_b   = (unsigned short*)(ws + alloc(SZ_W1));
  unsigned short* w2_b   = (unsigned short*)(ws + alloc(SZ_W2));
  float*          biasq  = (float*)(ws + alloc(QKV_LD * 4));
  unsigned short* h2_b   = (unsigned short*)(ws + alloc(SZ_ACT));
  char* pool = ws + alloc(SZ_G);
  // phase 1 overlay in pool: h | qkv | vt | o   (16+48+16+16 = 96 MiB)
  unsigned short* h_b   = (unsigned short*)(pool);
  unsigned short* qkv_b = (unsigned short*)(pool + SZ_ACT);
  unsigned short* vt_b  = (unsigned short*)(pool + 4 * SZ_ACT);
  unsigned short* o_b   = (unsigned short*)(pool + 5 * SZ_ACT);
  // phase 2 overlay: g occupies whole pool
  unsigned short* g_b   = (unsigned short*)(pool);
  // split-K partials overlay the (then-dead) wqkv/wo/w1 region
  float* p0 = (float*)ws;
  float* p1 = p0 + (size_t)M_TOK * D_MODEL;

  // weights -> bf16 (Q,K,V concatenated row-wise; Wq pre-scaled by QSCALE)
  cvt_kernel<<<1024, 256, 0, stream>>>(Wq, wqkv_b, D_MODEL * D_MODEL / 8, QSCALE);
  cvt_kernel<<<1024, 256, 0, stream>>>(Wk, wqkv_b + (size_t)D_MODEL * D_MODEL, D_MODEL * D_MODEL / 8, 1.0f);
  cvt_kernel<<<1024, 256, 0, stream>>>(Wv, wqkv_b + (size_t)2 * D_MODEL * D_MODEL, D_MODEL * D_MODEL / 8, 1.0f);
  cvt_kernel<<<1024, 256, 0, stream>>>(Wo, wo_b, D_MODEL * D_MODEL / 8, 1.0f);
  cvt_kernel<<<2048, 256, 0, stream>>>(W1, w1_b, 2 * D_FF * D_MODEL / 8, 1.0f);
  cvt_kernel<<<2048, 256, 0, stream>>>(W2, w2_b, D_MODEL * D_FF / 8, 1.0f);
  biasqkv_kernel<<<QKV_LD / 256, 256, 0, stream>>>(bq, bk, bv, rot, biasq);

  // norm1 -> h
  rmsnorm_kernel<<<M_TOK, 256, 0, stream>>>(x, n1w, h_b);

  // fused QKV projection (8-phase 256^2, 32x32 MFMA)
  gemm_p8<0><<<dim3(QKV_LD / 256, M_TOK / 256), 512, 0, stream>>>(
      h_b, D_MODEL, wqkv_b, D_MODEL, biasq, qkv_b, QKV_LD, D_MODEL, 0);

  // V transpose + attention
  vtrans_kernel<<<dim3(SEQ / 32, BATCH * N_HEADS), 256, 0, stream>>>(qkv_b, vt_b);
  attn_kernel<<<dim3(SEQ / 256, BATCH * N_HEADS), 512, 0, stream>>>(qkv_b, vt_b, o_b);

  // O projection + residual -> d_out (f32), 128^2 structure
  gemm_bt<1><<<dim3(D_MODEL / 128, M_TOK / 128), 256, 0, stream>>>(
      o_b, D_MODEL, wo_b, D_MODEL, bo, x, out, D_MODEL, D_MODEL, 0);

  // norm2 -> h2
  rmsnorm_kernel<<<M_TOK, 256, 0, stream>>>(out, n2w, h2_b);

  // W1 -> g (8-phase 256^2, 32x32 MFMA)
  gemm_p8<0><<<dim3(2 * D_FF / 256, M_TOK / 256), 512, 0, stream>>>(
      h2_b, D_MODEL, w1_b, D_MODEL, b1, g_b, 2 * D_FF, D_MODEL, 0);

  // SwiGLU in-place
  swiglu_kernel<<<(M_TOK * D_FF / 8) / 256, 256, 0, stream>>>(g_b);

  // W2 split-K on gemm_p8 (z=2): grid 8x16x2 = 256 blocks = 1/CU
  gemm_p8<2><<<dim3(D_MODEL / 256, M_TOK / 256, 2), 512, 0, stream>>>(
      g_b, 2 * D_FF, w2_b, D_FF, nullptr, p0, D_MODEL, D_FF / 2,
      (size_t)M_TOK * D_MODEL);

  // out += p0 + p1 + b2
  reduce2_kernel<<<(M_TOK * D_MODEL / 4) / 256, 256, 0, stream>>>(p0, p1, b2, out);
}

// Round 9
// 937.201 us; speedup vs baseline: 3.1329x; 1.0192x over previous
//
#include <hip/hip_runtime.h>
#include <hip/hip_bf16.h>

#define D_MODEL 2048
#define N_HEADS 16
#define HEAD_DIM 128
#define D_FF 8192
#define BATCH 2
#define SEQ 2048
#define M_TOK (BATCH * SEQ)
#define QKV_LD 6144
// 1/sqrt(128) * log2(e): folded into Wq/bq so scores are in exp2 domain
#define QSCALE 0.12751744f

typedef __attribute__((ext_vector_type(8))) short short8;
typedef __attribute__((ext_vector_type(4))) short short4v;
typedef __attribute__((ext_vector_type(4))) float f32x4;
typedef __attribute__((ext_vector_type(16))) float f32x16;
typedef __attribute__((ext_vector_type(2))) unsigned int uint2v;
typedef __attribute__((ext_vector_type(4))) unsigned int uint4v;

__device__ __forceinline__ unsigned short f2b(float f) {
  __hip_bfloat16 h = __float2bfloat16(f);
  return *reinterpret_cast<unsigned short*>(&h);
}
__device__ __forceinline__ float b2f(unsigned short u) {
  unsigned int x = ((unsigned int)u) << 16;
  return __uint_as_float(x);
}

__device__ __forceinline__ void gload_lds16(const void* gsrc, void* ldst) {
  __builtin_amdgcn_global_load_lds(
      (const __attribute__((address_space(1))) void*)gsrc,
      (__attribute__((address_space(3))) void*)ldst, 16, 0, 0);
}

__device__ __forceinline__ f32x16 mfma32(short8 a, short8 b, f32x16 c) {
  return __builtin_amdgcn_mfma_f32_32x32x16_bf16(a, b, c, 0, 0, 0);
}
__device__ __forceinline__ unsigned int cvtpk(float lo, float hi) {
  unsigned int r;
  asm("v_cvt_pk_bf16_f32 %0, %1, %2" : "=v"(r) : "v"(lo), "v"(hi));
  return r;
}
__device__ __forceinline__ uint2v plswap(unsigned int a, unsigned int b) {
  return __builtin_amdgcn_permlane32_swap(a, b, false, false);
}

// ---------------- f32 -> bf16 convert (optional scale) -----------------------
__global__ __launch_bounds__(256)
void cvt_kernel(const float* __restrict__ src, unsigned short* __restrict__ dst,
                int nchunks, float scale) {
  int i = blockIdx.x * blockDim.x + threadIdx.x;
  int stride = gridDim.x * blockDim.x;
  for (int c = i; c < nchunks; c += stride) {
    const float4 a = *(const float4*)(src + (size_t)c * 8);
    const float4 b = *(const float4*)(src + (size_t)c * 8 + 4);
    short8 r;
    r[0] = f2b(a.x * scale); r[1] = f2b(a.y * scale);
    r[2] = f2b(a.z * scale); r[3] = f2b(a.w * scale);
    r[4] = f2b(b.x * scale); r[5] = f2b(b.y * scale);
    r[6] = f2b(b.z * scale); r[7] = f2b(b.w * scale);
    *(short8*)(dst + (size_t)c * 8) = r;
  }
}

// ---------------- W1 -> bf16 with row interleave -----------------------------
// dst row r' = [b = r'>>6][half = (r'>>5)&1][r'&31] <- src row half*8192+b*32+(r'&31)
__global__ __launch_bounds__(256)
void cvt_w1p_kernel(const float* __restrict__ src,
                    unsigned short* __restrict__ dst) {
  int i = blockIdx.x * blockDim.x + threadIdx.x;
  int stride = gridDim.x * blockDim.x;
  const int total = 2 * D_FF * (D_MODEL / 8);
  for (int c = i; c < total; c += stride) {
    int rp = c >> 8, col8 = c & 255;
    int b = rp >> 6, half = (rp >> 5) & 1;
    int rs = half * D_FF + b * 32 + (rp & 31);
    const float* s = src + (size_t)rs * D_MODEL + col8 * 8;
    const float4 a = *(const float4*)s;
    const float4 bb = *(const float4*)(s + 4);
    short8 r;
    r[0] = f2b(a.x); r[1] = f2b(a.y); r[2] = f2b(a.z); r[3] = f2b(a.w);
    r[4] = f2b(bb.x); r[5] = f2b(bb.y); r[6] = f2b(bb.z); r[7] = f2b(bb.w);
    *(short8*)(dst + (size_t)c * 8) = r;
  }
}

// ---------------- b1 permuted to match W1' row order -------------------------
__global__ void permb1_kernel(const float* __restrict__ b1,
                              float* __restrict__ b1p) {
  int i = blockIdx.x * 256 + threadIdx.x;
  int b = i >> 6, half = (i >> 5) & 1;
  b1p[i] = b1[half * D_FF + b * 32 + (i & 31)];
}

// ---------------- concat bias: [(bq+rot)*QSCALE | bk | bv] -------------------
__global__ void biasqkv_kernel(const float* __restrict__ bq,
                               const float* __restrict__ bk,
                               const float* __restrict__ bv,
                               const float* __restrict__ rot,
                               float* __restrict__ outp) {
  int i = blockIdx.x * 256 + threadIdx.x;
  float v;
  if (i < 2048) v = (bq[i] + rot[i & (HEAD_DIM - 1)]) * QSCALE;
  else if (i < 4096) v = bk[i - 2048];
  else v = bv[i - 4096];
  outp[i] = v;
}

// ---------------- RMSNorm: f32 in -> bf16 out --------------------------------
__global__ __launch_bounds__(256)
void rmsnorm_kernel(const float* __restrict__ x, const float* __restrict__ wv,
                    unsigned short* __restrict__ outp) {
  const int row = blockIdx.x;
  const float* xr = x + (size_t)row * D_MODEL;
  const int base = threadIdx.x * 8;
  float4 a = *(const float4*)(xr + base);
  float4 c = *(const float4*)(xr + base + 4);
  float ss = a.x * a.x + a.y * a.y + a.z * a.z + a.w * a.w +
             c.x * c.x + c.y * c.y + c.z * c.z + c.w * c.w;
#pragma unroll
  for (int m = 1; m < 64; m <<= 1) ss += __shfl_xor(ss, m);
  __shared__ float red[4];
  if ((threadIdx.x & 63) == 0) red[threadIdx.x >> 6] = ss;
  __syncthreads();
  float tot = red[0] + red[1] + red[2] + red[3];
  float sc = rsqrtf(tot * (1.0f / D_MODEL) + 1e-8f);
  float4 w0 = *(const float4*)(wv + base);
  float4 w1 = *(const float4*)(wv + base + 4);
  short8 r;
  r[0] = f2b(a.x * sc * w0.x); r[1] = f2b(a.y * sc * w0.y);
  r[2] = f2b(a.z * sc * w0.z); r[3] = f2b(a.w * sc * w0.w);
  r[4] = f2b(c.x * sc * w1.x); r[5] = f2b(c.y * sc * w1.y);
  r[6] = f2b(c.z * sc * w1.z); r[7] = f2b(c.w * sc * w1.w);
  *(short8*)(outp + (size_t)row * D_MODEL + base) = r;
}

// ===== GEMM 256x256, BK=64, 8-phase pipelined, 32x32x16 MFMA (T2-T5) =========
// Swizzle f(row) = (row + (row>>3)) & 7 (bits 4-6 XOR): spreads 32-row b128
// reads to <=2 lanes/slot per 16-lane window (round-6-equivalent, conflict-
// free). f(r)==f(r+64) so one staging selector serves both chunk rows.
// MODE 0: bf16 out + bias.  MODE 2: f32 partial out.  MODE 3: swiglu-fused
// bf16 out (W1': rows interleaved so cb0 = x1, cb1 = x2; out LD = N/2).
template <int MODE>
__global__ __launch_bounds__(512, 2)
void gemm_p8(const unsigned short* __restrict__ A, int lda,
             const unsigned short* __restrict__ W, int ldw,
             const float* __restrict__ bias, void* __restrict__ outp,
             int N, int K, size_t out_zstride) {
  __shared__ unsigned short AL[2][2][128 * 64];
  __shared__ unsigned short BL[2][2][128 * 64];
  const int t = threadIdx.x;
  const int l = t & 63, w = t >> 6;
  const int wm = w >> 2, wn = w & 3;
  const int ln = l & 31, hi = l >> 5;
  const int m0 = blockIdx.y << 8, n0 = blockIdx.x << 8;
  const int koff = blockIdx.z * K;

  // staging: half-tile = 128 rows x 64 k; thread t stages chunks t, t+512
  const int r0 = t >> 3;
  const int cb16 = (t & 7) * 16;
  const int fs = ((r0 + (r0 >> 3)) & 7) << 4;
  const int sel = ((cb16 ^ fs) >> 1);
  const unsigned short* Abase = A + (size_t)m0 * lda + koff;
  const unsigned short* Wbase = W + (size_t)n0 * ldw + koff;
  const int d0e = t * 8, d1e = (t + 512) * 8;

#define STAGE(XL, Xb, ld, dd, h, ktd)                                        \
  do {                                                                       \
    const unsigned short* s_ =                                               \
        (Xb) + (size_t)((h) * 128 + r0) * (ld) + (ktd) * 64 + sel;           \
    gload_lds16(s_, &XL[dd][h][d0e]);                                        \
    gload_lds16(s_ + (size_t)64 * (ld), &XL[dd][h][d1e]);                    \
  } while (0)

  const int hb = wn >> 1;                       // B half for this wave
  const int browb = ((wn & 1) * 64 + ln) * 128; // B row base byte
  const int lnf = ln + (ln >> 3);               // swizzle seed

  f32x16 acc[4][2] = {};
  short8 bf[2][4];  // B-frags held across the 4 phases of a K-tile

#define READB(dd)                                                            \
  do {                                                                       \
    const char* Bb_ = (const char*)&BL[dd][hb][0];                           \
    _Pragma("unroll") for (int cb_ = 0; cb_ < 2; cb_++) {                    \
      const int fb_ = ((lnf + 4 * cb_) & 7) << 4;                            \
      _Pragma("unroll") for (int ks_ = 0; ks_ < 4; ks_++)                    \
        bf[cb_][ks_] = *(const short8*)(Bb_ + browb + cb_ * 4096 +           \
                                        ((ks_ * 32 + hi * 16) ^ fb_));       \
    }                                                                        \
  } while (0)

#define PHASE(dd, rb, RB, STAGE_STMT, VM_STMT)                               \
  do {                                                                       \
    const char* Ab_ = (const char*)&AL[dd][(rb) >> 1][0];                    \
    const int fa_ = ((lnf + 4 * ((rb) & 1)) & 7) << 4;                       \
    short8 af_[4];                                                           \
    if (RB) READB(dd);                                                       \
    _Pragma("unroll") for (int ks_ = 0; ks_ < 4; ks_++)                      \
      af_[ks_] = *(const short8*)(Ab_ +                                      \
                                  (wm * 64 + ((rb) & 1) * 32 + ln) * 128 +   \
                                  ((ks_ * 32 + hi * 16) ^ fa_));             \
    STAGE_STMT;                                                              \
    __builtin_amdgcn_sched_barrier(0);                                       \
    VM_STMT;                                                                 \
    __builtin_amdgcn_sched_barrier(0);                                       \
    __builtin_amdgcn_s_barrier();                                            \
    __builtin_amdgcn_sched_barrier(0);                                       \
    __builtin_amdgcn_s_setprio(1);                                           \
    _Pragma("unroll") for (int cb_ = 0; cb_ < 2; cb_++)                      \
      _Pragma("unroll") for (int ks_ = 0; ks_ < 4; ks_++)                    \
        acc[rb][cb_] = mfma32(af_[ks_], bf[cb_][ks_], acc[rb][cb_]);         \
    __builtin_amdgcn_s_setprio(0);                                           \
    __builtin_amdgcn_sched_barrier(0);                                       \
    __builtin_amdgcn_s_barrier();                                            \
    __builtin_amdgcn_sched_barrier(0);                                       \
  } while (0)

  const int NT = K >> 6;

  // prologue: kt0 fully, kt1's A-half0 + B-half0 (proven r5/r6/r8 chain)
  STAGE(AL, Abase, lda, 0, 0, 0);
  STAGE(AL, Abase, lda, 0, 1, 0);
  STAGE(BL, Wbase, ldw, 0, 0, 0);
  STAGE(BL, Wbase, ldw, 0, 1, 0);
  STAGE(AL, Abase, lda, 1, 0, 1);
  STAGE(BL, Wbase, ldw, 1, 0, 1);
  asm volatile("s_waitcnt vmcnt(4)" ::: "memory");
  __builtin_amdgcn_sched_barrier(0);
  __builtin_amdgcn_s_barrier();
  __builtin_amdgcn_sched_barrier(0);

  for (int kt = 0; kt < NT; kt += 2) {
    PHASE(0, 0, 1,
          { if (kt + 1 < NT) STAGE(BL, Wbase, ldw, 1, 1, kt + 1); }, {});
    PHASE(0, 1, 0,
          { if (kt + 1 < NT) STAGE(AL, Abase, lda, 1, 1, kt + 1); }, {});
    PHASE(0, 2, 0,
          { if (kt + 2 < NT) STAGE(AL, Abase, lda, 0, 0, kt + 2); }, {});
    PHASE(0, 3, 0,
          { if (kt + 2 < NT) STAGE(BL, Wbase, ldw, 0, 0, kt + 2); },
          {
            if (kt + 2 < NT)
              asm volatile("s_waitcnt vmcnt(4)" ::: "memory");
            else
              asm volatile("s_waitcnt vmcnt(0)" ::: "memory");
          });
    PHASE(1, 0, 1,
          { if (kt + 2 < NT) STAGE(BL, Wbase, ldw, 0, 1, kt + 2); }, {});
    PHASE(1, 1, 0,
          { if (kt + 2 < NT) STAGE(AL, Abase, lda, 0, 1, kt + 2); }, {});
    PHASE(1, 2, 0,
          { if (kt + 3 < NT) STAGE(AL, Abase, lda, 1, 0, kt + 3); }, {});
    PHASE(1, 3, 0,
          { if (kt + 3 < NT) STAGE(BL, Wbase, ldw, 1, 0, kt + 3); },
          {
            if (kt + 3 < NT)
              asm volatile("s_waitcnt vmcnt(4)" ::: "memory");
            else
              asm volatile("s_waitcnt vmcnt(0)" ::: "memory");
          });
  }
#undef PHASE
#undef READB
#undef STAGE

  // epilogue: row = m0+(rb>>1)*128+wm*64+(rb&1)*32+(r&3)+8*(r>>2)+4*hi
#pragma unroll
  for (int rb = 0; rb < 4; rb++) {
    const int rowb = m0 + (rb >> 1) * 128 + wm * 64 + (rb & 1) * 32 + 4 * hi;
    if (MODE == 3) {
      const int col0 = n0 + wn * 64 + ln;
      const float b1v = bias[col0];
      const float b2v = bias[col0 + 32];
      const int jout = (n0 >> 1) + wn * 32 + ln;
#pragma unroll
      for (int r = 0; r < 16; r++) {
        const int row = rowb + (r & 3) + 8 * (r >> 2);
        float x1 = acc[rb][0][r] + b1v;
        float x2 = acc[rb][1][r] + b2v;
        float sg = x2 / (1.0f + __expf(-x2));
        ((unsigned short*)outp)[(size_t)row * (N >> 1) + jout] = f2b(x1 * sg);
      }
    } else {
#pragma unroll
      for (int cb = 0; cb < 2; cb++) {
        const int col = n0 + wn * 64 + cb * 32 + ln;
        const float bv = (MODE == 0) ? bias[col] : 0.0f;
#pragma unroll
        for (int r = 0; r < 16; r++) {
          const int row = rowb + (r & 3) + 8 * (r >> 2);
          const float vv = acc[rb][cb][r] + bv;
          if (MODE == 0)
            ((unsigned short*)outp)[(size_t)row * N + col] = f2b(vv);
          else
            ((float*)outp + blockIdx.z * out_zstride)[(size_t)row * N + col] = vv;
        }
      }
    }
  }
}

// ---------------- GEMM 128x128 (m97 structure): O-proj -----------------------
template <int MODE>
__global__ __launch_bounds__(256)
void gemm_bt(const unsigned short* __restrict__ A, int lda,
             const unsigned short* __restrict__ W, int ldw,
             const float* __restrict__ bias, const float* res, void* outp,
             int N, int K, size_t out_zstride) {
  __shared__ unsigned short As[128 * 32];
  __shared__ unsigned short Bs[128 * 32];
  const int t = threadIdx.x;
  const int l = t & 63;
  const int w = t >> 6;
  const int m0 = blockIdx.y << 7;
  const int n0 = blockIdx.x << 7;
  const int wr = (w >> 1) << 6;
  const int wc = (w & 1) << 6;
  const int koff = blockIdx.z * K;

  const unsigned short* Ab = A + (size_t)m0 * lda + koff;
  const unsigned short* Wb = W + (size_t)n0 * ldw + koff;

  f32x4 acc[4][4] = {};

  const int c0 = t, c1 = t + 256;
  const int ar0 = c0 >> 2, ak0 = (c0 & 3) * 8;
  const int ar1 = c1 >> 2, ak1 = (c1 & 3) * 8;
  const int lr = l & 15, lk = (l >> 4) * 8;

  for (int k0 = 0; k0 < K; k0 += 32) {
    gload_lds16(Ab + (size_t)ar0 * lda + k0 + ak0, &As[c0 * 8]);
    gload_lds16(Ab + (size_t)ar1 * lda + k0 + ak1, &As[c1 * 8]);
    gload_lds16(Wb + (size_t)ar0 * ldw + k0 + ak0, &Bs[c0 * 8]);
    gload_lds16(Wb + (size_t)ar1 * ldw + k0 + ak1, &Bs[c1 * 8]);
    __syncthreads();
    short8 a[4], b[4];
#pragma unroll
    for (int mi = 0; mi < 4; mi++)
      a[mi] = *(const short8*)&As[(wr + mi * 16 + lr) * 32 + lk];
#pragma unroll
    for (int ni = 0; ni < 4; ni++)
      b[ni] = *(const short8*)&Bs[(wc + ni * 16 + lr) * 32 + lk];
#pragma unroll
    for (int mi = 0; mi < 4; mi++)
#pragma unroll
      for (int ni = 0; ni < 4; ni++)
        acc[mi][ni] = __builtin_amdgcn_mfma_f32_16x16x32_bf16(
            a[mi], b[ni], acc[mi][ni], 0, 0, 0);
    __syncthreads();
  }

  const int lg = (l >> 4) * 4;
#pragma unroll
  for (int mi = 0; mi < 4; mi++) {
#pragma unroll
    for (int ni = 0; ni < 4; ni++) {
      int cn = n0 + wc + ni * 16 + lr;
      float bval = bias[cn];
#pragma unroll
      for (int j = 0; j < 4; j++) {
        int r = m0 + wr + mi * 16 + lg + j;
        float vv = acc[mi][ni][j] + bval;
        size_t idx = (size_t)r * N + cn;
        ((float*)outp)[idx] = vv + res[idx];
      }
    }
  }
  (void)out_zstride;
}

// ---------------- V transpose: qkv v-slice -> vt[(bh*128+d)*S + s] -----------
__global__ __launch_bounds__(256)
void vtrans_kernel(const unsigned short* __restrict__ qkv,
                   unsigned short* __restrict__ vt) {
  const int bh = blockIdx.y;
  const int b = bh >> 4, h = bh & 15;
  const int s0 = blockIdx.x * 32;
  __shared__ unsigned short tile[32][136];
  const int t = threadIdx.x;
  for (int i = 0; i < 2; i++) {
    int c = t + i * 256;
    int s = c >> 4, dc = c & 15;
    *(short8*)&tile[s][dc * 8] =
        *(const short8*)(qkv + (size_t)(b * SEQ + s0 + s) * QKV_LD + 4096 +
                         h * HEAD_DIM + dc * 8);
  }
  __syncthreads();
  const int d = t >> 1, sh = (t & 1) * 16;
  unsigned short* dst = vt + ((size_t)bh * HEAD_DIM + d) * SEQ + s0 + sh;
  short8 r0, r1;
#pragma unroll
  for (int j = 0; j < 8; j++) r0[j] = tile[sh + j][d];
#pragma unroll
  for (int j = 0; j < 8; j++) r1[j] = tile[sh + 8 + j][d];
  *(short8*)dst = r0;
  *(short8*)(dst + 8) = r1;
}

// ======== Flash attention: 8-warp 32x32 swapped-operand ======================
__global__ __launch_bounds__(512, 2)
void attn_kernel(const unsigned short* __restrict__ qkv,
                 const unsigned short* __restrict__ vt,
                 unsigned short* __restrict__ o) {
  const int bh = blockIdx.y;
  const int b = bh >> 4, h = bh & 15;
  const int q0 = blockIdx.x << 8;
  const int t = threadIdx.x, w = t >> 6, l = t & 63;
  const int ln = l & 31, hi = l >> 5;

  __shared__ unsigned short Ks[2][64 * 128];

  short8 qf[8];
  {
    const unsigned short* qb =
        qkv + (size_t)(b * SEQ + q0 + w * 32 + ln) * QKV_LD + h * HEAD_DIM +
        hi * 8;
#pragma unroll
    for (int sl = 0; sl < 8; sl++) qf[sl] = *(const short8*)(qb + sl * 16);
  }

  f32x16 oacc[4] = {};
  float mrow = -1e30f, lrow = 0.f;

  const unsigned short* kbase =
      qkv + (size_t)(b * SEQ) * QKV_LD + 2048 + h * HEAD_DIM;
  const unsigned short* vbase = vt + (size_t)bh * HEAD_DIM * SEQ;

#define STAGEK(buf, kv0_)                                                    \
  do {                                                                       \
    _Pragma("unroll") for (int i_ = 0; i_ < 2; i_++) {                       \
      int c_ = t + i_ * 512;                                                 \
      int row_ = c_ >> 4, dc_ = c_ & 15;                                     \
      int f_ = ((row_ + (row_ >> 3)) & 7) << 4;                              \
      int sel_ = ((dc_ * 16) ^ f_) >> 1;                                     \
      gload_lds16(kbase + (size_t)((kv0_) + row_) * QKV_LD + sel_,           \
                  &Ks[buf][c_ * 8]);                                         \
    }                                                                        \
  } while (0)

  STAGEK(0, 0);
  __syncthreads();

  const int f0 = ((ln + (ln >> 3)) & 7) << 4;
  const int f1 = ((ln + (ln >> 3) + 4) & 7) << 4;

  for (int it = 0; it < SEQ / 64; ++it) {
    const int cur = it & 1;
    const int kv0 = it * 64;

    short8 vf[4][4];
#pragma unroll
    for (int db = 0; db < 4; db++)
#pragma unroll
      for (int ks = 0; ks < 4; ks++)
        vf[db][ks] = *(const short8*)(vbase + (size_t)(db * 32 + ln) * SEQ +
                                      kv0 + ks * 16 + hi * 8);

    if (it + 1 < SEQ / 64) STAGEK(cur ^ 1, kv0 + 64);

    const char* kb = (const char*)&Ks[cur][0];
    f32x16 s0 = {}, s1 = {};
#pragma unroll
    for (int sl = 0; sl < 8; sl++) {
      const int cwb = sl * 32 + hi * 16;
      short8 kf0 = *(const short8*)(kb + ln * 256 + (cwb ^ f0));
      short8 kf1 = *(const short8*)(kb + (32 + ln) * 256 + (cwb ^ f1));
      s0 = mfma32(kf0, qf[sl], s0);
      s1 = mfma32(kf1, qf[sl], s1);
    }

    float mx = s0[0];
#pragma unroll
    for (int r = 1; r < 16; r++) mx = fmaxf(mx, s0[r]);
#pragma unroll
    for (int r = 0; r < 16; r++) mx = fmaxf(mx, s1[r]);
    {
      uint2v r2 = plswap(__float_as_uint(mx), __float_as_uint(mx));
      mx = fmaxf(__uint_as_float(r2[0]), __uint_as_float(r2[1]));
    }

    if (!__all(mx <= mrow + 8.f)) {
      float mnew = fmaxf(mrow, mx);
      float fs = exp2f(mrow - mnew);
      mrow = mnew;
      lrow *= fs;
#pragma unroll
      for (int db = 0; db < 4; db++)
#pragma unroll
        for (int r = 0; r < 16; r++) oacc[db][r] *= fs;
    }

    float p0[16], p1[16];
    float sum = 0.f;
#pragma unroll
    for (int r = 0; r < 16; r++) {
      p0[r] = exp2f(s0[r] - mrow);
      sum += p0[r];
    }
#pragma unroll
    for (int r = 0; r < 16; r++) {
      p1[r] = exp2f(s1[r] - mrow);
      sum += p1[r];
    }
    lrow += sum;

    uint4v pk[4];
#define PACKSUB(P, K0)                                                       \
  {                                                                          \
    unsigned int a_, b_;                                                     \
    uint2v r_;                                                               \
    a_ = cvtpk(P[0], P[1]); b_ = cvtpk(P[4], P[5]);                          \
    r_ = plswap(a_, b_); pk[K0][0] = r_[0]; pk[K0][2] = r_[1];               \
    a_ = cvtpk(P[2], P[3]); b_ = cvtpk(P[6], P[7]);                          \
    r_ = plswap(a_, b_); pk[K0][1] = r_[0]; pk[K0][3] = r_[1];               \
    a_ = cvtpk(P[8], P[9]); b_ = cvtpk(P[12], P[13]);                        \
    r_ = plswap(a_, b_); pk[K0 + 1][0] = r_[0]; pk[K0 + 1][2] = r_[1];       \
    a_ = cvtpk(P[10], P[11]); b_ = cvtpk(P[14], P[15]);                      \
    r_ = plswap(a_, b_); pk[K0 + 1][1] = r_[0]; pk[K0 + 1][3] = r_[1];       \
  }
    PACKSUB(p0, 0);
    PACKSUB(p1, 2);
#undef PACKSUB

#pragma unroll
    for (int db = 0; db < 4; db++)
#pragma unroll
      for (int ks = 0; ks < 4; ks++)
        oacc[db] = mfma32(vf[db][ks], __builtin_bit_cast(short8, pk[ks]),
                          oacc[db]);

    __syncthreads();
  }
#undef STAGEK

  {
    uint2v r2 = plswap(__float_as_uint(lrow), __float_as_uint(lrow));
    lrow = __uint_as_float(r2[0]) + __uint_as_float(r2[1]);
  }
  const float inv = 1.0f / lrow;
  unsigned short* ob = o + (size_t)(b * SEQ + q0 + w * 32 + ln) * D_MODEL +
                       h * HEAD_DIM + hi * 4;
#pragma unroll
  for (int db = 0; db < 4; db++)
#pragma unroll
    for (int r = 0; r < 4; r++) {
      short4v v4;
#pragma unroll
      for (int j = 0; j < 4; j++)
        v4[j] = (short)f2b(oacc[db][4 * r + j] * inv);
      *(short4v*)(ob + db * 32 + r * 8) = v4;
    }
}

// ---------------- split-K reduce: out += p0 + p1 + b2 ------------------------
__global__ __launch_bounds__(256)
void reduce2_kernel(const float* __restrict__ p0, const float* __restrict__ p1,
                    const float* __restrict__ b2, float* __restrict__ out) {
  size_t i = (size_t)blockIdx.x * 256 + threadIdx.x;
  float4 a = ((const float4*)p0)[i];
  float4 b = ((const float4*)p1)[i];
  float4 o = ((const float4*)out)[i];
  float4 bb = ((const float4*)b2)[i & 511];
  o.x += a.x + b.x + bb.x;
  o.y += a.y + b.y + bb.y;
  o.z += a.z + b.z + bb.z;
  o.w += a.w + b.w + bb.w;
  ((float4*)out)[i] = o;
}

// ---------------- host: launch sequence --------------------------------------
extern "C" void kernel_launch(void* const* d_in, const int* in_sizes, int n_in,
                              void* d_out, int out_size, void* d_ws,
                              size_t ws_size, hipStream_t stream) {
  (void)in_sizes; (void)n_in; (void)out_size; (void)ws_size;
  const float* x   = (const float*)d_in[0];
  const float* Wq  = (const float*)d_in[1];
  const float* bq  = (const float*)d_in[2];
  const float* Wk  = (const float*)d_in[3];
  const float* bk  = (const float*)d_in[4];
  const float* Wv  = (const float*)d_in[5];
  const float* bv  = (const float*)d_in[6];
  const float* Wo  = (const float*)d_in[7];
  const float* bo  = (const float*)d_in[8];
  const float* rot = (const float*)d_in[9];
  const float* n1w = (const float*)d_in[10];
  const float* n2w = (const float*)d_in[11];
  const float* W1  = (const float*)d_in[12];
  const float* b1  = (const float*)d_in[13];
  const float* W2  = (const float*)d_in[14];
  const float* b2  = (const float*)d_in[15];
  float* out = (float*)d_out;
  char* ws = (char*)d_ws;

  const size_t SZ_D2  = (size_t)D_MODEL * D_MODEL * 2;   // 8 MiB
  const size_t SZ_ACT = (size_t)M_TOK * D_MODEL * 2;     // 16 MiB
  const size_t SZ_W1  = (size_t)2 * D_FF * D_MODEL * 2;  // 64 MiB
  const size_t SZ_W2  = (size_t)D_MODEL * D_FF * 2;      // 32 MiB
  const size_t SZ_G   = (size_t)M_TOK * 2 * D_FF * 2;    // 128 MiB

  size_t off = 0;
  auto alloc = [&](size_t sz) { size_t o = off; off += (sz + 255) & ~(size_t)255; return o; };
  unsigned short* wqkv_b = (unsigned short*)(ws + alloc(3 * SZ_D2));  // at ws+0
  unsigned short* wo_b   = (unsigned short*)(ws + alloc(SZ_D2));
  unsigned short* w1_b   = (unsigned short*)(ws + alloc(SZ_W1));     // permuted W1'
  unsigned short* w2_b   = (unsigned short*)(ws + alloc(SZ_W2));
  float*          biasq  = (float*)(ws + alloc(QKV_LD * 4));
  float*          b1p    = (float*)(ws + alloc(2 * D_FF * 4));
  unsigned short* h2_b   = (unsigned short*)(ws + alloc(SZ_ACT));
  char* pool = ws + alloc(SZ_G);
  // phase 1 overlay in pool: h | qkv | vt | o   (16+48+16+16 = 96 MiB)
  unsigned short* h_b   = (unsigned short*)(pool);
  unsigned short* qkv_b = (unsigned short*)(pool + SZ_ACT);
  unsigned short* vt_b  = (unsigned short*)(pool + 4 * SZ_ACT);
  unsigned short* o_b   = (unsigned short*)(pool + 5 * SZ_ACT);
  // phase 2 overlay: ff (4096 x 8192 bf16 = 64 MiB) occupies pool start
  unsigned short* ff_b  = (unsigned short*)(pool);
  // split-K partials overlay the (then-dead) wqkv/wo/w1 region
  float* p0 = (float*)ws;
  float* p1 = p0 + (size_t)M_TOK * D_MODEL;

  // weights -> bf16 (Q,K,V concatenated row-wise; Wq pre-scaled by QSCALE)
  cvt_kernel<<<1024, 256, 0, stream>>>(Wq, wqkv_b, D_MODEL * D_MODEL / 8, QSCALE);
  cvt_kernel<<<1024, 256, 0, stream>>>(Wk, wqkv_b + (size_t)D_MODEL * D_MODEL, D_MODEL * D_MODEL / 8, 1.0f);
  cvt_kernel<<<1024, 256, 0, stream>>>(Wv, wqkv_b + (size_t)2 * D_MODEL * D_MODEL, D_MODEL * D_MODEL / 8, 1.0f);
  cvt_kernel<<<1024, 256, 0, stream>>>(Wo, wo_b, D_MODEL * D_MODEL / 8, 1.0f);
  cvt_w1p_kernel<<<2048, 256, 0, stream>>>(W1, w1_b);
  cvt_kernel<<<2048, 256, 0, stream>>>(W2, w2_b, D_MODEL * D_FF / 8, 1.0f);
  biasqkv_kernel<<<QKV_LD / 256, 256, 0, stream>>>(bq, bk, bv, rot, biasq);
  permb1_kernel<<<2 * D_FF / 256, 256, 0, stream>>>(b1, b1p);

  // norm1 -> h
  rmsnorm_kernel<<<M_TOK, 256, 0, stream>>>(x, n1w, h_b);

  // fused QKV projection (8-phase 256^2, 32x32 MFMA)
  gemm_p8<0><<<dim3(QKV_LD / 256, M_TOK / 256), 512, 0, stream>>>(
      h_b, D_MODEL, wqkv_b, D_MODEL, biasq, qkv_b, QKV_LD, D_MODEL, 0);

  // V transpose + attention
  vtrans_kernel<<<dim3(SEQ / 32, BATCH * N_HEADS), 256, 0, stream>>>(qkv_b, vt_b);
  attn_kernel<<<dim3(SEQ / 256, BATCH * N_HEADS), 512, 0, stream>>>(qkv_b, vt_b, o_b);

  // O projection + residual -> d_out (f32), 128^2 structure
  gemm_bt<1><<<dim3(D_MODEL / 128, M_TOK / 128), 256, 0, stream>>>(
      o_b, D_MODEL, wo_b, D_MODEL, bo, x, out, D_MODEL, D_MODEL, 0);

  // norm2 -> h2
  rmsnorm_kernel<<<M_TOK, 256, 0, stream>>>(out, n2w, h2_b);

  // W1 + fused SwiGLU -> ff (8-phase 256^2, MODE 3)
  gemm_p8<3><<<dim3(2 * D_FF / 256, M_TOK / 256), 512, 0, stream>>>(
      h2_b, D_MODEL, w1_b, D_MODEL, b1p, ff_b, 2 * D_FF, D_MODEL, 0);

  // W2 split-K on gemm_p8 (z=2): A = ff [4096][8192]
  gemm_p8<2><<<dim3(D_MODEL / 256, M_TOK / 256, 2), 512, 0, stream>>>(
      ff_b, D_FF, w2_b, D_FF, nullptr, p0, D_MODEL, D_FF / 2,
      (size_t)M_TOK * D_MODEL);

  // out += p0 + p1 + b2
  reduce2_kernel<<<(M_TOK * D_MODEL / 4) / 256, 256, 0, stream>>>(p0, p1, b2, out);
}

// Round 10
// 917.695 us; speedup vs baseline: 3.1995x; 1.0213x over previous
//
#include <hip/hip_runtime.h>
#include <hip/hip_bf16.h>

#define D_MODEL 2048
#define N_HEADS 16
#define HEAD_DIM 128
#define D_FF 8192
#define BATCH 2
#define SEQ 2048
#define M_TOK (BATCH * SEQ)
#define QKV_LD 6144
// 1/sqrt(128) * log2(e): folded into Wq/bq so scores are in exp2 domain
#define QSCALE 0.12751744f

typedef __attribute__((ext_vector_type(8))) short short8;
typedef __attribute__((ext_vector_type(4))) short short4v;
typedef __attribute__((ext_vector_type(4))) float f32x4;
typedef __attribute__((ext_vector_type(16))) float f32x16;
typedef __attribute__((ext_vector_type(2))) unsigned int uint2v;
typedef __attribute__((ext_vector_type(4))) unsigned int uint4v;

__device__ __forceinline__ unsigned short f2b(float f) {
  __hip_bfloat16 h = __float2bfloat16(f);
  return *reinterpret_cast<unsigned short*>(&h);
}
__device__ __forceinline__ float b2f(unsigned short u) {
  unsigned int x = ((unsigned int)u) << 16;
  return __uint_as_float(x);
}

__device__ __forceinline__ void gload_lds16(const void* gsrc, void* ldst) {
  __builtin_amdgcn_global_load_lds(
      (const __attribute__((address_space(1))) void*)gsrc,
      (__attribute__((address_space(3))) void*)ldst, 16, 0, 0);
}

__device__ __forceinline__ f32x16 mfma32(short8 a, short8 b, f32x16 c) {
  return __builtin_amdgcn_mfma_f32_32x32x16_bf16(a, b, c, 0, 0, 0);
}
__device__ __forceinline__ unsigned int cvtpk(float lo, float hi) {
  unsigned int r;
  asm("v_cvt_pk_bf16_f32 %0, %1, %2" : "=v"(r) : "v"(lo), "v"(hi));
  return r;
}
__device__ __forceinline__ uint2v plswap(unsigned int a, unsigned int b) {
  return __builtin_amdgcn_permlane32_swap(a, b, false, false);
}

// ---------------- f32 -> bf16 convert (optional scale) -----------------------
__global__ __launch_bounds__(256)
void cvt_kernel(const float* __restrict__ src, unsigned short* __restrict__ dst,
                int nchunks, float scale) {
  int i = blockIdx.x * blockDim.x + threadIdx.x;
  int stride = gridDim.x * blockDim.x;
  for (int c = i; c < nchunks; c += stride) {
    const float4 a = *(const float4*)(src + (size_t)c * 8);
    const float4 b = *(const float4*)(src + (size_t)c * 8 + 4);
    short8 r;
    r[0] = f2b(a.x * scale); r[1] = f2b(a.y * scale);
    r[2] = f2b(a.z * scale); r[3] = f2b(a.w * scale);
    r[4] = f2b(b.x * scale); r[5] = f2b(b.y * scale);
    r[6] = f2b(b.z * scale); r[7] = f2b(b.w * scale);
    *(short8*)(dst + (size_t)c * 8) = r;
  }
}

// ---------------- W1 -> bf16 with row interleave -----------------------------
// dst row r' = [b = r'>>6][half = (r'>>5)&1][r'&31] <- src row half*8192+b*32+(r'&31)
__global__ __launch_bounds__(256)
void cvt_w1p_kernel(const float* __restrict__ src,
                    unsigned short* __restrict__ dst) {
  int i = blockIdx.x * blockDim.x + threadIdx.x;
  int stride = gridDim.x * blockDim.x;
  const int total = 2 * D_FF * (D_MODEL / 8);
  for (int c = i; c < total; c += stride) {
    int rp = c >> 8, col8 = c & 255;
    int b = rp >> 6, half = (rp >> 5) & 1;
    int rs = half * D_FF + b * 32 + (rp & 31);
    const float* s = src + (size_t)rs * D_MODEL + col8 * 8;
    const float4 a = *(const float4*)s;
    const float4 bb = *(const float4*)(s + 4);
    short8 r;
    r[0] = f2b(a.x); r[1] = f2b(a.y); r[2] = f2b(a.z); r[3] = f2b(a.w);
    r[4] = f2b(bb.x); r[5] = f2b(bb.y); r[6] = f2b(bb.z); r[7] = f2b(bb.w);
    *(short8*)(dst + (size_t)c * 8) = r;
  }
}

// ---------------- b1 permuted to match W1' row order -------------------------
__global__ void permb1_kernel(const float* __restrict__ b1,
                              float* __restrict__ b1p) {
  int i = blockIdx.x * 256 + threadIdx.x;
  int b = i >> 6, half = (i >> 5) & 1;
  b1p[i] = b1[half * D_FF + b * 32 + (i & 31)];
}

// ---------------- concat bias: [(bq+rot)*QSCALE | bk | bv] -------------------
__global__ void biasqkv_kernel(const float* __restrict__ bq,
                               const float* __restrict__ bk,
                               const float* __restrict__ bv,
                               const float* __restrict__ rot,
                               float* __restrict__ outp) {
  int i = blockIdx.x * 256 + threadIdx.x;
  float v;
  if (i < 2048) v = (bq[i] + rot[i & (HEAD_DIM - 1)]) * QSCALE;
  else if (i < 4096) v = bk[i - 2048];
  else v = bv[i - 4096];
  outp[i] = v;
}

// ---------------- RMSNorm: f32 in -> bf16 out --------------------------------
__global__ __launch_bounds__(256)
void rmsnorm_kernel(const float* __restrict__ x, const float* __restrict__ wv,
                    unsigned short* __restrict__ outp) {
  const int row = blockIdx.x;
  const float* xr = x + (size_t)row * D_MODEL;
  const int base = threadIdx.x * 8;
  float4 a = *(const float4*)(xr + base);
  float4 c = *(const float4*)(xr + base + 4);
  float ss = a.x * a.x + a.y * a.y + a.z * a.z + a.w * a.w +
             c.x * c.x + c.y * c.y + c.z * c.z + c.w * c.w;
#pragma unroll
  for (int m = 1; m < 64; m <<= 1) ss += __shfl_xor(ss, m);
  __shared__ float red[4];
  if ((threadIdx.x & 63) == 0) red[threadIdx.x >> 6] = ss;
  __syncthreads();
  float tot = red[0] + red[1] + red[2] + red[3];
  float sc = rsqrtf(tot * (1.0f / D_MODEL) + 1e-8f);
  float4 w0 = *(const float4*)(wv + base);
  float4 w1 = *(const float4*)(wv + base + 4);
  short8 r;
  r[0] = f2b(a.x * sc * w0.x); r[1] = f2b(a.y * sc * w0.y);
  r[2] = f2b(a.z * sc * w0.z); r[3] = f2b(a.w * sc * w0.w);
  r[4] = f2b(c.x * sc * w1.x); r[5] = f2b(c.y * sc * w1.y);
  r[6] = f2b(c.z * sc * w1.z); r[7] = f2b(c.w * sc * w1.w);
  *(short8*)(outp + (size_t)row * D_MODEL + base) = r;
}

// ===== GEMM 256x256, BK=64, 2-phase/K-tile pipelined, 32x32x16 MFMA ==========
// Phase p of a K-tile reads A-half p only (sub-blocks 2p, 2p+1) + B (cached
// in regs from phase 0) and issues 16 MFMA_32x32x16 (~128 cy) per barrier
// window — half the barrier count of the r8/r9 schedule, same liveness:
// the six stage points keep their K-tile-relative positions (merged pairwise),
// vmcnt(4) once per K-tile verifies next tile's halves landed.
// MODE 0: bf16 out + bias.  MODE 2: f32 partial out.  MODE 3: swiglu-fused
// bf16 out (W1': rows interleaved so cb0 = x1, cb1 = x2; out LD = N/2).
template <int MODE>
__global__ __launch_bounds__(512, 2)
void gemm_p8(const unsigned short* __restrict__ A, int lda,
             const unsigned short* __restrict__ W, int ldw,
             const float* __restrict__ bias, void* __restrict__ outp,
             int N, int K, size_t out_zstride) {
  __shared__ unsigned short AL[2][2][128 * 64];
  __shared__ unsigned short BL[2][2][128 * 64];
  const int t = threadIdx.x;
  const int l = t & 63, w = t >> 6;
  const int wm = w >> 2, wn = w & 3;
  const int ln = l & 31, hi = l >> 5;
  const int m0 = blockIdx.y << 8, n0 = blockIdx.x << 8;
  const int koff = blockIdx.z * K;

  // staging: half-tile = 128 rows x 64 k; thread t stages chunks t, t+512
  const int r0 = t >> 3;
  const int cb16 = (t & 7) * 16;
  const int fs = ((r0 + (r0 >> 3)) & 7) << 4;
  const int sel = ((cb16 ^ fs) >> 1);
  const unsigned short* Abase = A + (size_t)m0 * lda + koff;
  const unsigned short* Wbase = W + (size_t)n0 * ldw + koff;
  const int d0e = t * 8, d1e = (t + 512) * 8;

#define STAGE(XL, Xb, ld, dd, h, ktd)                                        \
  do {                                                                       \
    const unsigned short* s_ =                                               \
        (Xb) + (size_t)((h) * 128 + r0) * (ld) + (ktd) * 64 + sel;           \
    gload_lds16(s_, &XL[dd][h][d0e]);                                        \
    gload_lds16(s_ + (size_t)64 * (ld), &XL[dd][h][d1e]);                    \
  } while (0)

  const int hb = wn >> 1;                       // B half for this wave
  const int browb = ((wn & 1) * 64 + ln) * 128; // B row base byte
  const int lnf = ln + (ln >> 3);               // swizzle seed

  f32x16 acc[4][2] = {};
  short8 bf[2][4];  // B-frags held across both phases of a K-tile

#define READB(dd)                                                            \
  do {                                                                       \
    const char* Bb_ = (const char*)&BL[dd][hb][0];                           \
    _Pragma("unroll") for (int cb_ = 0; cb_ < 2; cb_++) {                    \
      const int fb_ = ((lnf + 4 * cb_) & 7) << 4;                            \
      _Pragma("unroll") for (int ks_ = 0; ks_ < 4; ks_++)                    \
        bf[cb_][ks_] = *(const short8*)(Bb_ + browb + cb_ * 4096 +           \
                                        ((ks_ * 32 + hi * 16) ^ fb_));       \
    }                                                                        \
  } while (0)

// PHASE2(dd, p): reads A-half p (sub-blocks 2p, 2p+1), 16 MFMA.
#define PHASE2(dd, p, STAGE_STMT, VM_STMT)                                   \
  do {                                                                       \
    const char* Ab_ = (const char*)&AL[dd][p][0];                            \
    short8 af_[2][4];                                                        \
    if ((p) == 0) READB(dd);                                                 \
    _Pragma("unroll") for (int sb_ = 0; sb_ < 2; sb_++) {                    \
      const int fa_ = ((lnf + 4 * sb_) & 7) << 4;                            \
      _Pragma("unroll") for (int ks_ = 0; ks_ < 4; ks_++)                    \
        af_[sb_][ks_] = *(const short8*)(Ab_ +                               \
                                         (wm * 64 + sb_ * 32 + ln) * 128 +   \
                                         ((ks_ * 32 + hi * 16) ^ fa_));      \
    }                                                                        \
    STAGE_STMT;                                                              \
    __builtin_amdgcn_sched_barrier(0);                                       \
    VM_STMT;                                                                 \
    __builtin_amdgcn_sched_barrier(0);                                       \
    __builtin_amdgcn_s_barrier();                                            \
    __builtin_amdgcn_sched_barrier(0);                                       \
    __builtin_amdgcn_s_setprio(1);                                           \
    _Pragma("unroll") for (int sb_ = 0; sb_ < 2; sb_++)                      \
      _Pragma("unroll") for (int cb_ = 0; cb_ < 2; cb_++)                    \
        _Pragma("unroll") for (int ks_ = 0; ks_ < 4; ks_++)                  \
          acc[2 * (p) + sb_][cb_] =                                          \
              mfma32(af_[sb_][ks_], bf[cb_][ks_], acc[2 * (p) + sb_][cb_]);  \
    __builtin_amdgcn_s_setprio(0);                                           \
    __builtin_amdgcn_sched_barrier(0);                                       \
    __builtin_amdgcn_s_barrier();                                            \
    __builtin_amdgcn_sched_barrier(0);                                       \
  } while (0)

  const int NT = K >> 6;

  // prologue: kt0 fully, kt1's A-half0 + B-half0 (proven r5-r9 chain)
  STAGE(AL, Abase, lda, 0, 0, 0);
  STAGE(AL, Abase, lda, 0, 1, 0);
  STAGE(BL, Wbase, ldw, 0, 0, 0);
  STAGE(BL, Wbase, ldw, 0, 1, 0);
  STAGE(AL, Abase, lda, 1, 0, 1);
  STAGE(BL, Wbase, ldw, 1, 0, 1);
  asm volatile("s_waitcnt vmcnt(4)" ::: "memory");
  __builtin_amdgcn_sched_barrier(0);
  __builtin_amdgcn_s_barrier();
  __builtin_amdgcn_sched_barrier(0);

  for (int kt = 0; kt < NT; kt += 2) {
    // ---- K-tile kt (dbuf 0) ----
    PHASE2(0, 0,
           {
             if (kt + 1 < NT) {
               STAGE(BL, Wbase, ldw, 1, 1, kt + 1);
               STAGE(AL, Abase, lda, 1, 1, kt + 1);
             }
           },
           {});
    PHASE2(0, 1,
           {
             if (kt + 2 < NT) {
               STAGE(AL, Abase, lda, 0, 0, kt + 2);
               STAGE(BL, Wbase, ldw, 0, 0, kt + 2);
             }
           },
           {
             if (kt + 2 < NT)
               asm volatile("s_waitcnt vmcnt(4)" ::: "memory");
             else
               asm volatile("s_waitcnt vmcnt(0)" ::: "memory");
           });
    // ---- K-tile kt+1 (dbuf 1) ----
    PHASE2(1, 0,
           {
             if (kt + 2 < NT) {
               STAGE(BL, Wbase, ldw, 0, 1, kt + 2);
               STAGE(AL, Abase, lda, 0, 1, kt + 2);
             }
           },
           {});
    PHASE2(1, 1,
           {
             if (kt + 3 < NT) {
               STAGE(AL, Abase, lda, 1, 0, kt + 3);
               STAGE(BL, Wbase, ldw, 1, 0, kt + 3);
             }
           },
           {
             if (kt + 3 < NT)
               asm volatile("s_waitcnt vmcnt(4)" ::: "memory");
             else
               asm volatile("s_waitcnt vmcnt(0)" ::: "memory");
           });
  }
#undef PHASE2
#undef READB
#undef STAGE

  // epilogue: row = m0+(rb>>1)*128+wm*64+(rb&1)*32+(r&3)+8*(r>>2)+4*hi
#pragma unroll
  for (int rb = 0; rb < 4; rb++) {
    const int rowb = m0 + (rb >> 1) * 128 + wm * 64 + (rb & 1) * 32 + 4 * hi;
    if (MODE == 3) {
      const int col0 = n0 + wn * 64 + ln;
      const float b1v = bias[col0];
      const float b2v = bias[col0 + 32];
      const int jout = (n0 >> 1) + wn * 32 + ln;
#pragma unroll
      for (int r = 0; r < 16; r++) {
        const int row = rowb + (r & 3) + 8 * (r >> 2);
        float x1 = acc[rb][0][r] + b1v;
        float x2 = acc[rb][1][r] + b2v;
        float sg = x2 / (1.0f + __expf(-x2));
        ((unsigned short*)outp)[(size_t)row * (N >> 1) + jout] = f2b(x1 * sg);
      }
    } else {
#pragma unroll
      for (int cb = 0; cb < 2; cb++) {
        const int col = n0 + wn * 64 + cb * 32 + ln;
        const float bv = (MODE == 0) ? bias[col] : 0.0f;
#pragma unroll
        for (int r = 0; r < 16; r++) {
          const int row = rowb + (r & 3) + 8 * (r >> 2);
          const float vv = acc[rb][cb][r] + bv;
          if (MODE == 0)
            ((unsigned short*)outp)[(size_t)row * N + col] = f2b(vv);
          else
            ((float*)outp + blockIdx.z * out_zstride)[(size_t)row * N + col] = vv;
        }
      }
    }
  }
}

// ---------------- GEMM 128x128 (m97 structure): O-proj -----------------------
template <int MODE>
__global__ __launch_bounds__(256)
void gemm_bt(const unsigned short* __restrict__ A, int lda,
             const unsigned short* __restrict__ W, int ldw,
             const float* __restrict__ bias, const float* res, void* outp,
             int N, int K, size_t out_zstride) {
  __shared__ unsigned short As[128 * 32];
  __shared__ unsigned short Bs[128 * 32];
  const int t = threadIdx.x;
  const int l = t & 63;
  const int w = t >> 6;
  const int m0 = blockIdx.y << 7;
  const int n0 = blockIdx.x << 7;
  const int wr = (w >> 1) << 6;
  const int wc = (w & 1) << 6;
  const int koff = blockIdx.z * K;

  const unsigned short* Ab = A + (size_t)m0 * lda + koff;
  const unsigned short* Wb = W + (size_t)n0 * ldw + koff;

  f32x4 acc[4][4] = {};

  const int c0 = t, c1 = t + 256;
  const int ar0 = c0 >> 2, ak0 = (c0 & 3) * 8;
  const int ar1 = c1 >> 2, ak1 = (c1 & 3) * 8;
  const int lr = l & 15, lk = (l >> 4) * 8;

  for (int k0 = 0; k0 < K; k0 += 32) {
    gload_lds16(Ab + (size_t)ar0 * lda + k0 + ak0, &As[c0 * 8]);
    gload_lds16(Ab + (size_t)ar1 * lda + k0 + ak1, &As[c1 * 8]);
    gload_lds16(Wb + (size_t)ar0 * ldw + k0 + ak0, &Bs[c0 * 8]);
    gload_lds16(Wb + (size_t)ar1 * ldw + k0 + ak1, &Bs[c1 * 8]);
    __syncthreads();
    short8 a[4], b[4];
#pragma unroll
    for (int mi = 0; mi < 4; mi++)
      a[mi] = *(const short8*)&As[(wr + mi * 16 + lr) * 32 + lk];
#pragma unroll
    for (int ni = 0; ni < 4; ni++)
      b[ni] = *(const short8*)&Bs[(wc + ni * 16 + lr) * 32 + lk];
#pragma unroll
    for (int mi = 0; mi < 4; mi++)
#pragma unroll
      for (int ni = 0; ni < 4; ni++)
        acc[mi][ni] = __builtin_amdgcn_mfma_f32_16x16x32_bf16(
            a[mi], b[ni], acc[mi][ni], 0, 0, 0);
    __syncthreads();
  }

  const int lg = (l >> 4) * 4;
#pragma unroll
  for (int mi = 0; mi < 4; mi++) {
#pragma unroll
    for (int ni = 0; ni < 4; ni++) {
      int cn = n0 + wc + ni * 16 + lr;
      float bval = bias[cn];
#pragma unroll
      for (int j = 0; j < 4; j++) {
        int r = m0 + wr + mi * 16 + lg + j;
        float vv = acc[mi][ni][j] + bval;
        size_t idx = (size_t)r * N + cn;
        ((float*)outp)[idx] = vv + res[idx];
      }
    }
  }
  (void)out_zstride;
}

// ---------------- V transpose: qkv v-slice -> vt[(bh*128+d)*S + s] -----------
__global__ __launch_bounds__(256)
void vtrans_kernel(const unsigned short* __restrict__ qkv,
                   unsigned short* __restrict__ vt) {
  const int bh = blockIdx.y;
  const int b = bh >> 4, h = bh & 15;
  const int s0 = blockIdx.x * 32;
  __shared__ unsigned short tile[32][136];
  const int t = threadIdx.x;
  for (int i = 0; i < 2; i++) {
    int c = t + i * 256;
    int s = c >> 4, dc = c & 15;
    *(short8*)&tile[s][dc * 8] =
        *(const short8*)(qkv + (size_t)(b * SEQ + s0 + s) * QKV_LD + 4096 +
                         h * HEAD_DIM + dc * 8);
  }
  __syncthreads();
  const int d = t >> 1, sh = (t & 1) * 16;
  unsigned short* dst = vt + ((size_t)bh * HEAD_DIM + d) * SEQ + s0 + sh;
  short8 r0, r1;
#pragma unroll
  for (int j = 0; j < 8; j++) r0[j] = tile[sh + j][d];
#pragma unroll
  for (int j = 0; j < 8; j++) r1[j] = tile[sh + 8 + j][d];
  *(short8*)dst = r0;
  *(short8*)(dst + 8) = r1;
}

// ======== Flash attention: 8-warp 32x32 swapped-operand ======================
__global__ __launch_bounds__(512, 2)
void attn_kernel(const unsigned short* __restrict__ qkv,
                 const unsigned short* __restrict__ vt,
                 unsigned short* __restrict__ o) {
  const int bh = blockIdx.y;
  const int b = bh >> 4, h = bh & 15;
  const int q0 = blockIdx.x << 8;
  const int t = threadIdx.x, w = t >> 6, l = t & 63;
  const int ln = l & 31, hi = l >> 5;

  __shared__ unsigned short Ks[2][64 * 128];

  short8 qf[8];
  {
    const unsigned short* qb =
        qkv + (size_t)(b * SEQ + q0 + w * 32 + ln) * QKV_LD + h * HEAD_DIM +
        hi * 8;
#pragma unroll
    for (int sl = 0; sl < 8; sl++) qf[sl] = *(const short8*)(qb + sl * 16);
  }

  f32x16 oacc[4] = {};
  float mrow = -1e30f, lrow = 0.f;

  const unsigned short* kbase =
      qkv + (size_t)(b * SEQ) * QKV_LD + 2048 + h * HEAD_DIM;
  const unsigned short* vbase = vt + (size_t)bh * HEAD_DIM * SEQ;

#define STAGEK(buf, kv0_)                                                    \
  do {                                                                       \
    _Pragma("unroll") for (int i_ = 0; i_ < 2; i_++) {                       \
      int c_ = t + i_ * 512;                                                 \
      int row_ = c_ >> 4, dc_ = c_ & 15;                                     \
      int f_ = ((row_ + (row_ >> 3)) & 7) << 4;                              \
      int sel_ = ((dc_ * 16) ^ f_) >> 1;                                     \
      gload_lds16(kbase + (size_t)((kv0_) + row_) * QKV_LD + sel_,           \
                  &Ks[buf][c_ * 8]);                                         \
    }                                                                        \
  } while (0)

  STAGEK(0, 0);
  __syncthreads();

  const int f0 = ((ln + (ln >> 3)) & 7) << 4;
  const int f1 = ((ln + (ln >> 3) + 4) & 7) << 4;

  for (int it = 0; it < SEQ / 64; ++it) {
    const int cur = it & 1;
    const int kv0 = it * 64;

    short8 vf[4][4];
#pragma unroll
    for (int db = 0; db < 4; db++)
#pragma unroll
      for (int ks = 0; ks < 4; ks++)
        vf[db][ks] = *(const short8*)(vbase + (size_t)(db * 32 + ln) * SEQ +
                                      kv0 + ks * 16 + hi * 8);

    if (it + 1 < SEQ / 64) STAGEK(cur ^ 1, kv0 + 64);

    const char* kb = (const char*)&Ks[cur][0];
    f32x16 s0 = {}, s1 = {};
#pragma unroll
    for (int sl = 0; sl < 8; sl++) {
      const int cwb = sl * 32 + hi * 16;
      short8 kf0 = *(const short8*)(kb + ln * 256 + (cwb ^ f0));
      short8 kf1 = *(const short8*)(kb + (32 + ln) * 256 + (cwb ^ f1));
      s0 = mfma32(kf0, qf[sl], s0);
      s1 = mfma32(kf1, qf[sl], s1);
    }

    float mx = s0[0];
#pragma unroll
    for (int r = 1; r < 16; r++) mx = fmaxf(mx, s0[r]);
#pragma unroll
    for (int r = 0; r < 16; r++) mx = fmaxf(mx, s1[r]);
    {
      uint2v r2 = plswap(__float_as_uint(mx), __float_as_uint(mx));
      mx = fmaxf(__uint_as_float(r2[0]), __uint_as_float(r2[1]));
    }

    if (!__all(mx <= mrow + 8.f)) {
      float mnew = fmaxf(mrow, mx);
      float fs = exp2f(mrow - mnew);
      mrow = mnew;
      lrow *= fs;
#pragma unroll
      for (int db = 0; db < 4; db++)
#pragma unroll
        for (int r = 0; r < 16; r++) oacc[db][r] *= fs;
    }

    float p0[16], p1[16];
    float sum = 0.f;
#pragma unroll
    for (int r = 0; r < 16; r++) {
      p0[r] = exp2f(s0[r] - mrow);
      sum += p0[r];
    }
#pragma unroll
    for (int r = 0; r < 16; r++) {
      p1[r] = exp2f(s1[r] - mrow);
      sum += p1[r];
    }
    lrow += sum;

    uint4v pk[4];
#define PACKSUB(P, K0)                                                       \
  {                                                                          \
    unsigned int a_, b_;                                                     \
    uint2v r_;                                                               \
    a_ = cvtpk(P[0], P[1]); b_ = cvtpk(P[4], P[5]);                          \
    r_ = plswap(a_, b_); pk[K0][0] = r_[0]; pk[K0][2] = r_[1];               \
    a_ = cvtpk(P[2], P[3]); b_ = cvtpk(P[6], P[7]);                          \
    r_ = plswap(a_, b_); pk[K0][1] = r_[0]; pk[K0][3] = r_[1];               \
    a_ = cvtpk(P[8], P[9]); b_ = cvtpk(P[12], P[13]);                        \
    r_ = plswap(a_, b_); pk[K0 + 1][0] = r_[0]; pk[K0 + 1][2] = r_[1];       \
    a_ = cvtpk(P[10], P[11]); b_ = cvtpk(P[14], P[15]);                      \
    r_ = plswap(a_, b_); pk[K0 + 1][1] = r_[0]; pk[K0 + 1][3] = r_[1];       \
  }
    PACKSUB(p0, 0);
    PACKSUB(p1, 2);
#undef PACKSUB

#pragma unroll
    for (int db = 0; db < 4; db++)
#pragma unroll
      for (int ks = 0; ks < 4; ks++)
        oacc[db] = mfma32(vf[db][ks], __builtin_bit_cast(short8, pk[ks]),
                          oacc[db]);

    __syncthreads();
  }
#undef STAGEK

  {
    uint2v r2 = plswap(__float_as_uint(lrow), __float_as_uint(lrow));
    lrow = __uint_as_float(r2[0]) + __uint_as_float(r2[1]);
  }
  const float inv = 1.0f / lrow;
  unsigned short* ob = o + (size_t)(b * SEQ + q0 + w * 32 + ln) * D_MODEL +
                       h * HEAD_DIM + hi * 4;
#pragma unroll
  for (int db = 0; db < 4; db++)
#pragma unroll
    for (int r = 0; r < 4; r++) {
      short4v v4;
#pragma unroll
      for (int j = 0; j < 4; j++)
        v4[j] = (short)f2b(oacc[db][4 * r + j] * inv);
      *(short4v*)(ob + db * 32 + r * 8) = v4;
    }
}

// ---------------- split-K reduce: out += p0 + p1 + b2 ------------------------
__global__ __launch_bounds__(256)
void reduce2_kernel(const float* __restrict__ p0, const float* __restrict__ p1,
                    const float* __restrict__ b2, float* __restrict__ out) {
  size_t i = (size_t)blockIdx.x * 256 + threadIdx.x;
  float4 a = ((const float4*)p0)[i];
  float4 b = ((const float4*)p1)[i];
  float4 o = ((const float4*)out)[i];
  float4 bb = ((const float4*)b2)[i & 511];
  o.x += a.x + b.x + bb.x;
  o.y += a.y + b.y + bb.y;
  o.z += a.z + b.z + bb.z;
  o.w += a.w + b.w + bb.w;
  ((float4*)out)[i] = o;
}

// ---------------- host: launch sequence --------------------------------------
extern "C" void kernel_launch(void* const* d_in, const int* in_sizes, int n_in,
                              void* d_out, int out_size, void* d_ws,
                              size_t ws_size, hipStream_t stream) {
  (void)in_sizes; (void)n_in; (void)out_size; (void)ws_size;
  const float* x   = (const float*)d_in[0];
  const float* Wq  = (const float*)d_in[1];
  const float* bq  = (const float*)d_in[2];
  const float* Wk  = (const float*)d_in[3];
  const float* bk  = (const float*)d_in[4];
  const float* Wv  = (const float*)d_in[5];
  const float* bv  = (const float*)d_in[6];
  const float* Wo  = (const float*)d_in[7];
  const float* bo  = (const float*)d_in[8];
  const float* rot = (const float*)d_in[9];
  const float* n1w = (const float*)d_in[10];
  const float* n2w = (const float*)d_in[11];
  const float* W1  = (const float*)d_in[12];
  const float* b1  = (const float*)d_in[13];
  const float* W2  = (const float*)d_in[14];
  const float* b2  = (const float*)d_in[15];
  float* out = (float*)d_out;
  char* ws = (char*)d_ws;

  const size_t SZ_D2  = (size_t)D_MODEL * D_MODEL * 2;   // 8 MiB
  const size_t SZ_ACT = (size_t)M_TOK * D_MODEL * 2;     // 16 MiB
  const size_t SZ_W1  = (size_t)2 * D_FF * D_MODEL * 2;  // 64 MiB
  const size_t SZ_W2  = (size_t)D_MODEL * D_FF * 2;      // 32 MiB
  const size_t SZ_G   = (size_t)M_TOK * 2 * D_FF * 2;    // 128 MiB

  size_t off = 0;
  auto alloc = [&](size_t sz) { size_t o = off; off += (sz + 255) & ~(size_t)255; return o; };
  unsigned short* wqkv_b = (unsigned short*)(ws + alloc(3 * SZ_D2));  // at ws+0
  unsigned short* wo_b   = (unsigned short*)(ws + alloc(SZ_D2));
  unsigned short* w1_b   = (unsigned short*)(ws + alloc(SZ_W1));     // permuted W1'
  unsigned short* w2_b   = (unsigned short*)(ws + alloc(SZ_W2));
  float*          biasq  = (float*)(ws + alloc(QKV_LD * 4));
  float*          b1p    = (float*)(ws + alloc(2 * D_FF * 4));
  unsigned short* h2_b   = (unsigned short*)(ws + alloc(SZ_ACT));
  char* pool = ws + alloc(SZ_G);
  // phase 1 overlay in pool: h | qkv | vt | o   (16+48+16+16 = 96 MiB)
  unsigned short* h_b   = (unsigned short*)(pool);
  unsigned short* qkv_b = (unsigned short*)(pool + SZ_ACT);
  unsigned short* vt_b  = (unsigned short*)(pool + 4 * SZ_ACT);
  unsigned short* o_b   = (unsigned short*)(pool + 5 * SZ_ACT);
  // phase 2 overlay: ff (4096 x 8192 bf16 = 64 MiB) occupies pool start
  unsigned short* ff_b  = (unsigned short*)(pool);
  // split-K partials overlay the (then-dead) wqkv/wo/w1 region
  float* p0 = (float*)ws;
  float* p1 = p0 + (size_t)M_TOK * D_MODEL;

  // weights -> bf16 (Q,K,V concatenated row-wise; Wq pre-scaled by QSCALE)
  cvt_kernel<<<1024, 256, 0, stream>>>(Wq, wqkv_b, D_MODEL * D_MODEL / 8, QSCALE);
  cvt_kernel<<<1024, 256, 0, stream>>>(Wk, wqkv_b + (size_t)D_MODEL * D_MODEL, D_MODEL * D_MODEL / 8, 1.0f);
  cvt_kernel<<<1024, 256, 0, stream>>>(Wv, wqkv_b + (size_t)2 * D_MODEL * D_MODEL, D_MODEL * D_MODEL / 8, 1.0f);
  cvt_kernel<<<1024, 256, 0, stream>>>(Wo, wo_b, D_MODEL * D_MODEL / 8, 1.0f);
  cvt_w1p_kernel<<<2048, 256, 0, stream>>>(W1, w1_b);
  cvt_kernel<<<2048, 256, 0, stream>>>(W2, w2_b, D_MODEL * D_FF / 8, 1.0f);
  biasqkv_kernel<<<QKV_LD / 256, 256, 0, stream>>>(bq, bk, bv, rot, biasq);
  permb1_kernel<<<2 * D_FF / 256, 256, 0, stream>>>(b1, b1p);

  // norm1 -> h
  rmsnorm_kernel<<<M_TOK, 256, 0, stream>>>(x, n1w, h_b);

  // fused QKV projection (2-phase 256^2, 32x32 MFMA)
  gemm_p8<0><<<dim3(QKV_LD / 256, M_TOK / 256), 512, 0, stream>>>(
      h_b, D_MODEL, wqkv_b, D_MODEL, biasq, qkv_b, QKV_LD, D_MODEL, 0);

  // V transpose + attention
  vtrans_kernel<<<dim3(SEQ / 32, BATCH * N_HEADS), 256, 0, stream>>>(qkv_b, vt_b);
  attn_kernel<<<dim3(SEQ / 256, BATCH * N_HEADS), 512, 0, stream>>>(qkv_b, vt_b, o_b);

  // O projection + residual -> d_out (f32), 128^2 structure
  gemm_bt<1><<<dim3(D_MODEL / 128, M_TOK / 128), 256, 0, stream>>>(
      o_b, D_MODEL, wo_b, D_MODEL, bo, x, out, D_MODEL, D_MODEL, 0);

  // norm2 -> h2
  rmsnorm_kernel<<<M_TOK, 256, 0, stream>>>(out, n2w, h2_b);

  // W1 + fused SwiGLU -> ff (2-phase 256^2, MODE 3)
  gemm_p8<3><<<dim3(2 * D_FF / 256, M_TOK / 256), 512, 0, stream>>>(
      h2_b, D_MODEL, w1_b, D_MODEL, b1p, ff_b, 2 * D_FF, D_MODEL, 0);

  // W2 split-K on gemm_p8 (z=2): A = ff [4096][8192]
  gemm_p8<2><<<dim3(D_MODEL / 256, M_TOK / 256, 2), 512, 0, stream>>>(
      ff_b, D_FF, w2_b, D_FF, nullptr, p0, D_MODEL, D_FF / 2,
      (size_t)M_TOK * D_MODEL);

  // out += p0 + p1 + b2
  reduce2_kernel<<<(M_TOK * D_MODEL / 4) / 256, 256, 0, stream>>>(p0, p1, b2, out);
}